// Round 2
// baseline (586.677 us; speedup 1.0000x reference)
//
#include <hip/hip_runtime.h>
#include <cstddef>
#include <cstdint>

// Problem constants (from reference)
static constexpr int Nn    = 20000;
static constexpr int Ee    = 320000;
static constexpr int Vv    = 100;
static constexpr int Hh    = 128;
static constexpr int HEADS = 3;
static constexpr int Bb    = 200;
static constexpr float NEG = 0.2f;
static constexpr float EPS = 1e-5f;

typedef short bf16x8 __attribute__((ext_vector_type(8)));
typedef float f32x4  __attribute__((ext_vector_type(4)));

__device__ inline unsigned short bf16_rne(float x) {
    unsigned u = __builtin_bit_cast(unsigned, x);
    u += 0x7FFFu + ((u >> 16) & 1u);
    return (unsigned short)(u >> 16);
}
__device__ inline float bf16_f(unsigned short h) {
    unsigned u = ((unsigned)h) << 16;
    return __builtin_bit_cast(float, u);
}
__device__ inline float bf_lo(unsigned u) { return __builtin_bit_cast(float, u << 16); }
__device__ inline float bf_hi(unsigned u) { return __builtin_bit_cast(float, u & 0xFFFF0000u); }
__device__ inline float lrelu(float a) { return a >= 0.f ? a : NEG * a; }
__device__ inline float sigmoidf(float x) { return 1.f / (1.f + __expf(-x)); }

// ---------------------------------------------------------------------------
// CSR scan + fill (hist lives in prep_all)
// ---------------------------------------------------------------------------
__global__ __launch_bounds__(1024) void scan_offsets(const int* __restrict__ deg,
                                                     int* __restrict__ offs,
                                                     int* __restrict__ cur) {
    __shared__ int sums[1024];
    const int tid = threadIdx.x;
    const int per = (Nn + 1023) >> 10;
    int begin = tid * per;
    int end = begin + per; if (end > Nn) end = Nn;
    if (begin > Nn) begin = Nn;
    int s = 0;
    for (int i = begin; i < end; i++) s += deg[i];
    sums[tid] = s;
    __syncthreads();
    for (int off = 1; off < 1024; off <<= 1) {
        int v = (tid >= off) ? sums[tid - off] : 0;
        __syncthreads();
        sums[tid] += v;
        __syncthreads();
    }
    int run = sums[tid] - s;
    for (int i = begin; i < end; i++) {
        offs[i] = run; cur[i] = run;
        run += deg[i];
    }
    if (end == Nn) offs[Nn] = run;
}

__global__ void fill_csr(const int* __restrict__ dst, const int* __restrict__ src,
                         int* __restrict__ cur, int* __restrict__ csrc) {
    for (int i = blockIdx.x * blockDim.x + threadIdx.x; i < Ee; i += gridDim.x * blockDim.x) {
        int p = atomicAdd(&cur[dst[i]], 1);
        csrc[p] = src[i];
    }
}

// ---------------------------------------------------------------------------
// Fused prep: projW split; Wfused = blockdiag(Wn)@Ws split-transposed;
// va/vd = Wn_h @ att halves; vc = bn_h . att halves; biasF = convB + bn@Ws;
// GRU weight transposes; graph offsets; dst histogram.
// ---------------------------------------------------------------------------
struct PrepArgs {
    const float *projW, *convWn, *convWs, *convAtt, *convBn, *convB;
    const float *Wih0, *Whh0, *Wih1, *Whh1;
    const int *gid, *dst;
    unsigned short *pBth, *pBtl;
    unsigned short *WfTh0, *WfTl0, *WfTh1, *WfTl1;
    float *vavd, *vc, *biasF;
    float *WihT0, *WhhT0, *WihT1, *WhhT1;
    int *goffs, *deg;
};

__device__ inline void wsplit(const float* B, int K, int N, int idx,
                              unsigned short* Bth, unsigned short* Btl) {
    int k = idx / N, n = idx - k * N;
    float v = B[idx];
    unsigned short h = bf16_rne(v);
    unsigned short l = bf16_rne(v - bf16_f(h));
    Bth[(size_t)n * K + k] = h;
    Btl[(size_t)n * K + k] = l;
}
__device__ inline void gruT(const float* W, int K, int idx, float* WT) {
    int d = idx / (384 * K);
    int r = idx - d * 384 * K;
    int j = r / K, k = r - j * K;
    WT[(size_t)d * K * 384 + (size_t)k * 384 + j] = W[idx];
}

__global__ void prep_all(PrepArgs a) {
    int i = blockIdx.x * blockDim.x + threadIdx.x;
    if (i < 16384) { wsplit(a.projW, 128, 128, i, a.pBth, a.pBtl); return; } i -= 16384;
#pragma unroll
    for (int l = 0; l < 2; l++) {
        if (i < 49152) {
            int k = i >> 7, c = i & 127;
            int h = k >> 7, i_ = k & 127;
            const float* wn = a.convWn + (size_t)l * 49152 + (size_t)i_ * 384 + h * 128;
            const float* ws = a.convWs + (size_t)l * 49152 + (size_t)(h * 128) * 128 + c;
            float v = 0.f;
            for (int j = 0; j < 128; j++) v += wn[j] * ws[(size_t)j * 128];
            unsigned short hi = bf16_rne(v);
            unsigned short lo = bf16_rne(v - bf16_f(hi));
            unsigned short* th = l ? a.WfTh1 : a.WfTh0;
            unsigned short* tl = l ? a.WfTl1 : a.WfTl0;
            th[(size_t)c * 384 + k] = hi;
            tl[(size_t)c * 384 + k] = lo;
            return;
        }
        i -= 49152;
    }
    if (i < 1536) {
        int l = i / 768, r = i % 768;
        int sd = r / 384, rr = r % 384, h = rr >> 7, i_ = rr & 127;
        const float* wn = a.convWn + (size_t)l * 49152 + (size_t)i_ * 384 + h * 128;
        const float* at = a.convAtt + l * 768 + h * 256 + sd * 128;
        float v = 0.f;
        for (int j = 0; j < 128; j++) v += wn[j] * at[j];
        a.vavd[i] = v;
        return;
    } i -= 1536;
    if (i < 12) {
        int l = i / 6, r = i % 6, sd = r / 3, h = r % 3;
        const float* bn = a.convBn + l * 384 + h * 128;
        const float* at = a.convAtt + l * 768 + h * 256 + sd * 128;
        float v = 0.f;
        for (int j = 0; j < 128; j++) v += bn[j] * at[j];
        a.vc[i] = v;
        return;
    } i -= 12;
    if (i < 256) {
        int l = i >> 7, c = i & 127;
        const float* bn = a.convBn + l * 384;
        const float* ws = a.convWs + (size_t)l * 49152 + c;
        float v = a.convB[l * 128 + c];
        for (int k = 0; k < 384; k++) v += bn[k] * ws[(size_t)k * 128];
        a.biasF[i] = v;
        return;
    } i -= 256;
    if (i < 98304)  { gruT(a.Wih0, 128, i, a.WihT0); return; }  i -= 98304;
    if (i < 98304)  { gruT(a.Whh0, 128, i, a.WhhT0); return; }  i -= 98304;
    if (i < 196608) { gruT(a.Wih1, 256, i, a.WihT1); return; }  i -= 196608;
    if (i < 98304)  { gruT(a.Whh1, 128, i, a.WhhT1); return; }  i -= 98304;
    if (i < Nn) {
        int g = a.gid[i];
        if (i == 0) { for (int b = 0; b <= g; b++) a.goffs[b] = 0; }
        else { int pg = a.gid[i - 1]; for (int b = pg + 1; b <= g; b++) a.goffs[b] = i; }
        if (i == Nn - 1) { for (int b = g + 1; b <= Bb; b++) a.goffs[b] = Nn; }
        return;
    } i -= Nn;
    if (i < Ee) atomicAdd(&a.deg[a.dst[i]], 1);
}

// ---------------------------------------------------------------------------
// Split-bf16 MFMA GEMM, BM=32, BN=128, BK=32; 256 threads = 4 waves (1x4),
// wave tile 32x32 (2x2 MFMA 16x16x32). Fused epilogues:
// MODE 0: proj: hcur = acc+bias+projW[wid]; MODE 2: residual+LN+ReLU.
// Both: fused per-graph readout; optional next-layer att dots (register-space,
// no LDS conflicts) + bf16 hcur plane.
// ---------------------------------------------------------------------------
struct GArgs {
    const float* A; const unsigned short* Bth; const unsigned short* Btl;
    const float* bias; int M, K;
    const int* wid; const float* projW;                 // MODE 0
    const int* deg; const float* gamma; const float* beta;  // MODE 2
    float* hcur;
    const int* gid; float* reado;
    const float* vavd; const float* vc;                 // null -> skip dots/hb
    float* adf; float* addf;
    unsigned short* hb;
};

template <int MODE>
__global__ __launch_bounds__(256) void gemm_fused(GArgs a) {
    __shared__ unsigned short As_hi[32][40];
    __shared__ unsigned short As_lo[32][40];
    __shared__ unsigned short Bs_hi[128][40];
    __shared__ unsigned short Bs_lo[128][40];
    __shared__ float ytile[32][132];
    __shared__ float sred[6][32][4];
    __shared__ int sgid[32];
    const int tid  = threadIdx.x;
    const int row0 = blockIdx.y * 32;
    const int wn   = tid >> 6;          // wave 0..3 along N
    const int L    = tid & 63;
    const int lrow = L & 15;
    const int lq   = L >> 4;
    const int K = a.K;

    f32x4 acc[2][2];
#pragma unroll
    for (int i = 0; i < 2; i++)
#pragma unroll
        for (int j = 0; j < 2; j++) acc[i][j] = (f32x4){0.f, 0.f, 0.f, 0.f};

    for (int kb = 0; kb < K; kb += 32) {
        {   // stage A 32x32
            int m  = tid >> 3;
            int kq = (tid & 7) * 4;
            float4 v = *(const float4*)(a.A + (size_t)(row0 + m) * K + kb + kq);
            unsigned short h0 = bf16_rne(v.x), h1 = bf16_rne(v.y),
                           h2 = bf16_rne(v.z), h3 = bf16_rne(v.w);
            *(short4*)&As_hi[m][kq] = make_short4((short)h0, (short)h1, (short)h2, (short)h3);
            *(short4*)&As_lo[m][kq] = make_short4((short)bf16_rne(v.x - bf16_f(h0)),
                                                  (short)bf16_rne(v.y - bf16_f(h1)),
                                                  (short)bf16_rne(v.z - bf16_f(h2)),
                                                  (short)bf16_rne(v.w - bf16_f(h3)));
        }
        {   // stage B^T 128x32
            int n  = tid >> 1;
            int kh = (tid & 1) * 16;
            const unsigned short* sh = a.Bth + (size_t)n * K + kb + kh;
            const unsigned short* sl = a.Btl + (size_t)n * K + kb + kh;
            *(float4*)&Bs_hi[n][kh]     = *(const float4*)sh;
            *(float4*)&Bs_hi[n][kh + 8] = *(const float4*)(sh + 8);
            *(float4*)&Bs_lo[n][kh]     = *(const float4*)sl;
            *(float4*)&Bs_lo[n][kh + 8] = *(const float4*)(sl + 8);
        }
        __syncthreads();
        bf16x8 ah[2], al[2], bh[2], bl[2];
#pragma unroll
        for (int mi = 0; mi < 2; mi++) {
            int r = mi * 16 + lrow;
            ah[mi] = *(const bf16x8*)&As_hi[r][lq * 8];
            al[mi] = *(const bf16x8*)&As_lo[r][lq * 8];
        }
#pragma unroll
        for (int ni = 0; ni < 2; ni++) {
            int r = wn * 32 + ni * 16 + lrow;
            bh[ni] = *(const bf16x8*)&Bs_hi[r][lq * 8];
            bl[ni] = *(const bf16x8*)&Bs_lo[r][lq * 8];
        }
#pragma unroll
        for (int mi = 0; mi < 2; mi++)
#pragma unroll
            for (int ni = 0; ni < 2; ni++) {
                acc[mi][ni] = __builtin_amdgcn_mfma_f32_16x16x32_bf16(ah[mi], bh[ni], acc[mi][ni], 0, 0, 0);
                acc[mi][ni] = __builtin_amdgcn_mfma_f32_16x16x32_bf16(ah[mi], bl[ni], acc[mi][ni], 0, 0, 0);
                acc[mi][ni] = __builtin_amdgcn_mfma_f32_16x16x32_bf16(al[mi], bh[ni], acc[mi][ni], 0, 0, 0);
            }
        __syncthreads();
    }

    // bias
#pragma unroll
    for (int ni = 0; ni < 2; ni++) {
        float bb = a.bias[wn * 32 + ni * 16 + lrow];
#pragma unroll
        for (int mi = 0; mi < 2; mi++)
#pragma unroll
            for (int r = 0; r < 4; r++) acc[mi][ni][r] += bb;
    }

    if constexpr (MODE == 0) {
        // acc := y = acc + projW[wid[row]]  (bias already in)
#pragma unroll
        for (int mi = 0; mi < 2; mi++)
#pragma unroll
            for (int r = 0; r < 4; r++) {
                int lr = mi * 16 + lq * 4 + r;
                int row = row0 + lr;
                int wi = a.wid[row];
#pragma unroll
                for (int ni = 0; ni < 2; ni++) {
                    int c = wn * 32 + ni * 16 + lrow;
                    float y = acc[mi][ni][r] + a.projW[(size_t)wi * 128 + c];
                    acc[mi][ni][r] = y;
                    a.hcur[(size_t)row * 128 + c] = y;
                    ytile[lr][c] = y;
                }
            }
    }

    if constexpr (MODE == 2) {
        __shared__ float red1[32][4], red2[32][4];
        float g4[2], be4[2];
#pragma unroll
        for (int ni = 0; ni < 2; ni++) {
            int c = wn * 32 + ni * 16 + lrow;
            g4[ni] = a.gamma[c]; be4[ni] = a.beta[c];
        }
#pragma unroll
        for (int mi = 0; mi < 2; mi++)
#pragma unroll
            for (int r = 0; r < 4; r++) {
                int lr = mi * 16 + lq * 4 + r;
                int row = row0 + lr;
                int dg = a.deg[row];
#pragma unroll
                for (int ni = 0; ni < 2; ni++) {
                    int c = wn * 32 + ni * 16 + lrow;
                    float hold = a.hcur[(size_t)row * 128 + c];
                    acc[mi][ni][r] = hold + (dg > 0 ? acc[mi][ni][r] : 0.f);
                }
            }
#pragma unroll
        for (int mi = 0; mi < 2; mi++)
#pragma unroll
            for (int r = 0; r < 4; r++) {
                float ps = acc[mi][0][r] + acc[mi][1][r];
#pragma unroll
                for (int o = 1; o < 16; o <<= 1) ps += __shfl_xor(ps, o, 64);
                if (lrow == 0) red1[mi * 16 + lq * 4 + r][wn] = ps;
            }
        __syncthreads();
#pragma unroll
        for (int mi = 0; mi < 2; mi++)
#pragma unroll
            for (int r = 0; r < 4; r++) {
                int lr = mi * 16 + lq * 4 + r;
                float mu = (red1[lr][0] + red1[lr][1] + red1[lr][2] + red1[lr][3]) * (1.f / 128.f);
                float qs = 0.f;
#pragma unroll
                for (int ni = 0; ni < 2; ni++) {
                    float dx = acc[mi][ni][r] - mu;
                    qs += dx * dx;
                }
#pragma unroll
                for (int o = 1; o < 16; o <<= 1) qs += __shfl_xor(qs, o, 64);
                if (lrow == 0) red2[lr][wn] = qs;
            }
        __syncthreads();
#pragma unroll
        for (int mi = 0; mi < 2; mi++)
#pragma unroll
            for (int r = 0; r < 4; r++) {
                int lr = mi * 16 + lq * 4 + r;
                int row = row0 + lr;
                float mu = (red1[lr][0] + red1[lr][1] + red1[lr][2] + red1[lr][3]) * (1.f / 128.f);
                float var = (red2[lr][0] + red2[lr][1] + red2[lr][2] + red2[lr][3]) * (1.f / 128.f);
                float rs = rsqrtf(var + EPS);
#pragma unroll
                for (int ni = 0; ni < 2; ni++) {
                    int c = wn * 32 + ni * 16 + lrow;
                    float y = fmaxf((acc[mi][ni][r] - mu) * rs * g4[ni] + be4[ni], 0.f);
                    acc[mi][ni][r] = y;
                    a.hcur[(size_t)row * 128 + c] = y;
                    ytile[lr][c] = y;
                }
            }
    }

    if (tid < 32) sgid[tid] = a.gid[row0 + tid];

    // ---- register-space attention dots (no ytile loop, no global v loop) ----
    const bool dots = (a.vavd != nullptr);
    if (dots) {
        float vv0[6], vv1[6];
#pragma unroll
        for (int d = 0; d < 6; d++) {
            vv0[d] = a.vavd[d * 128 + wn * 32 + lrow];
            vv1[d] = a.vavd[d * 128 + wn * 32 + 16 + lrow];
        }
#pragma unroll
        for (int d = 0; d < 6; d++) {
#pragma unroll
            for (int mi = 0; mi < 2; mi++)
#pragma unroll
                for (int r = 0; r < 4; r++) {
                    float ps = acc[mi][0][r] * vv0[d] + acc[mi][1][r] * vv1[d];
#pragma unroll
                    for (int o = 1; o < 16; o <<= 1) ps += __shfl_xor(ps, o, 64);
                    if (lrow == 0) sred[d][mi * 16 + lq * 4 + r][wn] = ps;
                }
        }
    }
    __syncthreads();

    // fused per-graph readout (gid sorted -> runs, atomic per run)
    {
        int j = tid & 127, hh = tid >> 7;
        float sum = 0.f; int curg = -1;
        for (int r = hh * 16; r < hh * 16 + 16; r++) {
            int g = sgid[r];
            if (g != curg) {
                if (curg >= 0) atomicAdd(&a.reado[(size_t)curg * 128 + j], sum);
                sum = 0.f; curg = g;
            }
            sum += ytile[r][j];
        }
        if (curg >= 0) atomicAdd(&a.reado[(size_t)curg * 128 + j], sum);
    }

    if (dots) {
        if (tid < 192) {
            int row = tid & 31, d = tid >> 5;     // d in [0,6)
            float s = sred[d][row][0] + sred[d][row][1] + sred[d][row][2] + sred[d][row][3]
                    + a.vc[d];
            int node = row0 + row;
            int sd = d / 3, h = d - sd * 3;
            float* dstp = sd ? a.addf : a.adf;
            dstp[(size_t)node * 4 + h] = s;
        }
        {   // bf16 hcur plane from ytile (<=2-way bank aliasing, free)
            int row = tid >> 3, c0 = (tid & 7) * 16;
            unsigned* dst = (unsigned*)(a.hb + (size_t)(row0 + row) * 128 + c0);
#pragma unroll
            for (int q = 0; q < 8; q++) {
                unsigned lo = bf16_rne(ytile[row][c0 + 2 * q]);
                unsigned hi = bf16_rne(ytile[row][c0 + 2 * q + 1]);
                dst[q] = lo | (hi << 16);
            }
        }
    }
}

// ---------------------------------------------------------------------------
// GAT gather: one wave per dst node, bf16 hcur rows (256B), scores from dots.
// ---------------------------------------------------------------------------
__global__ __launch_bounds__(256) void gat_gather(const unsigned short* __restrict__ hb,
                                                  const float4* __restrict__ ad,
                                                  const float4* __restrict__ add,
                                                  const int* __restrict__ offs,
                                                  const int* __restrict__ csrc,
                                                  float* __restrict__ T) {
    __shared__ float4 slot[4][64];
    const int n = (blockIdx.x * 256 + threadIdx.x) >> 6;
    const int wv_ = threadIdx.x >> 6;
    const int L = threadIdx.x & 63;
    if (n >= Nn) return;
    const int start = offs[n];
    const int deg = offs[n + 1] - start;
    float2* o2 = (float2*)(T + (size_t)n * 384);
    if (deg == 0) {
        float2 z = make_float2(0.f, 0.f);
        o2[L] = z; o2[64 + L] = z; o2[128 + L] = z;
        return;
    }
    const float4 adn = add[n];
    float2 t0 = make_float2(0.f, 0.f), t1 = t0, t2 = t0;

    if (deg <= 64) {
        int sn = 0; float e0 = 0.f, e1 = 0.f, e2 = 0.f;
        if (L < deg) {
            sn = csrc[start + L];
            float4 a4 = ad[sn];
            e0 = __expf(lrelu(a4.x + adn.x));
            e1 = __expf(lrelu(a4.y + adn.y));
            e2 = __expf(lrelu(a4.z + adn.z));
        }
        float s0 = e0, s1 = e1, s2 = e2;
#pragma unroll
        for (int o = 32; o > 0; o >>= 1) {
            s0 += __shfl_xor(s0, o, 64);
            s1 += __shfl_xor(s1, o, 64);
            s2 += __shfl_xor(s2, o, 64);
        }
        slot[wv_][L] = make_float4(__builtin_bit_cast(float, sn),
                                   e0 / s0, e1 / s1, e2 / s2);
        __builtin_amdgcn_wave_barrier();
#pragma unroll 2
        for (int j = 0; j < deg; j++) {
            float4 sc = slot[wv_][j];
            int s_n = __builtin_bit_cast(int, sc.x);
            unsigned u = ((const unsigned*)(hb + (size_t)s_n * 128))[L];
            float x0 = bf_lo(u), x1 = bf_hi(u);
            t0.x += sc.y * x0; t0.y += sc.y * x1;
            t1.x += sc.z * x0; t1.y += sc.z * x1;
            t2.x += sc.w * x0; t2.y += sc.w * x1;
        }
    } else {
        float s0 = 0.f, s1 = 0.f, s2 = 0.f;
        for (int i = L; i < deg; i += 64) {
            int sn = csrc[start + i];
            float4 a4 = ad[sn];
            s0 += __expf(lrelu(a4.x + adn.x));
            s1 += __expf(lrelu(a4.y + adn.y));
            s2 += __expf(lrelu(a4.z + adn.z));
        }
#pragma unroll
        for (int o = 32; o > 0; o >>= 1) {
            s0 += __shfl_xor(s0, o, 64);
            s1 += __shfl_xor(s1, o, 64);
            s2 += __shfl_xor(s2, o, 64);
        }
        float i0 = 1.f / s0, i1 = 1.f / s1, i2 = 1.f / s2;
        for (int base = 0; base < deg; base += 64) {
            int cnt = deg - base; if (cnt > 64) cnt = 64;
            if (L < cnt) {
                int sn = csrc[start + base + L];
                float4 a4 = ad[sn];
                slot[wv_][L] = make_float4(__builtin_bit_cast(float, sn),
                                           __expf(lrelu(a4.x + adn.x)) * i0,
                                           __expf(lrelu(a4.y + adn.y)) * i1,
                                           __expf(lrelu(a4.z + adn.z)) * i2);
            }
            __builtin_amdgcn_wave_barrier();
            for (int j = 0; j < cnt; j++) {
                float4 sc = slot[wv_][j];
                int s_n = __builtin_bit_cast(int, sc.x);
                unsigned u = ((const unsigned*)(hb + (size_t)s_n * 128))[L];
                float x0 = bf_lo(u), x1 = bf_hi(u);
                t0.x += sc.y * x0; t0.y += sc.y * x1;
                t1.x += sc.z * x0; t1.y += sc.z * x1;
                t2.x += sc.w * x0; t2.y += sc.w * x1;
            }
            __builtin_amdgcn_wave_barrier();
        }
    }
    o2[L] = t0; o2[64 + L] = t1; o2[128 + L] = t2;
}

// ---------------------------------------------------------------------------
// GRU v3: operand feeding via register shuffle (no LDS broadcast, no big
// register arrays -> no spill).
//  - grid (Bb/2, 2 dirs), 384 threads (6 waves), thread j owns gate j.
//  - GNB=2 batch elems per block: each weight load feeds 2 FMAs.
//  - gi phase: accumulate unscaled (linear), scale by invc at end; x operands
//    read as all-lanes-same-address float4 vector loads (1 instr, 1 L1 line).
//  - recurrence: h distributed across 64 lanes (2 regs x 2 nb); k-loop fully
//    unrolled so __shfl(h, k) is a readlane with immediate -> pure VALU.
//  - step 0 skips the h-dot (h == 0).
//  - h redistribution via tiny LDS arrays (hsh[128][2]) once per step.
// ---------------------------------------------------------------------------
__global__ __launch_bounds__(384) void gru_l0(const float* __restrict__ reado,
                                              const int* __restrict__ goffs,
                                              const float* __restrict__ WihT0,
                                              const float* __restrict__ WhhT0,
                                              const float* __restrict__ bih0,
                                              const float* __restrict__ bhh0,
                                              float* __restrict__ y0g,
                                              float* __restrict__ out) {
    const int dir = blockIdx.y;
    const int b0 = blockIdx.x * 2;
    const int j = threadIdx.x;
    const int L = j & 63;
    __shared__ float gis[384][2];
    __shared__ float ghs[384][2];
    __shared__ float hsh[128][2];

    float invc[2];
#pragma unroll
    for (int nb = 0; nb < 2; nb++) {
        int cnt = goffs[b0 + nb + 1] - goffs[b0 + nb];
        invc[nb] = 1.f / fmaxf((float)cnt, 1.f);
    }

    const float* Wi = WihT0 + (size_t)dir * 128 * 384;
    const float* Wh = WhhT0 + (size_t)dir * 128 * 384;
    const float bij = bih0[dir * 384 + j];
    const float bhj = bhh0[dir * 384 + j];

    // ---- gi phase: gi[t][nb] = sum_k Wi[k][j] * reado[t][b0+nb][k] ----
    float gi[3][2];
#pragma unroll
    for (int t = 0; t < 3; t++) { gi[t][0] = 0.f; gi[t][1] = 0.f; }
#pragma unroll 4
    for (int k = 0; k < 128; k += 4) {
        float w0 = Wi[(size_t)(k + 0) * 384 + j];
        float w1 = Wi[(size_t)(k + 1) * 384 + j];
        float w2 = Wi[(size_t)(k + 2) * 384 + j];
        float w3 = Wi[(size_t)(k + 3) * 384 + j];
#pragma unroll
        for (int t = 0; t < 3; t++)
#pragma unroll
            for (int nb = 0; nb < 2; nb++) {
                float4 x = *(const float4*)(reado + ((size_t)t * Bb + b0 + nb) * 128 + k);
                gi[t][nb] += w0 * x.x + w1 * x.y + w2 * x.z + w3 * x.w;
            }
    }
#pragma unroll
    for (int t = 0; t < 3; t++)
#pragma unroll
        for (int nb = 0; nb < 2; nb++)
            gi[t][nb] = gi[t][nb] * invc[nb] + bij;

    // ---- recurrence: h in lane-distributed registers ----
    float h0[2] = {0.f, 0.f};   // h[L][nb]
    float h1[2] = {0.f, 0.f};   // h[64+L][nb]
#pragma unroll
    for (int step = 0; step < 3; step++) {
        float g0 = bhj, g1 = bhj;
        if (step > 0) {
#pragma unroll
            for (int k = 0; k < 64; k++) {
                float w = Wh[(size_t)k * 384 + j];
                g0 += w * __shfl(h0[0], k, 64);
                g1 += w * __shfl(h0[1], k, 64);
            }
#pragma unroll
            for (int k = 0; k < 64; k++) {
                float w = Wh[(size_t)(64 + k) * 384 + j];
                g0 += w * __shfl(h1[0], k, 64);
                g1 += w * __shfl(h1[1], k, 64);
            }
        }
        float gs0 = dir ? gi[2 - step][0] : gi[step][0];
        float gs1 = dir ? gi[2 - step][1] : gi[step][1];
        *(float2*)&gis[j][0] = make_float2(gs0, gs1);
        *(float2*)&ghs[j][0] = make_float2(g0, g1);
        __syncthreads();
        if (j < 128) {
            const int t = dir ? 2 - step : step;
#pragma unroll
            for (int nb = 0; nb < 2; nb++) {
                float r  = sigmoidf(gis[j][nb] + ghs[j][nb]);
                float z  = sigmoidf(gis[j + 128][nb] + ghs[j + 128][nb]);
                float nn = tanhf(gis[j + 256][nb] + r * ghs[j + 256][nb]);
                float hprev = (step == 0) ? 0.f : hsh[j][nb];
                float hnew = (1.f - z) * nn + z * hprev;
                hsh[j][nb] = hnew;
                y0g[((size_t)t * Bb + (b0 + nb)) * 256 + dir * 128 + j] = hnew;
                if (step == 2)
                    atomicAdd(&out[(size_t)(b0 + nb) * Hh + j], 0.25f * hnew);
            }
        }
        __syncthreads();
        if (step < 2) {
            float2 a = *(const float2*)&hsh[L][0];
            float2 b = *(const float2*)&hsh[64 + L][0];
            h0[0] = a.x; h0[1] = a.y;
            h1[0] = b.x; h1[1] = b.y;
        }
    }
}

__global__ __launch_bounds__(384) void gru_l1(const float* __restrict__ y0g,
                                              const float* __restrict__ WihT1,
                                              const float* __restrict__ WhhT1,
                                              const float* __restrict__ bih1,
                                              const float* __restrict__ bhh1,
                                              float* __restrict__ out) {
    const int dir = blockIdx.y;
    const int b0 = blockIdx.x * 2;
    const int j = threadIdx.x;
    const int L = j & 63;
    __shared__ float gis[384][2];
    __shared__ float ghs[384][2];
    __shared__ float hsh[128][2];

    const float* Wi = WihT1 + (size_t)dir * 256 * 384;
    const float* Wh = WhhT1 + (size_t)dir * 128 * 384;
    const float bij = bih1[dir * 384 + j];
    const float bhj = bhh1[dir * 384 + j];

    // ---- gi phase: K = 256 (concat of both dirs' layer-0 outputs) ----
    float gi[3][2];
#pragma unroll
    for (int t = 0; t < 3; t++) { gi[t][0] = bij; gi[t][1] = bij; }
#pragma unroll 4
    for (int k = 0; k < 256; k += 4) {
        float w0 = Wi[(size_t)(k + 0) * 384 + j];
        float w1 = Wi[(size_t)(k + 1) * 384 + j];
        float w2 = Wi[(size_t)(k + 2) * 384 + j];
        float w3 = Wi[(size_t)(k + 3) * 384 + j];
#pragma unroll
        for (int t = 0; t < 3; t++)
#pragma unroll
            for (int nb = 0; nb < 2; nb++) {
                float4 x = *(const float4*)(y0g + ((size_t)t * Bb + b0 + nb) * 256 + k);
                gi[t][nb] += w0 * x.x + w1 * x.y + w2 * x.z + w3 * x.w;
            }
    }

    // ---- recurrence ----
    float h0[2] = {0.f, 0.f};
    float h1[2] = {0.f, 0.f};
#pragma unroll
    for (int step = 0; step < 3; step++) {
        float g0 = bhj, g1 = bhj;
        if (step > 0) {
#pragma unroll
            for (int k = 0; k < 64; k++) {
                float w = Wh[(size_t)k * 384 + j];
                g0 += w * __shfl(h0[0], k, 64);
                g1 += w * __shfl(h0[1], k, 64);
            }
#pragma unroll
            for (int k = 0; k < 64; k++) {
                float w = Wh[(size_t)(64 + k) * 384 + j];
                g0 += w * __shfl(h1[0], k, 64);
                g1 += w * __shfl(h1[1], k, 64);
            }
        }
        float gs0 = dir ? gi[2 - step][0] : gi[step][0];
        float gs1 = dir ? gi[2 - step][1] : gi[step][1];
        *(float2*)&gis[j][0] = make_float2(gs0, gs1);
        *(float2*)&ghs[j][0] = make_float2(g0, g1);
        __syncthreads();
        if (j < 128) {
#pragma unroll
            for (int nb = 0; nb < 2; nb++) {
                float r  = sigmoidf(gis[j][nb] + ghs[j][nb]);
                float z  = sigmoidf(gis[j + 128][nb] + ghs[j + 128][nb]);
                float nn = tanhf(gis[j + 256][nb] + r * ghs[j + 256][nb]);
                float hprev = (step == 0) ? 0.f : hsh[j][nb];
                float hnew = (1.f - z) * nn + z * hprev;
                hsh[j][nb] = hnew;
                if (step == 2)
                    atomicAdd(&out[(size_t)(b0 + nb) * Hh + j], 0.25f * hnew);
            }
        }
        __syncthreads();
        if (step < 2) {
            float2 a = *(const float2*)&hsh[L][0];
            float2 b = *(const float2*)&hsh[64 + L][0];
            h0[0] = a.x; h0[1] = a.y;
            h1[0] = b.x; h1[1] = b.y;
        }
    }
}

// ---------------------------------------------------------------------------
extern "C" void kernel_launch(void* const* d_in, const int* in_sizes, int n_in,
                              void* d_out, int out_size, void* d_ws, size_t ws_size,
                              hipStream_t stream) {
    const float* h      = (const float*)d_in[0];
    const int*   wid    = (const int*)d_in[1];
    const int*   src    = (const int*)d_in[2];
    const int*   dst    = (const int*)d_in[3];
    const int*   gid    = (const int*)d_in[4];
    const float* projW  = (const float*)d_in[5];
    const float* projB  = (const float*)d_in[6];
    const float* convWn = (const float*)d_in[7];
    const float* convBn = (const float*)d_in[8];
    const float* convAtt= (const float*)d_in[9];
    const float* convWs = (const float*)d_in[10];
    const float* convB  = (const float*)d_in[11];
    const float* convG  = (const float*)d_in[12];
    const float* convBe = (const float*)d_in[13];
    const float* Wih0   = (const float*)d_in[14];
    const float* Whh0   = (const float*)d_in[15];
    const float* bih0   = (const float*)d_in[16];
    const float* bhh0   = (const float*)d_in[17];
    const float* Wih1   = (const float*)d_in[18];
    const float* Whh1   = (const float*)d_in[19];
    const float* bih1   = (const float*)d_in[20];
    const float* bhh1   = (const float*)d_in[21];
    float* out = (float*)d_out;

    char* p = (char*)d_ws;
    auto align16 = [&]() { p = (char*)(((uintptr_t)p + 15) & ~(uintptr_t)15); };
    auto alloc_f = [&](size_t n) { align16(); float* r = (float*)p; p += n * sizeof(float); return r; };
    auto alloc_i = [&](size_t n) { align16(); int* r = (int*)p; p += n * sizeof(int); return r; };
    auto alloc_s = [&](size_t n) { align16(); unsigned short* r = (unsigned short*)p; p += n * sizeof(unsigned short); return r; };
    float* hcur  = alloc_f((size_t)Nn * 128);
    float* T     = alloc_f((size_t)Nn * 384);
    float* adbuf = alloc_f((size_t)Nn * 4);
    float* addbuf= alloc_f((size_t)Nn * 4);
    // contiguous zero region: reado | deg
    float* reado = alloc_f((size_t)3 * Bb * Hh);
    int* deg  = alloc_i(Nn);
    const size_t zero_bytes = (size_t)3 * Bb * Hh * sizeof(float) + Nn * sizeof(int);
    float* WihT0 = alloc_f((size_t)2 * 128 * 384);
    float* WhhT0 = alloc_f((size_t)2 * 128 * 384);
    float* WihT1 = alloc_f((size_t)2 * 256 * 384);
    float* WhhT1 = alloc_f((size_t)2 * 128 * 384);
    float* vavd  = alloc_f(1536);
    float* vc    = alloc_f(12);
    float* biasF = alloc_f(256);
    float* y0g   = alloc_f((size_t)3 * Bb * 256);   // layer-0 outputs [t][b][dir*128+j]
    int* offs = alloc_i(Nn + 1);
    int* cur  = alloc_i(Nn);
    int* csrc = alloc_i(Ee);
    int* goffs = alloc_i(Bb + 1);
    unsigned short* hb = alloc_s((size_t)Nn * 128);   // bf16 hcur plane
    unsigned short* pBth = alloc_s(128 * 128);
    unsigned short* pBtl = alloc_s(128 * 128);
    unsigned short* WfTh[2] = { alloc_s(128 * 384), alloc_s(128 * 384) };
    unsigned short* WfTl[2] = { alloc_s(128 * 384), alloc_s(128 * 384) };

    hipMemsetAsync(reado, 0, zero_bytes, stream);
    hipMemsetAsync(out, 0, (size_t)Bb * Hh * sizeof(float), stream);

    PrepArgs pa;
    pa.projW = projW + (size_t)Vv * Hh;
    pa.convWn = convWn; pa.convWs = convWs; pa.convAtt = convAtt;
    pa.convBn = convBn; pa.convB = convB;
    pa.Wih0 = Wih0; pa.Whh0 = Whh0; pa.Wih1 = Wih1; pa.Whh1 = Whh1;
    pa.gid = gid; pa.dst = dst;
    pa.pBth = pBth; pa.pBtl = pBtl;
    pa.WfTh0 = WfTh[0]; pa.WfTl0 = WfTl[0]; pa.WfTh1 = WfTh[1]; pa.WfTl1 = WfTl[1];
    pa.vavd = vavd; pa.vc = vc; pa.biasF = biasF;
    pa.WihT0 = WihT0; pa.WhhT0 = WhhT0; pa.WihT1 = WihT1; pa.WhhT1 = WhhT1;
    pa.goffs = goffs; pa.deg = deg;
    const int prep_total = 16384 + 2 * 49152 + 1536 + 12 + 256 + 98304 + 98304 + 196608 + 98304 + Nn + Ee;
    prep_all<<<(prep_total + 255) / 256, 256, 0, stream>>>(pa);

    scan_offsets<<<1, 1024, 0, stream>>>(deg, offs, cur);
    fill_csr<<<1250, 256, 0, stream>>>(dst, src, cur, csrc);

    // projection + dots L0 + hb + readout0
    {
        GArgs g = {};
        g.A = h; g.Bth = pBth; g.Btl = pBtl; g.bias = projB;
        g.M = Nn; g.K = 128;
        g.wid = wid; g.projW = projW; g.hcur = hcur;
        g.gid = gid; g.reado = reado;
        g.vavd = vavd; g.vc = vc; g.adf = adbuf; g.addf = addbuf; g.hb = hb;
        gemm_fused<0><<<dim3(1, Nn / 32), 256, 0, stream>>>(g);
    }

    const int nwaveblocks = (Nn * 64 + 255) / 256;   // 5000
    for (int l = 0; l < 2; l++) {
        gat_gather<<<nwaveblocks, 256, 0, stream>>>(hb, (const float4*)adbuf, (const float4*)addbuf,
                                                    offs, csrc, T);
        {
            GArgs g = {};
            g.A = T; g.Bth = WfTh[l]; g.Btl = WfTl[l]; g.bias = biasF + l * 128;
            g.M = Nn; g.K = 384;
            g.deg = deg; g.gamma = convG + l * Hh; g.beta = convBe + l * Hh;
            g.hcur = hcur;
            g.gid = gid; g.reado = reado + (size_t)(l + 1) * Bb * Hh;
            if (l == 0) { g.vavd = vavd + 768; g.vc = vc + 6; g.adf = adbuf; g.addf = addbuf; g.hb = hb; }
            gemm_fused<2><<<dim3(1, Nn / 32), 256, 0, stream>>>(g);
        }
    }

    gru_l0<<<dim3(Bb / 2, 2), 384, 0, stream>>>(reado, goffs, WihT0, WhhT0, bih0, bhh0,
                                                y0g, out);
    gru_l1<<<dim3(Bb / 2, 2), 384, 0, stream>>>(y0g, WihT1, WhhT1, bih1, bhh1, out);
}

// Round 3
// 408.230 us; speedup vs baseline: 1.4371x; 1.4371x over previous
//
#include <hip/hip_runtime.h>
#include <cstddef>
#include <cstdint>

// Problem constants (from reference)
static constexpr int Nn    = 20000;
static constexpr int Ee    = 320000;
static constexpr int Vv    = 100;
static constexpr int Hh    = 128;
static constexpr int HEADS = 3;
static constexpr int Bb    = 200;
static constexpr float NEG = 0.2f;
static constexpr float EPS = 1e-5f;

typedef short bf16x8 __attribute__((ext_vector_type(8)));
typedef float f32x4  __attribute__((ext_vector_type(4)));

__device__ inline unsigned short bf16_rne(float x) {
    unsigned u = __builtin_bit_cast(unsigned, x);
    u += 0x7FFFu + ((u >> 16) & 1u);
    return (unsigned short)(u >> 16);
}
__device__ inline float bf16_f(unsigned short h) {
    unsigned u = ((unsigned)h) << 16;
    return __builtin_bit_cast(float, u);
}
__device__ inline float bf_lo(unsigned u) { return __builtin_bit_cast(float, u << 16); }
__device__ inline float bf_hi(unsigned u) { return __builtin_bit_cast(float, u & 0xFFFF0000u); }
__device__ inline float lrelu(float a) { return a >= 0.f ? a : NEG * a; }
__device__ inline float sigmoidf(float x) { return 1.f / (1.f + __expf(-x)); }

// ---------------------------------------------------------------------------
// CSR scan + fill (hist lives in prep_all)
// ---------------------------------------------------------------------------
__global__ __launch_bounds__(1024) void scan_offsets(const int* __restrict__ deg,
                                                     int* __restrict__ offs,
                                                     int* __restrict__ cur) {
    __shared__ int sums[1024];
    const int tid = threadIdx.x;
    const int per = (Nn + 1023) >> 10;
    int begin = tid * per;
    int end = begin + per; if (end > Nn) end = Nn;
    if (begin > Nn) begin = Nn;
    int s = 0;
    for (int i = begin; i < end; i++) s += deg[i];
    sums[tid] = s;
    __syncthreads();
    for (int off = 1; off < 1024; off <<= 1) {
        int v = (tid >= off) ? sums[tid - off] : 0;
        __syncthreads();
        sums[tid] += v;
        __syncthreads();
    }
    int run = sums[tid] - s;
    for (int i = begin; i < end; i++) {
        offs[i] = run; cur[i] = run;
        run += deg[i];
    }
    if (end == Nn) offs[Nn] = run;
}

__global__ void fill_csr(const int* __restrict__ dst, const int* __restrict__ src,
                         int* __restrict__ cur, int* __restrict__ csrc) {
    for (int i = blockIdx.x * blockDim.x + threadIdx.x; i < Ee; i += gridDim.x * blockDim.x) {
        int p = atomicAdd(&cur[dst[i]], 1);
        csrc[p] = src[i];
    }
}

// ---------------------------------------------------------------------------
// Fused prep: projW split; Wfused = blockdiag(Wn)@Ws split-transposed;
// va/vd = Wn_h @ att halves; vc = bn_h . att halves; biasF = convB + bn@Ws;
// graph offsets; dst histogram. (GRU weights are used in their original
// row-major layout now -- no transposes.)
// ---------------------------------------------------------------------------
struct PrepArgs {
    const float *projW, *convWn, *convWs, *convAtt, *convBn, *convB;
    const int *gid, *dst;
    unsigned short *pBth, *pBtl;
    unsigned short *WfTh0, *WfTl0, *WfTh1, *WfTl1;
    float *vavd, *vc, *biasF;
    int *goffs, *deg;
};

__device__ inline void wsplit(const float* B, int K, int N, int idx,
                              unsigned short* Bth, unsigned short* Btl) {
    int k = idx / N, n = idx - k * N;
    float v = B[idx];
    unsigned short h = bf16_rne(v);
    unsigned short l = bf16_rne(v - bf16_f(h));
    Bth[(size_t)n * K + k] = h;
    Btl[(size_t)n * K + k] = l;
}

__global__ void prep_all(PrepArgs a) {
    int i = blockIdx.x * blockDim.x + threadIdx.x;
    if (i < 16384) { wsplit(a.projW, 128, 128, i, a.pBth, a.pBtl); return; } i -= 16384;
#pragma unroll
    for (int l = 0; l < 2; l++) {
        if (i < 49152) {
            int k = i >> 7, c = i & 127;
            int h = k >> 7, i_ = k & 127;
            const float* wn = a.convWn + (size_t)l * 49152 + (size_t)i_ * 384 + h * 128;
            const float* ws = a.convWs + (size_t)l * 49152 + (size_t)(h * 128) * 128 + c;
            float v = 0.f;
            for (int j = 0; j < 128; j++) v += wn[j] * ws[(size_t)j * 128];
            unsigned short hi = bf16_rne(v);
            unsigned short lo = bf16_rne(v - bf16_f(hi));
            unsigned short* th = l ? a.WfTh1 : a.WfTh0;
            unsigned short* tl = l ? a.WfTl1 : a.WfTl0;
            th[(size_t)c * 384 + k] = hi;
            tl[(size_t)c * 384 + k] = lo;
            return;
        }
        i -= 49152;
    }
    if (i < 1536) {
        int l = i / 768, r = i % 768;
        int sd = r / 384, rr = r % 384, h = rr >> 7, i_ = rr & 127;
        const float* wn = a.convWn + (size_t)l * 49152 + (size_t)i_ * 384 + h * 128;
        const float* at = a.convAtt + l * 768 + h * 256 + sd * 128;
        float v = 0.f;
        for (int j = 0; j < 128; j++) v += wn[j] * at[j];
        a.vavd[i] = v;
        return;
    } i -= 1536;
    if (i < 12) {
        int l = i / 6, r = i % 6, sd = r / 3, h = r % 3;
        const float* bn = a.convBn + l * 384 + h * 128;
        const float* at = a.convAtt + l * 768 + h * 256 + sd * 128;
        float v = 0.f;
        for (int j = 0; j < 128; j++) v += bn[j] * at[j];
        a.vc[i] = v;
        return;
    } i -= 12;
    if (i < 256) {
        int l = i >> 7, c = i & 127;
        const float* bn = a.convBn + l * 384;
        const float* ws = a.convWs + (size_t)l * 49152 + c;
        float v = a.convB[l * 128 + c];
        for (int k = 0; k < 384; k++) v += bn[k] * ws[(size_t)k * 128];
        a.biasF[i] = v;
        return;
    } i -= 256;
    if (i < Nn) {
        int g = a.gid[i];
        if (i == 0) { for (int b = 0; b <= g; b++) a.goffs[b] = 0; }
        else { int pg = a.gid[i - 1]; for (int b = pg + 1; b <= g; b++) a.goffs[b] = i; }
        if (i == Nn - 1) { for (int b = g + 1; b <= Bb; b++) a.goffs[b] = Nn; }
        return;
    } i -= Nn;
    if (i < Ee) atomicAdd(&a.deg[a.dst[i]], 1);
}

// ---------------------------------------------------------------------------
// Split-bf16 MFMA GEMM, BM=32, BN=128, BK=32; 256 threads = 4 waves (1x4),
// wave tile 32x32 (2x2 MFMA 16x16x32). Fused epilogues:
// MODE 0: proj: hcur = acc+bias+projW[wid]; MODE 2: residual+LN+ReLU.
// Both: fused per-graph readout; optional next-layer att dots (register-space,
// no LDS conflicts) + bf16 hcur plane.
// ---------------------------------------------------------------------------
struct GArgs {
    const float* A; const unsigned short* Bth; const unsigned short* Btl;
    const float* bias; int M, K;
    const int* wid; const float* projW;                 // MODE 0
    const int* deg; const float* gamma; const float* beta;  // MODE 2
    float* hcur;
    const int* gid; float* reado;
    const float* vavd; const float* vc;                 // null -> skip dots/hb
    float* adf; float* addf;
    unsigned short* hb;
};

template <int MODE>
__global__ __launch_bounds__(256) void gemm_fused(GArgs a) {
    __shared__ unsigned short As_hi[32][40];
    __shared__ unsigned short As_lo[32][40];
    __shared__ unsigned short Bs_hi[128][40];
    __shared__ unsigned short Bs_lo[128][40];
    __shared__ float ytile[32][132];
    __shared__ float sred[6][32][4];
    __shared__ int sgid[32];
    const int tid  = threadIdx.x;
    const int row0 = blockIdx.y * 32;
    const int wn   = tid >> 6;          // wave 0..3 along N
    const int L    = tid & 63;
    const int lrow = L & 15;
    const int lq   = L >> 4;
    const int K = a.K;

    f32x4 acc[2][2];
#pragma unroll
    for (int i = 0; i < 2; i++)
#pragma unroll
        for (int j = 0; j < 2; j++) acc[i][j] = (f32x4){0.f, 0.f, 0.f, 0.f};

    for (int kb = 0; kb < K; kb += 32) {
        {   // stage A 32x32
            int m  = tid >> 3;
            int kq = (tid & 7) * 4;
            float4 v = *(const float4*)(a.A + (size_t)(row0 + m) * K + kb + kq);
            unsigned short h0 = bf16_rne(v.x), h1 = bf16_rne(v.y),
                           h2 = bf16_rne(v.z), h3 = bf16_rne(v.w);
            *(short4*)&As_hi[m][kq] = make_short4((short)h0, (short)h1, (short)h2, (short)h3);
            *(short4*)&As_lo[m][kq] = make_short4((short)bf16_rne(v.x - bf16_f(h0)),
                                                  (short)bf16_rne(v.y - bf16_f(h1)),
                                                  (short)bf16_rne(v.z - bf16_f(h2)),
                                                  (short)bf16_rne(v.w - bf16_f(h3)));
        }
        {   // stage B^T 128x32
            int n  = tid >> 1;
            int kh = (tid & 1) * 16;
            const unsigned short* sh = a.Bth + (size_t)n * K + kb + kh;
            const unsigned short* sl = a.Btl + (size_t)n * K + kb + kh;
            *(float4*)&Bs_hi[n][kh]     = *(const float4*)sh;
            *(float4*)&Bs_hi[n][kh + 8] = *(const float4*)(sh + 8);
            *(float4*)&Bs_lo[n][kh]     = *(const float4*)sl;
            *(float4*)&Bs_lo[n][kh + 8] = *(const float4*)(sl + 8);
        }
        __syncthreads();
        bf16x8 ah[2], al[2], bh[2], bl[2];
#pragma unroll
        for (int mi = 0; mi < 2; mi++) {
            int r = mi * 16 + lrow;
            ah[mi] = *(const bf16x8*)&As_hi[r][lq * 8];
            al[mi] = *(const bf16x8*)&As_lo[r][lq * 8];
        }
#pragma unroll
        for (int ni = 0; ni < 2; ni++) {
            int r = wn * 32 + ni * 16 + lrow;
            bh[ni] = *(const bf16x8*)&Bs_hi[r][lq * 8];
            bl[ni] = *(const bf16x8*)&Bs_lo[r][lq * 8];
        }
#pragma unroll
        for (int mi = 0; mi < 2; mi++)
#pragma unroll
            for (int ni = 0; ni < 2; ni++) {
                acc[mi][ni] = __builtin_amdgcn_mfma_f32_16x16x32_bf16(ah[mi], bh[ni], acc[mi][ni], 0, 0, 0);
                acc[mi][ni] = __builtin_amdgcn_mfma_f32_16x16x32_bf16(ah[mi], bl[ni], acc[mi][ni], 0, 0, 0);
                acc[mi][ni] = __builtin_amdgcn_mfma_f32_16x16x32_bf16(al[mi], bh[ni], acc[mi][ni], 0, 0, 0);
            }
        __syncthreads();
    }

    // bias
#pragma unroll
    for (int ni = 0; ni < 2; ni++) {
        float bb = a.bias[wn * 32 + ni * 16 + lrow];
#pragma unroll
        for (int mi = 0; mi < 2; mi++)
#pragma unroll
            for (int r = 0; r < 4; r++) acc[mi][ni][r] += bb;
    }

    if constexpr (MODE == 0) {
        // acc := y = acc + projW[wid[row]]  (bias already in)
#pragma unroll
        for (int mi = 0; mi < 2; mi++)
#pragma unroll
            for (int r = 0; r < 4; r++) {
                int lr = mi * 16 + lq * 4 + r;
                int row = row0 + lr;
                int wi = a.wid[row];
#pragma unroll
                for (int ni = 0; ni < 2; ni++) {
                    int c = wn * 32 + ni * 16 + lrow;
                    float y = acc[mi][ni][r] + a.projW[(size_t)wi * 128 + c];
                    acc[mi][ni][r] = y;
                    a.hcur[(size_t)row * 128 + c] = y;
                    ytile[lr][c] = y;
                }
            }
    }

    if constexpr (MODE == 2) {
        __shared__ float red1[32][4], red2[32][4];
        float g4[2], be4[2];
#pragma unroll
        for (int ni = 0; ni < 2; ni++) {
            int c = wn * 32 + ni * 16 + lrow;
            g4[ni] = a.gamma[c]; be4[ni] = a.beta[c];
        }
#pragma unroll
        for (int mi = 0; mi < 2; mi++)
#pragma unroll
            for (int r = 0; r < 4; r++) {
                int lr = mi * 16 + lq * 4 + r;
                int row = row0 + lr;
                int dg = a.deg[row];
#pragma unroll
                for (int ni = 0; ni < 2; ni++) {
                    int c = wn * 32 + ni * 16 + lrow;
                    float hold = a.hcur[(size_t)row * 128 + c];
                    acc[mi][ni][r] = hold + (dg > 0 ? acc[mi][ni][r] : 0.f);
                }
            }
#pragma unroll
        for (int mi = 0; mi < 2; mi++)
#pragma unroll
            for (int r = 0; r < 4; r++) {
                float ps = acc[mi][0][r] + acc[mi][1][r];
#pragma unroll
                for (int o = 1; o < 16; o <<= 1) ps += __shfl_xor(ps, o, 64);
                if (lrow == 0) red1[mi * 16 + lq * 4 + r][wn] = ps;
            }
        __syncthreads();
#pragma unroll
        for (int mi = 0; mi < 2; mi++)
#pragma unroll
            for (int r = 0; r < 4; r++) {
                int lr = mi * 16 + lq * 4 + r;
                float mu = (red1[lr][0] + red1[lr][1] + red1[lr][2] + red1[lr][3]) * (1.f / 128.f);
                float qs = 0.f;
#pragma unroll
                for (int ni = 0; ni < 2; ni++) {
                    float dx = acc[mi][ni][r] - mu;
                    qs += dx * dx;
                }
#pragma unroll
                for (int o = 1; o < 16; o <<= 1) qs += __shfl_xor(qs, o, 64);
                if (lrow == 0) red2[lr][wn] = qs;
            }
        __syncthreads();
#pragma unroll
        for (int mi = 0; mi < 2; mi++)
#pragma unroll
            for (int r = 0; r < 4; r++) {
                int lr = mi * 16 + lq * 4 + r;
                int row = row0 + lr;
                float mu = (red1[lr][0] + red1[lr][1] + red1[lr][2] + red1[lr][3]) * (1.f / 128.f);
                float var = (red2[lr][0] + red2[lr][1] + red2[lr][2] + red2[lr][3]) * (1.f / 128.f);
                float rs = rsqrtf(var + EPS);
#pragma unroll
                for (int ni = 0; ni < 2; ni++) {
                    int c = wn * 32 + ni * 16 + lrow;
                    float y = fmaxf((acc[mi][ni][r] - mu) * rs * g4[ni] + be4[ni], 0.f);
                    acc[mi][ni][r] = y;
                    a.hcur[(size_t)row * 128 + c] = y;
                    ytile[lr][c] = y;
                }
            }
    }

    if (tid < 32) sgid[tid] = a.gid[row0 + tid];

    // ---- register-space attention dots (no ytile loop, no global v loop) ----
    const bool dots = (a.vavd != nullptr);
    if (dots) {
        float vv0[6], vv1[6];
#pragma unroll
        for (int d = 0; d < 6; d++) {
            vv0[d] = a.vavd[d * 128 + wn * 32 + lrow];
            vv1[d] = a.vavd[d * 128 + wn * 32 + 16 + lrow];
        }
#pragma unroll
        for (int d = 0; d < 6; d++) {
#pragma unroll
            for (int mi = 0; mi < 2; mi++)
#pragma unroll
                for (int r = 0; r < 4; r++) {
                    float ps = acc[mi][0][r] * vv0[d] + acc[mi][1][r] * vv1[d];
#pragma unroll
                    for (int o = 1; o < 16; o <<= 1) ps += __shfl_xor(ps, o, 64);
                    if (lrow == 0) sred[d][mi * 16 + lq * 4 + r][wn] = ps;
                }
        }
    }
    __syncthreads();

    // fused per-graph readout (gid sorted -> runs, atomic per run)
    {
        int j = tid & 127, hh = tid >> 7;
        float sum = 0.f; int curg = -1;
        for (int r = hh * 16; r < hh * 16 + 16; r++) {
            int g = sgid[r];
            if (g != curg) {
                if (curg >= 0) atomicAdd(&a.reado[(size_t)curg * 128 + j], sum);
                sum = 0.f; curg = g;
            }
            sum += ytile[r][j];
        }
        if (curg >= 0) atomicAdd(&a.reado[(size_t)curg * 128 + j], sum);
    }

    if (dots) {
        if (tid < 192) {
            int row = tid & 31, d = tid >> 5;     // d in [0,6)
            float s = sred[d][row][0] + sred[d][row][1] + sred[d][row][2] + sred[d][row][3]
                    + a.vc[d];
            int node = row0 + row;
            int sd = d / 3, h = d - sd * 3;
            float* dstp = sd ? a.addf : a.adf;
            dstp[(size_t)node * 4 + h] = s;
        }
        {   // bf16 hcur plane from ytile (<=2-way bank aliasing, free)
            int row = tid >> 3, c0 = (tid & 7) * 16;
            unsigned* dst = (unsigned*)(a.hb + (size_t)(row0 + row) * 128 + c0);
#pragma unroll
            for (int q = 0; q < 8; q++) {
                unsigned lo = bf16_rne(ytile[row][c0 + 2 * q]);
                unsigned hi = bf16_rne(ytile[row][c0 + 2 * q + 1]);
                dst[q] = lo | (hi << 16);
            }
        }
    }
}

// ---------------------------------------------------------------------------
// GAT gather: one wave per dst node, bf16 hcur rows (256B), scores from dots.
// ---------------------------------------------------------------------------
__global__ __launch_bounds__(256) void gat_gather(const unsigned short* __restrict__ hb,
                                                  const float4* __restrict__ ad,
                                                  const float4* __restrict__ add,
                                                  const int* __restrict__ offs,
                                                  const int* __restrict__ csrc,
                                                  float* __restrict__ T) {
    __shared__ float4 slot[4][64];
    const int n = (blockIdx.x * 256 + threadIdx.x) >> 6;
    const int wv_ = threadIdx.x >> 6;
    const int L = threadIdx.x & 63;
    if (n >= Nn) return;
    const int start = offs[n];
    const int deg = offs[n + 1] - start;
    float2* o2 = (float2*)(T + (size_t)n * 384);
    if (deg == 0) {
        float2 z = make_float2(0.f, 0.f);
        o2[L] = z; o2[64 + L] = z; o2[128 + L] = z;
        return;
    }
    const float4 adn = add[n];
    float2 t0 = make_float2(0.f, 0.f), t1 = t0, t2 = t0;

    if (deg <= 64) {
        int sn = 0; float e0 = 0.f, e1 = 0.f, e2 = 0.f;
        if (L < deg) {
            sn = csrc[start + L];
            float4 a4 = ad[sn];
            e0 = __expf(lrelu(a4.x + adn.x));
            e1 = __expf(lrelu(a4.y + adn.y));
            e2 = __expf(lrelu(a4.z + adn.z));
        }
        float s0 = e0, s1 = e1, s2 = e2;
#pragma unroll
        for (int o = 32; o > 0; o >>= 1) {
            s0 += __shfl_xor(s0, o, 64);
            s1 += __shfl_xor(s1, o, 64);
            s2 += __shfl_xor(s2, o, 64);
        }
        slot[wv_][L] = make_float4(__builtin_bit_cast(float, sn),
                                   e0 / s0, e1 / s1, e2 / s2);
        __builtin_amdgcn_wave_barrier();
#pragma unroll 2
        for (int j = 0; j < deg; j++) {
            float4 sc = slot[wv_][j];
            int s_n = __builtin_bit_cast(int, sc.x);
            unsigned u = ((const unsigned*)(hb + (size_t)s_n * 128))[L];
            float x0 = bf_lo(u), x1 = bf_hi(u);
            t0.x += sc.y * x0; t0.y += sc.y * x1;
            t1.x += sc.z * x0; t1.y += sc.z * x1;
            t2.x += sc.w * x0; t2.y += sc.w * x1;
        }
    } else {
        float s0 = 0.f, s1 = 0.f, s2 = 0.f;
        for (int i = L; i < deg; i += 64) {
            int sn = csrc[start + i];
            float4 a4 = ad[sn];
            s0 += __expf(lrelu(a4.x + adn.x));
            s1 += __expf(lrelu(a4.y + adn.y));
            s2 += __expf(lrelu(a4.z + adn.z));
        }
#pragma unroll
        for (int o = 32; o > 0; o >>= 1) {
            s0 += __shfl_xor(s0, o, 64);
            s1 += __shfl_xor(s1, o, 64);
            s2 += __shfl_xor(s2, o, 64);
        }
        float i0 = 1.f / s0, i1 = 1.f / s1, i2 = 1.f / s2;
        for (int base = 0; base < deg; base += 64) {
            int cnt = deg - base; if (cnt > 64) cnt = 64;
            if (L < cnt) {
                int sn = csrc[start + base + L];
                float4 a4 = ad[sn];
                slot[wv_][L] = make_float4(__builtin_bit_cast(float, sn),
                                           __expf(lrelu(a4.x + adn.x)) * i0,
                                           __expf(lrelu(a4.y + adn.y)) * i1,
                                           __expf(lrelu(a4.z + adn.z)) * i2);
            }
            __builtin_amdgcn_wave_barrier();
            for (int j = 0; j < cnt; j++) {
                float4 sc = slot[wv_][j];
                int s_n = __builtin_bit_cast(int, sc.x);
                unsigned u = ((const unsigned*)(hb + (size_t)s_n * 128))[L];
                float x0 = bf_lo(u), x1 = bf_hi(u);
                t0.x += sc.y * x0; t0.y += sc.y * x1;
                t1.x += sc.z * x0; t1.y += sc.z * x1;
                t2.x += sc.w * x0; t2.y += sc.w * x1;
            }
            __builtin_amdgcn_wave_barrier();
        }
    }
    o2[L] = t0; o2[64 + L] = t1; o2[128 + L] = t2;
}

// ---------------------------------------------------------------------------
// GRU v4: round-0's known-good per-thread shape (gi in 3 scalars, h in LDS,
// weights streamed), with exactly two fixes for its measured latency-bound
// counters (Occupancy 22%, 1 scalar load per FMA):
//  - dir-split kernels: grid (Bb, 2) = 400 blocks each (was 200) -> ~1.6
//    blocks/CU; layer boundary is the needed cross-dir sync.
//  - ORIGINAL row-major Wih/Whh layout: thread j reads its own contiguous
//    row W[j][k..k+3] as float4 -> 32 vector loads per dot (was 128 scalar).
//  - step 0 skips the h-dot (h == 0).
// No per-thread arrays, no big unroll windows -> no spill (round-1/2 lesson).
// ---------------------------------------------------------------------------
__global__ __launch_bounds__(384) void gru_l0(const float* __restrict__ reado,
                                              const int* __restrict__ goffs,
                                              const float* __restrict__ Wih,
                                              const float* __restrict__ Whh,
                                              const float* __restrict__ bih,
                                              const float* __restrict__ bhh,
                                              float* __restrict__ y0g,
                                              float* __restrict__ out) {
    const int dir = blockIdx.y;
    const int b = blockIdx.x;
    const int j = threadIdx.x;
    __shared__ float xs[3][128];
    __shared__ float hs[128];
    __shared__ float gil[384], ghl[384];

    const float invc = 1.f / fmaxf((float)(goffs[b + 1] - goffs[b]), 1.f);
    {
        int t = j >> 7, k = j & 127;
        xs[t][k] = reado[(size_t)t * Bb * Hh + (size_t)b * Hh + k] * invc;
    }
    if (j < 128) hs[j] = 0.f;
    __syncthreads();

    const float* Wi = Wih + ((size_t)dir * 384 + j) * 128;   // row j, contiguous
    const float* Wh = Whh + ((size_t)dir * 384 + j) * 128;
    const float bij = bih[dir * 384 + j];
    const float bhj = bhh[dir * 384 + j];

    float gi0 = bij, gi1 = bij, gi2 = bij;
#pragma unroll 4
    for (int k = 0; k < 128; k += 4) {
        float4 w  = *(const float4*)(Wi + k);
        float4 x0 = *(const float4*)&xs[0][k];
        float4 x1 = *(const float4*)&xs[1][k];
        float4 x2 = *(const float4*)&xs[2][k];
        gi0 += w.x * x0.x + w.y * x0.y + w.z * x0.z + w.w * x0.w;
        gi1 += w.x * x1.x + w.y * x1.y + w.z * x1.z + w.w * x1.w;
        gi2 += w.x * x2.x + w.y * x2.y + w.z * x2.z + w.w * x2.w;
    }

#pragma unroll
    for (int step = 0; step < 3; step++) {
        float g = bhj;
        if (step > 0) {
#pragma unroll 4
            for (int k = 0; k < 128; k += 4) {
                float4 w  = *(const float4*)(Wh + k);
                float4 hv = *(const float4*)&hs[k];
                g += w.x * hv.x + w.y * hv.y + w.z * hv.z + w.w * hv.w;
            }
        }
        ghl[j] = g;
        gil[j] = dir ? (step == 0 ? gi2 : (step == 1 ? gi1 : gi0))
                     : (step == 0 ? gi0 : (step == 1 ? gi1 : gi2));
        __syncthreads();
        if (j < 128) {
            const int t = dir ? 2 - step : step;
            float r  = sigmoidf(gil[j] + ghl[j]);
            float z  = sigmoidf(gil[j + 128] + ghl[j + 128]);
            float nn = tanhf(gil[j + 256] + r * ghl[j + 256]);
            float hnew = (1.f - z) * nn + z * hs[j];
            hs[j] = hnew;
            y0g[((size_t)t * Bb + b) * 256 + dir * 128 + j] = hnew;
            if (step == 2)
                atomicAdd(&out[(size_t)b * Hh + j], 0.25f * hnew);
        }
        __syncthreads();
    }
}

__global__ __launch_bounds__(384) void gru_l1(const float* __restrict__ y0g,
                                              const float* __restrict__ Wih,
                                              const float* __restrict__ Whh,
                                              const float* __restrict__ bih,
                                              const float* __restrict__ bhh,
                                              float* __restrict__ out) {
    const int dir = blockIdx.y;
    const int b = blockIdx.x;
    const int j = threadIdx.x;
    __shared__ float ys[3][256];
    __shared__ float hs[128];
    __shared__ float gil[384], ghl[384];

    for (int i = j; i < 3 * 256; i += 384) {
        int t = i >> 8, u = i & 255;
        ys[t][u] = y0g[((size_t)t * Bb + b) * 256 + u];
    }
    if (j < 128) hs[j] = 0.f;
    __syncthreads();

    const float* Wi = Wih + ((size_t)dir * 384 + j) * 256;   // row j, contiguous
    const float* Wh = Whh + ((size_t)dir * 384 + j) * 128;
    const float bij = bih[dir * 384 + j];
    const float bhj = bhh[dir * 384 + j];

    float gi0 = bij, gi1 = bij, gi2 = bij;
#pragma unroll 4
    for (int k = 0; k < 256; k += 4) {
        float4 w  = *(const float4*)(Wi + k);
        float4 x0 = *(const float4*)&ys[0][k];
        float4 x1 = *(const float4*)&ys[1][k];
        float4 x2 = *(const float4*)&ys[2][k];
        gi0 += w.x * x0.x + w.y * x0.y + w.z * x0.z + w.w * x0.w;
        gi1 += w.x * x1.x + w.y * x1.y + w.z * x1.z + w.w * x1.w;
        gi2 += w.x * x2.x + w.y * x2.y + w.z * x2.z + w.w * x2.w;
    }

#pragma unroll
    for (int step = 0; step < 3; step++) {
        float g = bhj;
        if (step > 0) {
#pragma unroll 4
            for (int k = 0; k < 128; k += 4) {
                float4 w  = *(const float4*)(Wh + k);
                float4 hv = *(const float4*)&hs[k];
                g += w.x * hv.x + w.y * hv.y + w.z * hv.z + w.w * hv.w;
            }
        }
        ghl[j] = g;
        gil[j] = dir ? (step == 0 ? gi2 : (step == 1 ? gi1 : gi0))
                     : (step == 0 ? gi0 : (step == 1 ? gi1 : gi2));
        __syncthreads();
        if (j < 128) {
            float r  = sigmoidf(gil[j] + ghl[j]);
            float z  = sigmoidf(gil[j + 128] + ghl[j + 128]);
            float nn = tanhf(gil[j + 256] + r * ghl[j + 256]);
            float hnew = (1.f - z) * nn + z * hs[j];
            hs[j] = hnew;
            if (step == 2)
                atomicAdd(&out[(size_t)b * Hh + j], 0.25f * hnew);
        }
        __syncthreads();
    }
}

// ---------------------------------------------------------------------------
extern "C" void kernel_launch(void* const* d_in, const int* in_sizes, int n_in,
                              void* d_out, int out_size, void* d_ws, size_t ws_size,
                              hipStream_t stream) {
    const float* h      = (const float*)d_in[0];
    const int*   wid    = (const int*)d_in[1];
    const int*   src    = (const int*)d_in[2];
    const int*   dst    = (const int*)d_in[3];
    const int*   gid    = (const int*)d_in[4];
    const float* projW  = (const float*)d_in[5];
    const float* projB  = (const float*)d_in[6];
    const float* convWn = (const float*)d_in[7];
    const float* convBn = (const float*)d_in[8];
    const float* convAtt= (const float*)d_in[9];
    const float* convWs = (const float*)d_in[10];
    const float* convB  = (const float*)d_in[11];
    const float* convG  = (const float*)d_in[12];
    const float* convBe = (const float*)d_in[13];
    const float* Wih0   = (const float*)d_in[14];
    const float* Whh0   = (const float*)d_in[15];
    const float* bih0   = (const float*)d_in[16];
    const float* bhh0   = (const float*)d_in[17];
    const float* Wih1   = (const float*)d_in[18];
    const float* Whh1   = (const float*)d_in[19];
    const float* bih1   = (const float*)d_in[20];
    const float* bhh1   = (const float*)d_in[21];
    float* out = (float*)d_out;

    char* p = (char*)d_ws;
    auto align16 = [&]() { p = (char*)(((uintptr_t)p + 15) & ~(uintptr_t)15); };
    auto alloc_f = [&](size_t n) { align16(); float* r = (float*)p; p += n * sizeof(float); return r; };
    auto alloc_i = [&](size_t n) { align16(); int* r = (int*)p; p += n * sizeof(int); return r; };
    auto alloc_s = [&](size_t n) { align16(); unsigned short* r = (unsigned short*)p; p += n * sizeof(unsigned short); return r; };
    float* hcur  = alloc_f((size_t)Nn * 128);
    float* T     = alloc_f((size_t)Nn * 384);
    float* adbuf = alloc_f((size_t)Nn * 4);
    float* addbuf= alloc_f((size_t)Nn * 4);
    // contiguous zero region: reado | deg
    float* reado = alloc_f((size_t)3 * Bb * Hh);
    int* deg  = alloc_i(Nn);
    const size_t zero_bytes = (size_t)3 * Bb * Hh * sizeof(float) + Nn * sizeof(int);
    float* vavd  = alloc_f(1536);
    float* vc    = alloc_f(12);
    float* biasF = alloc_f(256);
    float* y0g   = alloc_f((size_t)3 * Bb * 256);   // layer-0 outputs [t][b][dir*128+j]
    int* offs = alloc_i(Nn + 1);
    int* cur  = alloc_i(Nn);
    int* csrc = alloc_i(Ee);
    int* goffs = alloc_i(Bb + 1);
    unsigned short* hb = alloc_s((size_t)Nn * 128);   // bf16 hcur plane
    unsigned short* pBth = alloc_s(128 * 128);
    unsigned short* pBtl = alloc_s(128 * 128);
    unsigned short* WfTh[2] = { alloc_s(128 * 384), alloc_s(128 * 384) };
    unsigned short* WfTl[2] = { alloc_s(128 * 384), alloc_s(128 * 384) };

    hipMemsetAsync(reado, 0, zero_bytes, stream);
    hipMemsetAsync(out, 0, (size_t)Bb * Hh * sizeof(float), stream);

    PrepArgs pa;
    pa.projW = projW + (size_t)Vv * Hh;
    pa.convWn = convWn; pa.convWs = convWs; pa.convAtt = convAtt;
    pa.convBn = convBn; pa.convB = convB;
    pa.gid = gid; pa.dst = dst;
    pa.pBth = pBth; pa.pBtl = pBtl;
    pa.WfTh0 = WfTh[0]; pa.WfTl0 = WfTl[0]; pa.WfTh1 = WfTh[1]; pa.WfTl1 = WfTl[1];
    pa.vavd = vavd; pa.vc = vc; pa.biasF = biasF;
    pa.goffs = goffs; pa.deg = deg;
    const int prep_total = 16384 + 2 * 49152 + 1536 + 12 + 256 + Nn + Ee;
    prep_all<<<(prep_total + 255) / 256, 256, 0, stream>>>(pa);

    scan_offsets<<<1, 1024, 0, stream>>>(deg, offs, cur);
    fill_csr<<<1250, 256, 0, stream>>>(dst, src, cur, csrc);

    // projection + dots L0 + hb + readout0
    {
        GArgs g = {};
        g.A = h; g.Bth = pBth; g.Btl = pBtl; g.bias = projB;
        g.M = Nn; g.K = 128;
        g.wid = wid; g.projW = projW; g.hcur = hcur;
        g.gid = gid; g.reado = reado;
        g.vavd = vavd; g.vc = vc; g.adf = adbuf; g.addf = addbuf; g.hb = hb;
        gemm_fused<0><<<dim3(1, Nn / 32), 256, 0, stream>>>(g);
    }

    const int nwaveblocks = (Nn * 64 + 255) / 256;   // 5000
    for (int l = 0; l < 2; l++) {
        gat_gather<<<nwaveblocks, 256, 0, stream>>>(hb, (const float4*)adbuf, (const float4*)addbuf,
                                                    offs, csrc, T);
        {
            GArgs g = {};
            g.A = T; g.Bth = WfTh[l]; g.Btl = WfTl[l]; g.bias = biasF + l * 128;
            g.M = Nn; g.K = 384;
            g.deg = deg; g.gamma = convG + l * Hh; g.beta = convBe + l * Hh;
            g.hcur = hcur;
            g.gid = gid; g.reado = reado + (size_t)(l + 1) * Bb * Hh;
            if (l == 0) { g.vavd = vavd + 768; g.vc = vc + 6; g.adf = adbuf; g.addf = addbuf; g.hb = hb; }
            gemm_fused<2><<<dim3(1, Nn / 32), 256, 0, stream>>>(g);
        }
    }

    gru_l0<<<dim3(Bb, 2), 384, 0, stream>>>(reado, goffs, Wih0, Whh0, bih0, bhh0,
                                            y0g, out);
    gru_l1<<<dim3(Bb, 2), 384, 0, stream>>>(y0g, Wih1, Whh1, bih1, bhh1, out);
}

// Round 4
// 387.545 us; speedup vs baseline: 1.5138x; 1.0534x over previous
//
#include <hip/hip_runtime.h>
#include <cstddef>
#include <cstdint>

// Problem constants (from reference)
static constexpr int Nn    = 20000;
static constexpr int Ee    = 320000;
static constexpr int Vv    = 100;
static constexpr int Hh    = 128;
static constexpr int HEADS = 3;
static constexpr int Bb    = 200;
static constexpr float NEG = 0.2f;
static constexpr float EPS = 1e-5f;

typedef short bf16x8 __attribute__((ext_vector_type(8)));
typedef float f32x4  __attribute__((ext_vector_type(4)));

__device__ inline unsigned short bf16_rne(float x) {
    unsigned u = __builtin_bit_cast(unsigned, x);
    u += 0x7FFFu + ((u >> 16) & 1u);
    return (unsigned short)(u >> 16);
}
__device__ inline float bf16_f(unsigned short h) {
    unsigned u = ((unsigned)h) << 16;
    return __builtin_bit_cast(float, u);
}
__device__ inline float bf_lo(unsigned u) { return __builtin_bit_cast(float, u << 16); }
__device__ inline float bf_hi(unsigned u) { return __builtin_bit_cast(float, u & 0xFFFF0000u); }
__device__ inline float lrelu(float a) { return a >= 0.f ? a : NEG * a; }
__device__ inline float sigmoidf(float x) { return 1.f / (1.f + __expf(-x)); }

// ---------------------------------------------------------------------------
// CSR scan + fill (hist lives in prep_all)
// ---------------------------------------------------------------------------
__global__ __launch_bounds__(1024) void scan_offsets(const int* __restrict__ deg,
                                                     int* __restrict__ offs,
                                                     int* __restrict__ cur) {
    __shared__ int sums[1024];
    const int tid = threadIdx.x;
    const int per = (Nn + 1023) >> 10;
    int begin = tid * per;
    int end = begin + per; if (end > Nn) end = Nn;
    if (begin > Nn) begin = Nn;
    int s = 0;
    for (int i = begin; i < end; i++) s += deg[i];
    sums[tid] = s;
    __syncthreads();
    for (int off = 1; off < 1024; off <<= 1) {
        int v = (tid >= off) ? sums[tid - off] : 0;
        __syncthreads();
        sums[tid] += v;
        __syncthreads();
    }
    int run = sums[tid] - s;
    for (int i = begin; i < end; i++) {
        offs[i] = run; cur[i] = run;
        run += deg[i];
    }
    if (end == Nn) offs[Nn] = run;
}

__global__ void fill_csr(const int* __restrict__ dst, const int* __restrict__ src,
                         int* __restrict__ cur, int* __restrict__ csrc) {
    for (int i = blockIdx.x * blockDim.x + threadIdx.x; i < Ee; i += gridDim.x * blockDim.x) {
        int p = atomicAdd(&cur[dst[i]], 1);
        csrc[p] = src[i];
    }
}

// ---------------------------------------------------------------------------
// Fused prep: projW split; Wfused = blockdiag(Wn)@Ws split-transposed;
// va/vd = Wn_h @ att halves; vc = bn_h . att halves; biasF = convB + bn@Ws;
// GRU weight transposes (coalesced [k][j] layout); graph offsets; dst hist.
// ---------------------------------------------------------------------------
struct PrepArgs {
    const float *projW, *convWn, *convWs, *convAtt, *convBn, *convB;
    const float *Wih0, *Whh0, *Wih1, *Whh1;
    const int *gid, *dst;
    unsigned short *pBth, *pBtl;
    unsigned short *WfTh0, *WfTl0, *WfTh1, *WfTl1;
    float *vavd, *vc, *biasF;
    float *WihT0, *WhhT0, *WihT1, *WhhT1;
    int *goffs, *deg;
};

__device__ inline void wsplit(const float* B, int K, int N, int idx,
                              unsigned short* Bth, unsigned short* Btl) {
    int k = idx / N, n = idx - k * N;
    float v = B[idx];
    unsigned short h = bf16_rne(v);
    unsigned short l = bf16_rne(v - bf16_f(h));
    Bth[(size_t)n * K + k] = h;
    Btl[(size_t)n * K + k] = l;
}
__device__ inline void gruT(const float* W, int K, int idx, float* WT) {
    int d = idx / (384 * K);
    int r = idx - d * 384 * K;
    int j = r / K, k = r - j * K;
    WT[(size_t)d * K * 384 + (size_t)k * 384 + j] = W[idx];
}

__global__ void prep_all(PrepArgs a) {
    int i = blockIdx.x * blockDim.x + threadIdx.x;
    if (i < 16384) { wsplit(a.projW, 128, 128, i, a.pBth, a.pBtl); return; } i -= 16384;
#pragma unroll
    for (int l = 0; l < 2; l++) {
        if (i < 49152) {
            int k = i >> 7, c = i & 127;
            int h = k >> 7, i_ = k & 127;
            const float* wn = a.convWn + (size_t)l * 49152 + (size_t)i_ * 384 + h * 128;
            const float* ws = a.convWs + (size_t)l * 49152 + (size_t)(h * 128) * 128 + c;
            float v = 0.f;
            for (int j = 0; j < 128; j++) v += wn[j] * ws[(size_t)j * 128];
            unsigned short hi = bf16_rne(v);
            unsigned short lo = bf16_rne(v - bf16_f(hi));
            unsigned short* th = l ? a.WfTh1 : a.WfTh0;
            unsigned short* tl = l ? a.WfTl1 : a.WfTl0;
            th[(size_t)c * 384 + k] = hi;
            tl[(size_t)c * 384 + k] = lo;
            return;
        }
        i -= 49152;
    }
    if (i < 1536) {
        int l = i / 768, r = i % 768;
        int sd = r / 384, rr = r % 384, h = rr >> 7, i_ = rr & 127;
        const float* wn = a.convWn + (size_t)l * 49152 + (size_t)i_ * 384 + h * 128;
        const float* at = a.convAtt + l * 768 + h * 256 + sd * 128;
        float v = 0.f;
        for (int j = 0; j < 128; j++) v += wn[j] * at[j];
        a.vavd[i] = v;
        return;
    } i -= 1536;
    if (i < 12) {
        int l = i / 6, r = i % 6, sd = r / 3, h = r % 3;
        const float* bn = a.convBn + l * 384 + h * 128;
        const float* at = a.convAtt + l * 768 + h * 256 + sd * 128;
        float v = 0.f;
        for (int j = 0; j < 128; j++) v += bn[j] * at[j];
        a.vc[i] = v;
        return;
    } i -= 12;
    if (i < 256) {
        int l = i >> 7, c = i & 127;
        const float* bn = a.convBn + l * 384;
        const float* ws = a.convWs + (size_t)l * 49152 + c;
        float v = a.convB[l * 128 + c];
        for (int k = 0; k < 384; k++) v += bn[k] * ws[(size_t)k * 128];
        a.biasF[i] = v;
        return;
    } i -= 256;
    if (i < 98304)  { gruT(a.Wih0, 128, i, a.WihT0); return; }  i -= 98304;
    if (i < 98304)  { gruT(a.Whh0, 128, i, a.WhhT0); return; }  i -= 98304;
    if (i < 196608) { gruT(a.Wih1, 256, i, a.WihT1); return; }  i -= 196608;
    if (i < 98304)  { gruT(a.Whh1, 128, i, a.WhhT1); return; }  i -= 98304;
    if (i < Nn) {
        int g = a.gid[i];
        if (i == 0) { for (int b = 0; b <= g; b++) a.goffs[b] = 0; }
        else { int pg = a.gid[i - 1]; for (int b = pg + 1; b <= g; b++) a.goffs[b] = i; }
        if (i == Nn - 1) { for (int b = g + 1; b <= Bb; b++) a.goffs[b] = Nn; }
        return;
    } i -= Nn;
    if (i < Ee) atomicAdd(&a.deg[a.dst[i]], 1);
}

// ---------------------------------------------------------------------------
// Split-bf16 MFMA GEMM, BM=32, BN=128, BK=32; 256 threads = 4 waves (1x4),
// wave tile 32x32 (2x2 MFMA 16x16x32). Fused epilogues:
// MODE 0: proj: hcur = acc+bias+projW[wid]; MODE 2: residual+LN+ReLU.
// Both: fused per-graph readout; optional next-layer att dots (register-space,
// no LDS conflicts) + bf16 hcur plane.
// ---------------------------------------------------------------------------
struct GArgs {
    const float* A; const unsigned short* Bth; const unsigned short* Btl;
    const float* bias; int M, K;
    const int* wid; const float* projW;                 // MODE 0
    const int* deg; const float* gamma; const float* beta;  // MODE 2
    float* hcur;
    const int* gid; float* reado;
    const float* vavd; const float* vc;                 // null -> skip dots/hb
    float* adf; float* addf;
    unsigned short* hb;
};

template <int MODE>
__global__ __launch_bounds__(256) void gemm_fused(GArgs a) {
    __shared__ unsigned short As_hi[32][40];
    __shared__ unsigned short As_lo[32][40];
    __shared__ unsigned short Bs_hi[128][40];
    __shared__ unsigned short Bs_lo[128][40];
    __shared__ float ytile[32][132];
    __shared__ float sred[6][32][4];
    __shared__ int sgid[32];
    const int tid  = threadIdx.x;
    const int row0 = blockIdx.y * 32;
    const int wn   = tid >> 6;          // wave 0..3 along N
    const int L    = tid & 63;
    const int lrow = L & 15;
    const int lq   = L >> 4;
    const int K = a.K;

    f32x4 acc[2][2];
#pragma unroll
    for (int i = 0; i < 2; i++)
#pragma unroll
        for (int j = 0; j < 2; j++) acc[i][j] = (f32x4){0.f, 0.f, 0.f, 0.f};

    for (int kb = 0; kb < K; kb += 32) {
        {   // stage A 32x32
            int m  = tid >> 3;
            int kq = (tid & 7) * 4;
            float4 v = *(const float4*)(a.A + (size_t)(row0 + m) * K + kb + kq);
            unsigned short h0 = bf16_rne(v.x), h1 = bf16_rne(v.y),
                           h2 = bf16_rne(v.z), h3 = bf16_rne(v.w);
            *(short4*)&As_hi[m][kq] = make_short4((short)h0, (short)h1, (short)h2, (short)h3);
            *(short4*)&As_lo[m][kq] = make_short4((short)bf16_rne(v.x - bf16_f(h0)),
                                                  (short)bf16_rne(v.y - bf16_f(h1)),
                                                  (short)bf16_rne(v.z - bf16_f(h2)),
                                                  (short)bf16_rne(v.w - bf16_f(h3)));
        }
        {   // stage B^T 128x32
            int n  = tid >> 1;
            int kh = (tid & 1) * 16;
            const unsigned short* sh = a.Bth + (size_t)n * K + kb + kh;
            const unsigned short* sl = a.Btl + (size_t)n * K + kb + kh;
            *(float4*)&Bs_hi[n][kh]     = *(const float4*)sh;
            *(float4*)&Bs_hi[n][kh + 8] = *(const float4*)(sh + 8);
            *(float4*)&Bs_lo[n][kh]     = *(const float4*)sl;
            *(float4*)&Bs_lo[n][kh + 8] = *(const float4*)(sl + 8);
        }
        __syncthreads();
        bf16x8 ah[2], al[2], bh[2], bl[2];
#pragma unroll
        for (int mi = 0; mi < 2; mi++) {
            int r = mi * 16 + lrow;
            ah[mi] = *(const bf16x8*)&As_hi[r][lq * 8];
            al[mi] = *(const bf16x8*)&As_lo[r][lq * 8];
        }
#pragma unroll
        for (int ni = 0; ni < 2; ni++) {
            int r = wn * 32 + ni * 16 + lrow;
            bh[ni] = *(const bf16x8*)&Bs_hi[r][lq * 8];
            bl[ni] = *(const bf16x8*)&Bs_lo[r][lq * 8];
        }
#pragma unroll
        for (int mi = 0; mi < 2; mi++)
#pragma unroll
            for (int ni = 0; ni < 2; ni++) {
                acc[mi][ni] = __builtin_amdgcn_mfma_f32_16x16x32_bf16(ah[mi], bh[ni], acc[mi][ni], 0, 0, 0);
                acc[mi][ni] = __builtin_amdgcn_mfma_f32_16x16x32_bf16(ah[mi], bl[ni], acc[mi][ni], 0, 0, 0);
                acc[mi][ni] = __builtin_amdgcn_mfma_f32_16x16x32_bf16(al[mi], bh[ni], acc[mi][ni], 0, 0, 0);
            }
        __syncthreads();
    }

    // bias
#pragma unroll
    for (int ni = 0; ni < 2; ni++) {
        float bb = a.bias[wn * 32 + ni * 16 + lrow];
#pragma unroll
        for (int mi = 0; mi < 2; mi++)
#pragma unroll
            for (int r = 0; r < 4; r++) acc[mi][ni][r] += bb;
    }

    if constexpr (MODE == 0) {
        // acc := y = acc + projW[wid[row]]  (bias already in)
#pragma unroll
        for (int mi = 0; mi < 2; mi++)
#pragma unroll
            for (int r = 0; r < 4; r++) {
                int lr = mi * 16 + lq * 4 + r;
                int row = row0 + lr;
                int wi = a.wid[row];
#pragma unroll
                for (int ni = 0; ni < 2; ni++) {
                    int c = wn * 32 + ni * 16 + lrow;
                    float y = acc[mi][ni][r] + a.projW[(size_t)wi * 128 + c];
                    acc[mi][ni][r] = y;
                    a.hcur[(size_t)row * 128 + c] = y;
                    ytile[lr][c] = y;
                }
            }
    }

    if constexpr (MODE == 2) {
        __shared__ float red1[32][4], red2[32][4];
        float g4[2], be4[2];
#pragma unroll
        for (int ni = 0; ni < 2; ni++) {
            int c = wn * 32 + ni * 16 + lrow;
            g4[ni] = a.gamma[c]; be4[ni] = a.beta[c];
        }
#pragma unroll
        for (int mi = 0; mi < 2; mi++)
#pragma unroll
            for (int r = 0; r < 4; r++) {
                int lr = mi * 16 + lq * 4 + r;
                int row = row0 + lr;
                int dg = a.deg[row];
#pragma unroll
                for (int ni = 0; ni < 2; ni++) {
                    int c = wn * 32 + ni * 16 + lrow;
                    float hold = a.hcur[(size_t)row * 128 + c];
                    acc[mi][ni][r] = hold + (dg > 0 ? acc[mi][ni][r] : 0.f);
                }
            }
#pragma unroll
        for (int mi = 0; mi < 2; mi++)
#pragma unroll
            for (int r = 0; r < 4; r++) {
                float ps = acc[mi][0][r] + acc[mi][1][r];
#pragma unroll
                for (int o = 1; o < 16; o <<= 1) ps += __shfl_xor(ps, o, 64);
                if (lrow == 0) red1[mi * 16 + lq * 4 + r][wn] = ps;
            }
        __syncthreads();
#pragma unroll
        for (int mi = 0; mi < 2; mi++)
#pragma unroll
            for (int r = 0; r < 4; r++) {
                int lr = mi * 16 + lq * 4 + r;
                float mu = (red1[lr][0] + red1[lr][1] + red1[lr][2] + red1[lr][3]) * (1.f / 128.f);
                float qs = 0.f;
#pragma unroll
                for (int ni = 0; ni < 2; ni++) {
                    float dx = acc[mi][ni][r] - mu;
                    qs += dx * dx;
                }
#pragma unroll
                for (int o = 1; o < 16; o <<= 1) qs += __shfl_xor(qs, o, 64);
                if (lrow == 0) red2[lr][wn] = qs;
            }
        __syncthreads();
#pragma unroll
        for (int mi = 0; mi < 2; mi++)
#pragma unroll
            for (int r = 0; r < 4; r++) {
                int lr = mi * 16 + lq * 4 + r;
                int row = row0 + lr;
                float mu = (red1[lr][0] + red1[lr][1] + red1[lr][2] + red1[lr][3]) * (1.f / 128.f);
                float var = (red2[lr][0] + red2[lr][1] + red2[lr][2] + red2[lr][3]) * (1.f / 128.f);
                float rs = rsqrtf(var + EPS);
#pragma unroll
                for (int ni = 0; ni < 2; ni++) {
                    int c = wn * 32 + ni * 16 + lrow;
                    float y = fmaxf((acc[mi][ni][r] - mu) * rs * g4[ni] + be4[ni], 0.f);
                    acc[mi][ni][r] = y;
                    a.hcur[(size_t)row * 128 + c] = y;
                    ytile[lr][c] = y;
                }
            }
    }

    if (tid < 32) sgid[tid] = a.gid[row0 + tid];

    // ---- register-space attention dots (no ytile loop, no global v loop) ----
    const bool dots = (a.vavd != nullptr);
    if (dots) {
        float vv0[6], vv1[6];
#pragma unroll
        for (int d = 0; d < 6; d++) {
            vv0[d] = a.vavd[d * 128 + wn * 32 + lrow];
            vv1[d] = a.vavd[d * 128 + wn * 32 + 16 + lrow];
        }
#pragma unroll
        for (int d = 0; d < 6; d++) {
#pragma unroll
            for (int mi = 0; mi < 2; mi++)
#pragma unroll
                for (int r = 0; r < 4; r++) {
                    float ps = acc[mi][0][r] * vv0[d] + acc[mi][1][r] * vv1[d];
#pragma unroll
                    for (int o = 1; o < 16; o <<= 1) ps += __shfl_xor(ps, o, 64);
                    if (lrow == 0) sred[d][mi * 16 + lq * 4 + r][wn] = ps;
                }
        }
    }
    __syncthreads();

    // fused per-graph readout (gid sorted -> runs, atomic per run)
    {
        int j = tid & 127, hh = tid >> 7;
        float sum = 0.f; int curg = -1;
        for (int r = hh * 16; r < hh * 16 + 16; r++) {
            int g = sgid[r];
            if (g != curg) {
                if (curg >= 0) atomicAdd(&a.reado[(size_t)curg * 128 + j], sum);
                sum = 0.f; curg = g;
            }
            sum += ytile[r][j];
        }
        if (curg >= 0) atomicAdd(&a.reado[(size_t)curg * 128 + j], sum);
    }

    if (dots) {
        if (tid < 192) {
            int row = tid & 31, d = tid >> 5;     // d in [0,6)
            float s = sred[d][row][0] + sred[d][row][1] + sred[d][row][2] + sred[d][row][3]
                    + a.vc[d];
            int node = row0 + row;
            int sd = d / 3, h = d - sd * 3;
            float* dstp = sd ? a.addf : a.adf;
            dstp[(size_t)node * 4 + h] = s;
        }
        {   // bf16 hcur plane from ytile (<=2-way bank aliasing, free)
            int row = tid >> 3, c0 = (tid & 7) * 16;
            unsigned* dst = (unsigned*)(a.hb + (size_t)(row0 + row) * 128 + c0);
#pragma unroll
            for (int q = 0; q < 8; q++) {
                unsigned lo = bf16_rne(ytile[row][c0 + 2 * q]);
                unsigned hi = bf16_rne(ytile[row][c0 + 2 * q + 1]);
                dst[q] = lo | (hi << 16);
            }
        }
    }
}

// ---------------------------------------------------------------------------
// GAT gather: one wave per dst node, bf16 hcur rows (256B), scores from dots.
// ---------------------------------------------------------------------------
__global__ __launch_bounds__(256) void gat_gather(const unsigned short* __restrict__ hb,
                                                  const float4* __restrict__ ad,
                                                  const float4* __restrict__ add,
                                                  const int* __restrict__ offs,
                                                  const int* __restrict__ csrc,
                                                  float* __restrict__ T) {
    __shared__ float4 slot[4][64];
    const int n = (blockIdx.x * 256 + threadIdx.x) >> 6;
    const int wv_ = threadIdx.x >> 6;
    const int L = threadIdx.x & 63;
    if (n >= Nn) return;
    const int start = offs[n];
    const int deg = offs[n + 1] - start;
    float2* o2 = (float2*)(T + (size_t)n * 384);
    if (deg == 0) {
        float2 z = make_float2(0.f, 0.f);
        o2[L] = z; o2[64 + L] = z; o2[128 + L] = z;
        return;
    }
    const float4 adn = add[n];
    float2 t0 = make_float2(0.f, 0.f), t1 = t0, t2 = t0;

    if (deg <= 64) {
        int sn = 0; float e0 = 0.f, e1 = 0.f, e2 = 0.f;
        if (L < deg) {
            sn = csrc[start + L];
            float4 a4 = ad[sn];
            e0 = __expf(lrelu(a4.x + adn.x));
            e1 = __expf(lrelu(a4.y + adn.y));
            e2 = __expf(lrelu(a4.z + adn.z));
        }
        float s0 = e0, s1 = e1, s2 = e2;
#pragma unroll
        for (int o = 32; o > 0; o >>= 1) {
            s0 += __shfl_xor(s0, o, 64);
            s1 += __shfl_xor(s1, o, 64);
            s2 += __shfl_xor(s2, o, 64);
        }
        slot[wv_][L] = make_float4(__builtin_bit_cast(float, sn),
                                   e0 / s0, e1 / s1, e2 / s2);
        __builtin_amdgcn_wave_barrier();
#pragma unroll 2
        for (int j = 0; j < deg; j++) {
            float4 sc = slot[wv_][j];
            int s_n = __builtin_bit_cast(int, sc.x);
            unsigned u = ((const unsigned*)(hb + (size_t)s_n * 128))[L];
            float x0 = bf_lo(u), x1 = bf_hi(u);
            t0.x += sc.y * x0; t0.y += sc.y * x1;
            t1.x += sc.z * x0; t1.y += sc.z * x1;
            t2.x += sc.w * x0; t2.y += sc.w * x1;
        }
    } else {
        float s0 = 0.f, s1 = 0.f, s2 = 0.f;
        for (int i = L; i < deg; i += 64) {
            int sn = csrc[start + i];
            float4 a4 = ad[sn];
            s0 += __expf(lrelu(a4.x + adn.x));
            s1 += __expf(lrelu(a4.y + adn.y));
            s2 += __expf(lrelu(a4.z + adn.z));
        }
#pragma unroll
        for (int o = 32; o > 0; o >>= 1) {
            s0 += __shfl_xor(s0, o, 64);
            s1 += __shfl_xor(s1, o, 64);
            s2 += __shfl_xor(s2, o, 64);
        }
        float i0 = 1.f / s0, i1 = 1.f / s1, i2 = 1.f / s2;
        for (int base = 0; base < deg; base += 64) {
            int cnt = deg - base; if (cnt > 64) cnt = 64;
            if (L < cnt) {
                int sn = csrc[start + base + L];
                float4 a4 = ad[sn];
                slot[wv_][L] = make_float4(__builtin_bit_cast(float, sn),
                                           __expf(lrelu(a4.x + adn.x)) * i0,
                                           __expf(lrelu(a4.y + adn.y)) * i1,
                                           __expf(lrelu(a4.z + adn.z)) * i2);
            }
            __builtin_amdgcn_wave_barrier();
            for (int j = 0; j < cnt; j++) {
                float4 sc = slot[wv_][j];
                int s_n = __builtin_bit_cast(int, sc.x);
                unsigned u = ((const unsigned*)(hb + (size_t)s_n * 128))[L];
                float x0 = bf_lo(u), x1 = bf_hi(u);
                t0.x += sc.y * x0; t0.y += sc.y * x1;
                t1.x += sc.z * x0; t1.y += sc.z * x1;
                t2.x += sc.w * x0; t2.y += sc.w * x1;
            }
            __builtin_amdgcn_wave_barrier();
        }
    }
    o2[L] = t0; o2[64 + L] = t1; o2[128 + L] = t2;
}

// ---------------------------------------------------------------------------
// GRU v5: round-0's proven per-thread shape (coalesced transposed weights,
// h in LDS, weights streamed from L2 -- NO register weight cache, the r1/r2
// spill cause), with the two safe levers:
//  - GNB=2 batch elems per block: halves weight traffic (710 -> ~350 MB).
//  - layer-split kernels + dir-split blocks: grid (Bb/2, 2) = 200 blocks
//    x 384 threads per kernel.
// LDS broadcasts packed as float2 over nb. Per-thread state: 6 gi scalars.
// ---------------------------------------------------------------------------
__global__ __launch_bounds__(384) void gru_l0(const float* __restrict__ reado,
                                              const int* __restrict__ goffs,
                                              const float* __restrict__ WihT,
                                              const float* __restrict__ WhhT,
                                              const float* __restrict__ bih,
                                              const float* __restrict__ bhh,
                                              float* __restrict__ y0g,
                                              float* __restrict__ out) {
    const int dir = blockIdx.y;
    const int b0 = blockIdx.x * 2;
    const int j = threadIdx.x;
    __shared__ float xs[3][128][2];
    __shared__ float hsh[128][2];
    __shared__ float gis[384][2];
    __shared__ float ghs[384][2];

    const int cg0 = goffs[b0], cg1 = goffs[b0 + 1], cg2 = goffs[b0 + 2];
    const float invc0 = 1.f / fmaxf((float)(cg1 - cg0), 1.f);
    const float invc1 = 1.f / fmaxf((float)(cg2 - cg1), 1.f);

    for (int i = j; i < 768; i += 384) {
        int nb = i & 1, k = (i >> 1) & 127, t = i >> 8;
        xs[t][k][nb] = reado[(size_t)t * (Bb * Hh) + (size_t)(b0 + nb) * Hh + k];
    }
    if (j < 128) { hsh[j][0] = 0.f; hsh[j][1] = 0.f; }
    __syncthreads();

    const float* Wi = WihT + (size_t)dir * 128 * 384 + j;   // [k][j] coalesced
    const float* Wh = WhhT + (size_t)dir * 128 * 384 + j;
    const float bij = bih[dir * 384 + j];
    const float bhj = bhh[dir * 384 + j];

    float gi00 = 0.f, gi01 = 0.f, gi10 = 0.f, gi11 = 0.f, gi20 = 0.f, gi21 = 0.f;
#pragma unroll 4
    for (int k = 0; k < 128; k++) {
        float w = Wi[(size_t)k * 384];
        float2 x0 = *(const float2*)&xs[0][k][0];
        float2 x1 = *(const float2*)&xs[1][k][0];
        float2 x2 = *(const float2*)&xs[2][k][0];
        gi00 += w * x0.x; gi01 += w * x0.y;
        gi10 += w * x1.x; gi11 += w * x1.y;
        gi20 += w * x2.x; gi21 += w * x2.y;
    }
    gi00 = gi00 * invc0 + bij; gi01 = gi01 * invc1 + bij;
    gi10 = gi10 * invc0 + bij; gi11 = gi11 * invc1 + bij;
    gi20 = gi20 * invc0 + bij; gi21 = gi21 * invc1 + bij;

#pragma unroll
    for (int step = 0; step < 3; step++) {
        float g0 = bhj, g1 = bhj;
        if (step > 0) {
#pragma unroll 4
            for (int k = 0; k < 128; k++) {
                float w = Wh[(size_t)k * 384];
                float2 hv = *(const float2*)&hsh[k][0];
                g0 += w * hv.x; g1 += w * hv.y;
            }
        }
        float gs0, gs1;
        if (dir) { gs0 = (step == 0 ? gi20 : (step == 1 ? gi10 : gi00));
                   gs1 = (step == 0 ? gi21 : (step == 1 ? gi11 : gi01)); }
        else     { gs0 = (step == 0 ? gi00 : (step == 1 ? gi10 : gi20));
                   gs1 = (step == 0 ? gi01 : (step == 1 ? gi11 : gi21)); }
        gis[j][0] = gs0; gis[j][1] = gs1;
        ghs[j][0] = g0;  ghs[j][1] = g1;
        __syncthreads();
        if (j < 128) {
            const int t = dir ? 2 - step : step;
#pragma unroll
            for (int nb = 0; nb < 2; nb++) {
                float r  = sigmoidf(gis[j][nb] + ghs[j][nb]);
                float z  = sigmoidf(gis[j + 128][nb] + ghs[j + 128][nb]);
                float nn = tanhf(gis[j + 256][nb] + r * ghs[j + 256][nb]);
                float hnew = (1.f - z) * nn + z * hsh[j][nb];
                hsh[j][nb] = hnew;
                y0g[((size_t)t * Bb + (b0 + nb)) * 256 + dir * 128 + j] = hnew;
                if (step == 2)
                    atomicAdd(&out[(size_t)(b0 + nb) * Hh + j], 0.25f * hnew);
            }
        }
        __syncthreads();
    }
}

__global__ __launch_bounds__(384) void gru_l1(const float* __restrict__ y0g,
                                              const float* __restrict__ WihT,
                                              const float* __restrict__ WhhT,
                                              const float* __restrict__ bih,
                                              const float* __restrict__ bhh,
                                              float* __restrict__ out) {
    const int dir = blockIdx.y;
    const int b0 = blockIdx.x * 2;
    const int j = threadIdx.x;
    __shared__ float ys[3][256][2];
    __shared__ float hsh[128][2];
    __shared__ float gis[384][2];
    __shared__ float ghs[384][2];

    for (int i = j; i < 1536; i += 384) {
        int nb = i & 1, k = (i >> 1) & 255, t = i >> 9;
        ys[t][k][nb] = y0g[((size_t)t * Bb + (b0 + nb)) * 256 + k];
    }
    if (j < 128) { hsh[j][0] = 0.f; hsh[j][1] = 0.f; }
    __syncthreads();

    const float* Wi = WihT + (size_t)dir * 256 * 384 + j;   // [k][j] coalesced
    const float* Wh = WhhT + (size_t)dir * 128 * 384 + j;
    const float bij = bih[dir * 384 + j];
    const float bhj = bhh[dir * 384 + j];

    float gi00 = bij, gi01 = bij, gi10 = bij, gi11 = bij, gi20 = bij, gi21 = bij;
#pragma unroll 4
    for (int k = 0; k < 256; k++) {
        float w = Wi[(size_t)k * 384];
        float2 x0 = *(const float2*)&ys[0][k][0];
        float2 x1 = *(const float2*)&ys[1][k][0];
        float2 x2 = *(const float2*)&ys[2][k][0];
        gi00 += w * x0.x; gi01 += w * x0.y;
        gi10 += w * x1.x; gi11 += w * x1.y;
        gi20 += w * x2.x; gi21 += w * x2.y;
    }

#pragma unroll
    for (int step = 0; step < 3; step++) {
        float g0 = bhj, g1 = bhj;
        if (step > 0) {
#pragma unroll 4
            for (int k = 0; k < 128; k++) {
                float w = Wh[(size_t)k * 384];
                float2 hv = *(const float2*)&hsh[k][0];
                g0 += w * hv.x; g1 += w * hv.y;
            }
        }
        float gs0, gs1;
        if (dir) { gs0 = (step == 0 ? gi20 : (step == 1 ? gi10 : gi00));
                   gs1 = (step == 0 ? gi21 : (step == 1 ? gi11 : gi01)); }
        else     { gs0 = (step == 0 ? gi00 : (step == 1 ? gi10 : gi20));
                   gs1 = (step == 0 ? gi01 : (step == 1 ? gi11 : gi21)); }
        gis[j][0] = gs0; gis[j][1] = gs1;
        ghs[j][0] = g0;  ghs[j][1] = g1;
        __syncthreads();
        if (j < 128) {
#pragma unroll
            for (int nb = 0; nb < 2; nb++) {
                float r  = sigmoidf(gis[j][nb] + ghs[j][nb]);
                float z  = sigmoidf(gis[j + 128][nb] + ghs[j + 128][nb]);
                float nn = tanhf(gis[j + 256][nb] + r * ghs[j + 256][nb]);
                float hnew = (1.f - z) * nn + z * hsh[j][nb];
                hsh[j][nb] = hnew;
                if (step == 2)
                    atomicAdd(&out[(size_t)(b0 + nb) * Hh + j], 0.25f * hnew);
            }
        }
        __syncthreads();
    }
}

// ---------------------------------------------------------------------------
extern "C" void kernel_launch(void* const* d_in, const int* in_sizes, int n_in,
                              void* d_out, int out_size, void* d_ws, size_t ws_size,
                              hipStream_t stream) {
    const float* h      = (const float*)d_in[0];
    const int*   wid    = (const int*)d_in[1];
    const int*   src    = (const int*)d_in[2];
    const int*   dst    = (const int*)d_in[3];
    const int*   gid    = (const int*)d_in[4];
    const float* projW  = (const float*)d_in[5];
    const float* projB  = (const float*)d_in[6];
    const float* convWn = (const float*)d_in[7];
    const float* convBn = (const float*)d_in[8];
    const float* convAtt= (const float*)d_in[9];
    const float* convWs = (const float*)d_in[10];
    const float* convB  = (const float*)d_in[11];
    const float* convG  = (const float*)d_in[12];
    const float* convBe = (const float*)d_in[13];
    const float* Wih0   = (const float*)d_in[14];
    const float* Whh0   = (const float*)d_in[15];
    const float* bih0   = (const float*)d_in[16];
    const float* bhh0   = (const float*)d_in[17];
    const float* Wih1   = (const float*)d_in[18];
    const float* Whh1   = (const float*)d_in[19];
    const float* bih1   = (const float*)d_in[20];
    const float* bhh1   = (const float*)d_in[21];
    float* out = (float*)d_out;

    char* p = (char*)d_ws;
    auto align16 = [&]() { p = (char*)(((uintptr_t)p + 15) & ~(uintptr_t)15); };
    auto alloc_f = [&](size_t n) { align16(); float* r = (float*)p; p += n * sizeof(float); return r; };
    auto alloc_i = [&](size_t n) { align16(); int* r = (int*)p; p += n * sizeof(int); return r; };
    auto alloc_s = [&](size_t n) { align16(); unsigned short* r = (unsigned short*)p; p += n * sizeof(unsigned short); return r; };
    float* hcur  = alloc_f((size_t)Nn * 128);
    float* T     = alloc_f((size_t)Nn * 384);
    float* adbuf = alloc_f((size_t)Nn * 4);
    float* addbuf= alloc_f((size_t)Nn * 4);
    // contiguous zero region: reado | deg
    float* reado = alloc_f((size_t)3 * Bb * Hh);
    int* deg  = alloc_i(Nn);
    const size_t zero_bytes = (size_t)3 * Bb * Hh * sizeof(float) + Nn * sizeof(int);
    float* WihT0 = alloc_f((size_t)2 * 128 * 384);
    float* WhhT0 = alloc_f((size_t)2 * 128 * 384);
    float* WihT1 = alloc_f((size_t)2 * 256 * 384);
    float* WhhT1 = alloc_f((size_t)2 * 128 * 384);
    float* vavd  = alloc_f(1536);
    float* vc    = alloc_f(12);
    float* biasF = alloc_f(256);
    float* y0g   = alloc_f((size_t)3 * Bb * 256);   // layer-0 outputs [t][b][dir*128+j]
    int* offs = alloc_i(Nn + 1);
    int* cur  = alloc_i(Nn);
    int* csrc = alloc_i(Ee);
    int* goffs = alloc_i(Bb + 1);
    unsigned short* hb = alloc_s((size_t)Nn * 128);   // bf16 hcur plane
    unsigned short* pBth = alloc_s(128 * 128);
    unsigned short* pBtl = alloc_s(128 * 128);
    unsigned short* WfTh[2] = { alloc_s(128 * 384), alloc_s(128 * 384) };
    unsigned short* WfTl[2] = { alloc_s(128 * 384), alloc_s(128 * 384) };

    hipMemsetAsync(reado, 0, zero_bytes, stream);
    hipMemsetAsync(out, 0, (size_t)Bb * Hh * sizeof(float), stream);

    PrepArgs pa;
    pa.projW = projW + (size_t)Vv * Hh;
    pa.convWn = convWn; pa.convWs = convWs; pa.convAtt = convAtt;
    pa.convBn = convBn; pa.convB = convB;
    pa.Wih0 = Wih0; pa.Whh0 = Whh0; pa.Wih1 = Wih1; pa.Whh1 = Whh1;
    pa.gid = gid; pa.dst = dst;
    pa.pBth = pBth; pa.pBtl = pBtl;
    pa.WfTh0 = WfTh[0]; pa.WfTl0 = WfTl[0]; pa.WfTh1 = WfTh[1]; pa.WfTl1 = WfTl[1];
    pa.vavd = vavd; pa.vc = vc; pa.biasF = biasF;
    pa.WihT0 = WihT0; pa.WhhT0 = WhhT0; pa.WihT1 = WihT1; pa.WhhT1 = WhhT1;
    pa.goffs = goffs; pa.deg = deg;
    const int prep_total = 16384 + 2 * 49152 + 1536 + 12 + 256 + 98304 + 98304 + 196608 + 98304 + Nn + Ee;
    prep_all<<<(prep_total + 255) / 256, 256, 0, stream>>>(pa);

    scan_offsets<<<1, 1024, 0, stream>>>(deg, offs, cur);
    fill_csr<<<1250, 256, 0, stream>>>(dst, src, cur, csrc);

    // projection + dots L0 + hb + readout0
    {
        GArgs g = {};
        g.A = h; g.Bth = pBth; g.Btl = pBtl; g.bias = projB;
        g.M = Nn; g.K = 128;
        g.wid = wid; g.projW = projW; g.hcur = hcur;
        g.gid = gid; g.reado = reado;
        g.vavd = vavd; g.vc = vc; g.adf = adbuf; g.addf = addbuf; g.hb = hb;
        gemm_fused<0><<<dim3(1, Nn / 32), 256, 0, stream>>>(g);
    }

    const int nwaveblocks = (Nn * 64 + 255) / 256;   // 5000
    for (int l = 0; l < 2; l++) {
        gat_gather<<<nwaveblocks, 256, 0, stream>>>(hb, (const float4*)adbuf, (const float4*)addbuf,
                                                    offs, csrc, T);
        {
            GArgs g = {};
            g.A = T; g.Bth = WfTh[l]; g.Btl = WfTl[l]; g.bias = biasF + l * 128;
            g.M = Nn; g.K = 384;
            g.deg = deg; g.gamma = convG + l * Hh; g.beta = convBe + l * Hh;
            g.hcur = hcur;
            g.gid = gid; g.reado = reado + (size_t)(l + 1) * Bb * Hh;
            if (l == 0) { g.vavd = vavd + 768; g.vc = vc + 6; g.adf = adbuf; g.addf = addbuf; g.hb = hb; }
            gemm_fused<2><<<dim3(1, Nn / 32), 256, 0, stream>>>(g);
        }
    }

    gru_l0<<<dim3(Bb / 2, 2), 384, 0, stream>>>(reado, goffs, WihT0, WhhT0, bih0, bhh0,
                                                y0g, out);
    gru_l1<<<dim3(Bb / 2, 2), 384, 0, stream>>>(y0g, WihT1, WhhT1, bih1, bhh1, out);
}

// Round 5
// 384.243 us; speedup vs baseline: 1.5268x; 1.0086x over previous
//
#include <hip/hip_runtime.h>
#include <cstddef>
#include <cstdint>

// Problem constants (from reference)
static constexpr int Nn    = 20000;
static constexpr int Ee    = 320000;
static constexpr int Vv    = 100;
static constexpr int Hh    = 128;
static constexpr int HEADS = 3;
static constexpr int Bb    = 200;
static constexpr float NEG = 0.2f;
static constexpr float EPS = 1e-5f;

typedef short bf16x8 __attribute__((ext_vector_type(8)));
typedef float f32x4  __attribute__((ext_vector_type(4)));

__device__ inline unsigned short bf16_rne(float x) {
    unsigned u = __builtin_bit_cast(unsigned, x);
    u += 0x7FFFu + ((u >> 16) & 1u);
    return (unsigned short)(u >> 16);
}
__device__ inline float bf16_f(unsigned short h) {
    unsigned u = ((unsigned)h) << 16;
    return __builtin_bit_cast(float, u);
}
__device__ inline float bf_lo(unsigned u) { return __builtin_bit_cast(float, u << 16); }
__device__ inline float bf_hi(unsigned u) { return __builtin_bit_cast(float, u & 0xFFFF0000u); }
__device__ inline float lrelu(float a) { return a >= 0.f ? a : NEG * a; }
__device__ inline float sigmoidf(float x) { return 1.f / (1.f + __expf(-x)); }

// ---------------------------------------------------------------------------
// CSR scan + fill (hist lives in prep_all). scan_offsets also zeroes `out`
// (folds away one memset dispatch).
// ---------------------------------------------------------------------------
__global__ __launch_bounds__(1024) void scan_offsets(const int* __restrict__ deg,
                                                     int* __restrict__ offs,
                                                     int* __restrict__ cur,
                                                     float* __restrict__ outz) {
    __shared__ int sums[1024];
    const int tid = threadIdx.x;
    for (int i = tid; i < Bb * Hh; i += 1024) outz[i] = 0.f;
    const int per = (Nn + 1023) >> 10;
    int begin = tid * per;
    int end = begin + per; if (end > Nn) end = Nn;
    if (begin > Nn) begin = Nn;
    int s = 0;
    for (int i = begin; i < end; i++) s += deg[i];
    sums[tid] = s;
    __syncthreads();
    for (int off = 1; off < 1024; off <<= 1) {
        int v = (tid >= off) ? sums[tid - off] : 0;
        __syncthreads();
        sums[tid] += v;
        __syncthreads();
    }
    int run = sums[tid] - s;
    for (int i = begin; i < end; i++) {
        offs[i] = run; cur[i] = run;
        run += deg[i];
    }
    if (end == Nn) offs[Nn] = run;
}

__global__ void fill_csr(const int* __restrict__ dst, const int* __restrict__ src,
                         int* __restrict__ cur, int* __restrict__ csrc) {
    for (int i = blockIdx.x * blockDim.x + threadIdx.x; i < Ee; i += gridDim.x * blockDim.x) {
        int p = atomicAdd(&cur[dst[i]], 1);
        csrc[p] = src[i];
    }
}

// ---------------------------------------------------------------------------
// Fused prep: projW split; Wfused = blockdiag(Wn)@Ws split-transposed;
// va/vd = Wn_h @ att halves; vc = bn_h . att halves; biasF = convB + bn@Ws;
// GRU weight transposes (coalesced [k][j] layout); graph offsets; dst hist.
// ---------------------------------------------------------------------------
struct PrepArgs {
    const float *projW, *convWn, *convWs, *convAtt, *convBn, *convB;
    const float *Wih0, *Whh0, *Wih1, *Whh1;
    const int *gid, *dst;
    unsigned short *pBth, *pBtl;
    unsigned short *WfTh0, *WfTl0, *WfTh1, *WfTl1;
    float *vavd, *vc, *biasF;
    float *WihT0, *WhhT0, *WihT1, *WhhT1;
    int *goffs, *deg;
};

__device__ inline void wsplit(const float* B, int K, int N, int idx,
                              unsigned short* Bth, unsigned short* Btl) {
    int k = idx / N, n = idx - k * N;
    float v = B[idx];
    unsigned short h = bf16_rne(v);
    unsigned short l = bf16_rne(v - bf16_f(h));
    Bth[(size_t)n * K + k] = h;
    Btl[(size_t)n * K + k] = l;
}
__device__ inline void gruT(const float* W, int K, int idx, float* WT) {
    int d = idx / (384 * K);
    int r = idx - d * 384 * K;
    int j = r / K, k = r - j * K;
    WT[(size_t)d * K * 384 + (size_t)k * 384 + j] = W[idx];
}

__global__ void prep_all(PrepArgs a) {
    int i = blockIdx.x * blockDim.x + threadIdx.x;
    if (i < 16384) { wsplit(a.projW, 128, 128, i, a.pBth, a.pBtl); return; } i -= 16384;
#pragma unroll
    for (int l = 0; l < 2; l++) {
        if (i < 49152) {
            int k = i >> 7, c = i & 127;
            int h = k >> 7, i_ = k & 127;
            const float* wn = a.convWn + (size_t)l * 49152 + (size_t)i_ * 384 + h * 128;
            const float* ws = a.convWs + (size_t)l * 49152 + (size_t)(h * 128) * 128 + c;
            float v = 0.f;
            for (int j = 0; j < 128; j++) v += wn[j] * ws[(size_t)j * 128];
            unsigned short hi = bf16_rne(v);
            unsigned short lo = bf16_rne(v - bf16_f(hi));
            unsigned short* th = l ? a.WfTh1 : a.WfTh0;
            unsigned short* tl = l ? a.WfTl1 : a.WfTl0;
            th[(size_t)c * 384 + k] = hi;
            tl[(size_t)c * 384 + k] = lo;
            return;
        }
        i -= 49152;
    }
    if (i < 1536) {
        int l = i / 768, r = i % 768;
        int sd = r / 384, rr = r % 384, h = rr >> 7, i_ = rr & 127;
        const float* wn = a.convWn + (size_t)l * 49152 + (size_t)i_ * 384 + h * 128;
        const float* at = a.convAtt + l * 768 + h * 256 + sd * 128;
        float v = 0.f;
        for (int j = 0; j < 128; j++) v += wn[j] * at[j];
        a.vavd[i] = v;
        return;
    } i -= 1536;
    if (i < 12) {
        int l = i / 6, r = i % 6, sd = r / 3, h = r % 3;
        const float* bn = a.convBn + l * 384 + h * 128;
        const float* at = a.convAtt + l * 768 + h * 256 + sd * 128;
        float v = 0.f;
        for (int j = 0; j < 128; j++) v += bn[j] * at[j];
        a.vc[i] = v;
        return;
    } i -= 12;
    if (i < 256) {
        int l = i >> 7, c = i & 127;
        const float* bn = a.convBn + l * 384;
        const float* ws = a.convWs + (size_t)l * 49152 + c;
        float v = a.convB[l * 128 + c];
        for (int k = 0; k < 384; k++) v += bn[k] * ws[(size_t)k * 128];
        a.biasF[i] = v;
        return;
    } i -= 256;
    if (i < 98304)  { gruT(a.Wih0, 128, i, a.WihT0); return; }  i -= 98304;
    if (i < 98304)  { gruT(a.Whh0, 128, i, a.WhhT0); return; }  i -= 98304;
    if (i < 196608) { gruT(a.Wih1, 256, i, a.WihT1); return; }  i -= 196608;
    if (i < 98304)  { gruT(a.Whh1, 128, i, a.WhhT1); return; }  i -= 98304;
    if (i < Nn) {
        int g = a.gid[i];
        if (i == 0) { for (int b = 0; b <= g; b++) a.goffs[b] = 0; }
        else { int pg = a.gid[i - 1]; for (int b = pg + 1; b <= g; b++) a.goffs[b] = i; }
        if (i == Nn - 1) { for (int b = g + 1; b <= Bb; b++) a.goffs[b] = Nn; }
        return;
    } i -= Nn;
    if (i < Ee) atomicAdd(&a.deg[a.dst[i]], 1);
}

// ---------------------------------------------------------------------------
// Split-bf16 MFMA GEMM, BM=32, BN=128, BK=32; 256 threads = 4 waves (1x4),
// wave tile 32x32 (2x2 MFMA 16x16x32). K-loop is register-prefetch
// software-pipelined: iteration k+1's global staging loads are issued right
// after the first barrier of iteration k, so they fly under the LDS-read +
// MFMA phase and are consumed at the next LDS write (T14 issue-early /
// write-late). Fused epilogues:
// MODE 0: proj: hcur = acc+bias+projW[wid]; MODE 2: residual+LN+ReLU.
// Both: fused per-graph readout; optional next-layer att dots + bf16 plane.
// ---------------------------------------------------------------------------
struct GArgs {
    const float* A; const unsigned short* Bth; const unsigned short* Btl;
    const float* bias; int M, K;
    const int* wid; const float* projW;                 // MODE 0
    const int* deg; const float* gamma; const float* beta;  // MODE 2
    float* hcur;
    const int* gid; float* reado;
    const float* vavd; const float* vc;                 // null -> skip dots/hb
    float* adf; float* addf;
    unsigned short* hb;
};

template <int MODE>
__global__ __launch_bounds__(256) void gemm_fused(GArgs a) {
    __shared__ unsigned short As_hi[32][40];
    __shared__ unsigned short As_lo[32][40];
    __shared__ unsigned short Bs_hi[128][40];
    __shared__ unsigned short Bs_lo[128][40];
    __shared__ float ytile[32][132];
    __shared__ float sred[6][32][4];
    __shared__ int sgid[32];
    const int tid  = threadIdx.x;
    const int row0 = blockIdx.y * 32;
    const int wn   = tid >> 6;          // wave 0..3 along N
    const int L    = tid & 63;
    const int lrow = L & 15;
    const int lq   = L >> 4;
    const int K = a.K;

    // staging geometry (fixed per thread)
    const int mA  = tid >> 3;           // A row 0..31
    const int kqA = (tid & 7) * 4;      // A col (floats)
    const int nB  = tid >> 1;           // B row 0..127
    const int khB = (tid & 1) * 16;     // B col base (shorts)
    const float* Arow = a.A + (size_t)(row0 + mA) * K + kqA;
    const unsigned short* Bhrow = a.Bth + (size_t)nB * K + khB;
    const unsigned short* Blrow = a.Btl + (size_t)nB * K + khB;

    f32x4 acc[2][2];
#pragma unroll
    for (int i = 0; i < 2; i++)
#pragma unroll
        for (int j = 0; j < 2; j++) acc[i][j] = (f32x4){0.f, 0.f, 0.f, 0.f};

    // prefetch iteration 0
    float4 av  = *(const float4*)(Arow);
    float4 vbh0 = *(const float4*)(Bhrow);
    float4 vbh1 = *(const float4*)(Bhrow + 8);
    float4 vbl0 = *(const float4*)(Blrow);
    float4 vbl1 = *(const float4*)(Blrow + 8);

    for (int kb = 0; kb < K; kb += 32) {
        {   // write staged registers to LDS (A converted to split-bf16)
            unsigned short h0 = bf16_rne(av.x), h1 = bf16_rne(av.y),
                           h2 = bf16_rne(av.z), h3 = bf16_rne(av.w);
            *(short4*)&As_hi[mA][kqA] = make_short4((short)h0, (short)h1, (short)h2, (short)h3);
            *(short4*)&As_lo[mA][kqA] = make_short4((short)bf16_rne(av.x - bf16_f(h0)),
                                                    (short)bf16_rne(av.y - bf16_f(h1)),
                                                    (short)bf16_rne(av.z - bf16_f(h2)),
                                                    (short)bf16_rne(av.w - bf16_f(h3)));
            *(float4*)&Bs_hi[nB][khB]     = vbh0;
            *(float4*)&Bs_hi[nB][khB + 8] = vbh1;
            *(float4*)&Bs_lo[nB][khB]     = vbl0;
            *(float4*)&Bs_lo[nB][khB + 8] = vbl1;
        }
        __syncthreads();
        if (kb + 32 < K) {   // issue next iteration's loads (hidden under MFMA)
            av   = *(const float4*)(Arow + kb + 32);
            vbh0 = *(const float4*)(Bhrow + kb + 32);
            vbh1 = *(const float4*)(Bhrow + kb + 40);
            vbl0 = *(const float4*)(Blrow + kb + 32);
            vbl1 = *(const float4*)(Blrow + kb + 40);
        }
        bf16x8 ah[2], al[2], bh[2], bl[2];
#pragma unroll
        for (int mi = 0; mi < 2; mi++) {
            int r = mi * 16 + lrow;
            ah[mi] = *(const bf16x8*)&As_hi[r][lq * 8];
            al[mi] = *(const bf16x8*)&As_lo[r][lq * 8];
        }
#pragma unroll
        for (int ni = 0; ni < 2; ni++) {
            int r = wn * 32 + ni * 16 + lrow;
            bh[ni] = *(const bf16x8*)&Bs_hi[r][lq * 8];
            bl[ni] = *(const bf16x8*)&Bs_lo[r][lq * 8];
        }
#pragma unroll
        for (int mi = 0; mi < 2; mi++)
#pragma unroll
            for (int ni = 0; ni < 2; ni++) {
                acc[mi][ni] = __builtin_amdgcn_mfma_f32_16x16x32_bf16(ah[mi], bh[ni], acc[mi][ni], 0, 0, 0);
                acc[mi][ni] = __builtin_amdgcn_mfma_f32_16x16x32_bf16(ah[mi], bl[ni], acc[mi][ni], 0, 0, 0);
                acc[mi][ni] = __builtin_amdgcn_mfma_f32_16x16x32_bf16(al[mi], bh[ni], acc[mi][ni], 0, 0, 0);
            }
        __syncthreads();
    }

    // bias
#pragma unroll
    for (int ni = 0; ni < 2; ni++) {
        float bb = a.bias[wn * 32 + ni * 16 + lrow];
#pragma unroll
        for (int mi = 0; mi < 2; mi++)
#pragma unroll
            for (int r = 0; r < 4; r++) acc[mi][ni][r] += bb;
    }

    if constexpr (MODE == 0) {
        // acc := y = acc + projW[wid[row]]  (bias already in)
#pragma unroll
        for (int mi = 0; mi < 2; mi++)
#pragma unroll
            for (int r = 0; r < 4; r++) {
                int lr = mi * 16 + lq * 4 + r;
                int row = row0 + lr;
                int wi = a.wid[row];
#pragma unroll
                for (int ni = 0; ni < 2; ni++) {
                    int c = wn * 32 + ni * 16 + lrow;
                    float y = acc[mi][ni][r] + a.projW[(size_t)wi * 128 + c];
                    acc[mi][ni][r] = y;
                    a.hcur[(size_t)row * 128 + c] = y;
                    ytile[lr][c] = y;
                }
            }
    }

    if constexpr (MODE == 2) {
        __shared__ float red1[32][4], red2[32][4];
        float g4[2], be4[2];
#pragma unroll
        for (int ni = 0; ni < 2; ni++) {
            int c = wn * 32 + ni * 16 + lrow;
            g4[ni] = a.gamma[c]; be4[ni] = a.beta[c];
        }
#pragma unroll
        for (int mi = 0; mi < 2; mi++)
#pragma unroll
            for (int r = 0; r < 4; r++) {
                int lr = mi * 16 + lq * 4 + r;
                int row = row0 + lr;
                int dg = a.deg[row];
#pragma unroll
                for (int ni = 0; ni < 2; ni++) {
                    int c = wn * 32 + ni * 16 + lrow;
                    float hold = a.hcur[(size_t)row * 128 + c];
                    acc[mi][ni][r] = hold + (dg > 0 ? acc[mi][ni][r] : 0.f);
                }
            }
#pragma unroll
        for (int mi = 0; mi < 2; mi++)
#pragma unroll
            for (int r = 0; r < 4; r++) {
                float ps = acc[mi][0][r] + acc[mi][1][r];
#pragma unroll
                for (int o = 1; o < 16; o <<= 1) ps += __shfl_xor(ps, o, 64);
                if (lrow == 0) red1[mi * 16 + lq * 4 + r][wn] = ps;
            }
        __syncthreads();
#pragma unroll
        for (int mi = 0; mi < 2; mi++)
#pragma unroll
            for (int r = 0; r < 4; r++) {
                int lr = mi * 16 + lq * 4 + r;
                float mu = (red1[lr][0] + red1[lr][1] + red1[lr][2] + red1[lr][3]) * (1.f / 128.f);
                float qs = 0.f;
#pragma unroll
                for (int ni = 0; ni < 2; ni++) {
                    float dx = acc[mi][ni][r] - mu;
                    qs += dx * dx;
                }
#pragma unroll
                for (int o = 1; o < 16; o <<= 1) qs += __shfl_xor(qs, o, 64);
                if (lrow == 0) red2[lr][wn] = qs;
            }
        __syncthreads();
#pragma unroll
        for (int mi = 0; mi < 2; mi++)
#pragma unroll
            for (int r = 0; r < 4; r++) {
                int lr = mi * 16 + lq * 4 + r;
                int row = row0 + lr;
                float mu = (red1[lr][0] + red1[lr][1] + red1[lr][2] + red1[lr][3]) * (1.f / 128.f);
                float var = (red2[lr][0] + red2[lr][1] + red2[lr][2] + red2[lr][3]) * (1.f / 128.f);
                float rs = rsqrtf(var + EPS);
#pragma unroll
                for (int ni = 0; ni < 2; ni++) {
                    int c = wn * 32 + ni * 16 + lrow;
                    float y = fmaxf((acc[mi][ni][r] - mu) * rs * g4[ni] + be4[ni], 0.f);
                    acc[mi][ni][r] = y;
                    a.hcur[(size_t)row * 128 + c] = y;
                    ytile[lr][c] = y;
                }
            }
    }

    if (tid < 32) sgid[tid] = a.gid[row0 + tid];

    // ---- register-space attention dots (no ytile loop, no global v loop) ----
    const bool dots = (a.vavd != nullptr);
    if (dots) {
        float vv0[6], vv1[6];
#pragma unroll
        for (int d = 0; d < 6; d++) {
            vv0[d] = a.vavd[d * 128 + wn * 32 + lrow];
            vv1[d] = a.vavd[d * 128 + wn * 32 + 16 + lrow];
        }
#pragma unroll
        for (int d = 0; d < 6; d++) {
#pragma unroll
            for (int mi = 0; mi < 2; mi++)
#pragma unroll
                for (int r = 0; r < 4; r++) {
                    float ps = acc[mi][0][r] * vv0[d] + acc[mi][1][r] * vv1[d];
#pragma unroll
                    for (int o = 1; o < 16; o <<= 1) ps += __shfl_xor(ps, o, 64);
                    if (lrow == 0) sred[d][mi * 16 + lq * 4 + r][wn] = ps;
                }
        }
    }
    __syncthreads();

    // fused per-graph readout (gid sorted -> runs, atomic per run)
    {
        int j = tid & 127, hh = tid >> 7;
        float sum = 0.f; int curg = -1;
        for (int r = hh * 16; r < hh * 16 + 16; r++) {
            int g = sgid[r];
            if (g != curg) {
                if (curg >= 0) atomicAdd(&a.reado[(size_t)curg * 128 + j], sum);
                sum = 0.f; curg = g;
            }
            sum += ytile[r][j];
        }
        if (curg >= 0) atomicAdd(&a.reado[(size_t)curg * 128 + j], sum);
    }

    if (dots) {
        if (tid < 192) {
            int row = tid & 31, d = tid >> 5;     // d in [0,6)
            float s = sred[d][row][0] + sred[d][row][1] + sred[d][row][2] + sred[d][row][3]
                    + a.vc[d];
            int node = row0 + row;
            int sd = d / 3, h = d - sd * 3;
            float* dstp = sd ? a.addf : a.adf;
            dstp[(size_t)node * 4 + h] = s;
        }
        {   // bf16 hcur plane from ytile (<=2-way bank aliasing, free)
            int row = tid >> 3, c0 = (tid & 7) * 16;
            unsigned* dst = (unsigned*)(a.hb + (size_t)(row0 + row) * 128 + c0);
#pragma unroll
            for (int q = 0; q < 8; q++) {
                unsigned lo = bf16_rne(ytile[row][c0 + 2 * q]);
                unsigned hi = bf16_rne(ytile[row][c0 + 2 * q + 1]);
                dst[q] = lo | (hi << 16);
            }
        }
    }
}

// ---------------------------------------------------------------------------
// GAT gather: one wave per dst node, bf16 hcur rows (256B), scores from dots.
// ---------------------------------------------------------------------------
__global__ __launch_bounds__(256) void gat_gather(const unsigned short* __restrict__ hb,
                                                  const float4* __restrict__ ad,
                                                  const float4* __restrict__ add,
                                                  const int* __restrict__ offs,
                                                  const int* __restrict__ csrc,
                                                  float* __restrict__ T) {
    __shared__ float4 slot[4][64];
    const int n = (blockIdx.x * 256 + threadIdx.x) >> 6;
    const int wv_ = threadIdx.x >> 6;
    const int L = threadIdx.x & 63;
    if (n >= Nn) return;
    const int start = offs[n];
    const int deg = offs[n + 1] - start;
    float2* o2 = (float2*)(T + (size_t)n * 384);
    if (deg == 0) {
        float2 z = make_float2(0.f, 0.f);
        o2[L] = z; o2[64 + L] = z; o2[128 + L] = z;
        return;
    }
    const float4 adn = add[n];
    float2 t0 = make_float2(0.f, 0.f), t1 = t0, t2 = t0;

    if (deg <= 64) {
        int sn = 0; float e0 = 0.f, e1 = 0.f, e2 = 0.f;
        if (L < deg) {
            sn = csrc[start + L];
            float4 a4 = ad[sn];
            e0 = __expf(lrelu(a4.x + adn.x));
            e1 = __expf(lrelu(a4.y + adn.y));
            e2 = __expf(lrelu(a4.z + adn.z));
        }
        float s0 = e0, s1 = e1, s2 = e2;
#pragma unroll
        for (int o = 32; o > 0; o >>= 1) {
            s0 += __shfl_xor(s0, o, 64);
            s1 += __shfl_xor(s1, o, 64);
            s2 += __shfl_xor(s2, o, 64);
        }
        slot[wv_][L] = make_float4(__builtin_bit_cast(float, sn),
                                   e0 / s0, e1 / s1, e2 / s2);
        __builtin_amdgcn_wave_barrier();
#pragma unroll 2
        for (int j = 0; j < deg; j++) {
            float4 sc = slot[wv_][j];
            int s_n = __builtin_bit_cast(int, sc.x);
            unsigned u = ((const unsigned*)(hb + (size_t)s_n * 128))[L];
            float x0 = bf_lo(u), x1 = bf_hi(u);
            t0.x += sc.y * x0; t0.y += sc.y * x1;
            t1.x += sc.z * x0; t1.y += sc.z * x1;
            t2.x += sc.w * x0; t2.y += sc.w * x1;
        }
    } else {
        float s0 = 0.f, s1 = 0.f, s2 = 0.f;
        for (int i = L; i < deg; i += 64) {
            int sn = csrc[start + i];
            float4 a4 = ad[sn];
            s0 += __expf(lrelu(a4.x + adn.x));
            s1 += __expf(lrelu(a4.y + adn.y));
            s2 += __expf(lrelu(a4.z + adn.z));
        }
#pragma unroll
        for (int o = 32; o > 0; o >>= 1) {
            s0 += __shfl_xor(s0, o, 64);
            s1 += __shfl_xor(s1, o, 64);
            s2 += __shfl_xor(s2, o, 64);
        }
        float i0 = 1.f / s0, i1 = 1.f / s1, i2 = 1.f / s2;
        for (int base = 0; base < deg; base += 64) {
            int cnt = deg - base; if (cnt > 64) cnt = 64;
            if (L < cnt) {
                int sn = csrc[start + base + L];
                float4 a4 = ad[sn];
                slot[wv_][L] = make_float4(__builtin_bit_cast(float, sn),
                                           __expf(lrelu(a4.x + adn.x)) * i0,
                                           __expf(lrelu(a4.y + adn.y)) * i1,
                                           __expf(lrelu(a4.z + adn.z)) * i2);
            }
            __builtin_amdgcn_wave_barrier();
            for (int j = 0; j < cnt; j++) {
                float4 sc = slot[wv_][j];
                int s_n = __builtin_bit_cast(int, sc.x);
                unsigned u = ((const unsigned*)(hb + (size_t)s_n * 128))[L];
                float x0 = bf_lo(u), x1 = bf_hi(u);
                t0.x += sc.y * x0; t0.y += sc.y * x1;
                t1.x += sc.z * x0; t1.y += sc.z * x1;
                t2.x += sc.w * x0; t2.y += sc.w * x1;
            }
            __builtin_amdgcn_wave_barrier();
        }
    }
    o2[L] = t0; o2[64 + L] = t1; o2[128 + L] = t2;
}

// ---------------------------------------------------------------------------
// GRU v5 (proven in round 4): coalesced transposed weights streamed from L2,
// h in LDS, GNB=2 batch elems per block, layer-split kernels + dir-split
// blocks: grid (Bb/2, 2) = 200 blocks x 384 threads per kernel.
// ---------------------------------------------------------------------------
__global__ __launch_bounds__(384) void gru_l0(const float* __restrict__ reado,
                                              const int* __restrict__ goffs,
                                              const float* __restrict__ WihT,
                                              const float* __restrict__ WhhT,
                                              const float* __restrict__ bih,
                                              const float* __restrict__ bhh,
                                              float* __restrict__ y0g,
                                              float* __restrict__ out) {
    const int dir = blockIdx.y;
    const int b0 = blockIdx.x * 2;
    const int j = threadIdx.x;
    __shared__ float xs[3][128][2];
    __shared__ float hsh[128][2];
    __shared__ float gis[384][2];
    __shared__ float ghs[384][2];

    const int cg0 = goffs[b0], cg1 = goffs[b0 + 1], cg2 = goffs[b0 + 2];
    const float invc0 = 1.f / fmaxf((float)(cg1 - cg0), 1.f);
    const float invc1 = 1.f / fmaxf((float)(cg2 - cg1), 1.f);

    for (int i = j; i < 768; i += 384) {
        int nb = i & 1, k = (i >> 1) & 127, t = i >> 8;
        xs[t][k][nb] = reado[(size_t)t * (Bb * Hh) + (size_t)(b0 + nb) * Hh + k];
    }
    if (j < 128) { hsh[j][0] = 0.f; hsh[j][1] = 0.f; }
    __syncthreads();

    const float* Wi = WihT + (size_t)dir * 128 * 384 + j;   // [k][j] coalesced
    const float* Wh = WhhT + (size_t)dir * 128 * 384 + j;
    const float bij = bih[dir * 384 + j];
    const float bhj = bhh[dir * 384 + j];

    float gi00 = 0.f, gi01 = 0.f, gi10 = 0.f, gi11 = 0.f, gi20 = 0.f, gi21 = 0.f;
#pragma unroll 4
    for (int k = 0; k < 128; k++) {
        float w = Wi[(size_t)k * 384];
        float2 x0 = *(const float2*)&xs[0][k][0];
        float2 x1 = *(const float2*)&xs[1][k][0];
        float2 x2 = *(const float2*)&xs[2][k][0];
        gi00 += w * x0.x; gi01 += w * x0.y;
        gi10 += w * x1.x; gi11 += w * x1.y;
        gi20 += w * x2.x; gi21 += w * x2.y;
    }
    gi00 = gi00 * invc0 + bij; gi01 = gi01 * invc1 + bij;
    gi10 = gi10 * invc0 + bij; gi11 = gi11 * invc1 + bij;
    gi20 = gi20 * invc0 + bij; gi21 = gi21 * invc1 + bij;

#pragma unroll
    for (int step = 0; step < 3; step++) {
        float g0 = bhj, g1 = bhj;
        if (step > 0) {
#pragma unroll 4
            for (int k = 0; k < 128; k++) {
                float w = Wh[(size_t)k * 384];
                float2 hv = *(const float2*)&hsh[k][0];
                g0 += w * hv.x; g1 += w * hv.y;
            }
        }
        float gs0, gs1;
        if (dir) { gs0 = (step == 0 ? gi20 : (step == 1 ? gi10 : gi00));
                   gs1 = (step == 0 ? gi21 : (step == 1 ? gi11 : gi01)); }
        else     { gs0 = (step == 0 ? gi00 : (step == 1 ? gi10 : gi20));
                   gs1 = (step == 0 ? gi01 : (step == 1 ? gi11 : gi21)); }
        gis[j][0] = gs0; gis[j][1] = gs1;
        ghs[j][0] = g0;  ghs[j][1] = g1;
        __syncthreads();
        if (j < 128) {
            const int t = dir ? 2 - step : step;
#pragma unroll
            for (int nb = 0; nb < 2; nb++) {
                float r  = sigmoidf(gis[j][nb] + ghs[j][nb]);
                float z  = sigmoidf(gis[j + 128][nb] + ghs[j + 128][nb]);
                float nn = tanhf(gis[j + 256][nb] + r * ghs[j + 256][nb]);
                float hnew = (1.f - z) * nn + z * hsh[j][nb];
                hsh[j][nb] = hnew;
                y0g[((size_t)t * Bb + (b0 + nb)) * 256 + dir * 128 + j] = hnew;
                if (step == 2)
                    atomicAdd(&out[(size_t)(b0 + nb) * Hh + j], 0.25f * hnew);
            }
        }
        __syncthreads();
    }
}

__global__ __launch_bounds__(384) void gru_l1(const float* __restrict__ y0g,
                                              const float* __restrict__ WihT,
                                              const float* __restrict__ WhhT,
                                              const float* __restrict__ bih,
                                              const float* __restrict__ bhh,
                                              float* __restrict__ out) {
    const int dir = blockIdx.y;
    const int b0 = blockIdx.x * 2;
    const int j = threadIdx.x;
    __shared__ float ys[3][256][2];
    __shared__ float hsh[128][2];
    __shared__ float gis[384][2];
    __shared__ float ghs[384][2];

    for (int i = j; i < 1536; i += 384) {
        int nb = i & 1, k = (i >> 1) & 255, t = i >> 9;
        ys[t][k][nb] = y0g[((size_t)t * Bb + (b0 + nb)) * 256 + k];
    }
    if (j < 128) { hsh[j][0] = 0.f; hsh[j][1] = 0.f; }
    __syncthreads();

    const float* Wi = WihT + (size_t)dir * 256 * 384 + j;   // [k][j] coalesced
    const float* Wh = WhhT + (size_t)dir * 128 * 384 + j;
    const float bij = bih[dir * 384 + j];
    const float bhj = bhh[dir * 384 + j];

    float gi00 = bij, gi01 = bij, gi10 = bij, gi11 = bij, gi20 = bij, gi21 = bij;
#pragma unroll 4
    for (int k = 0; k < 256; k++) {
        float w = Wi[(size_t)k * 384];
        float2 x0 = *(const float2*)&ys[0][k][0];
        float2 x1 = *(const float2*)&ys[1][k][0];
        float2 x2 = *(const float2*)&ys[2][k][0];
        gi00 += w * x0.x; gi01 += w * x0.y;
        gi10 += w * x1.x; gi11 += w * x1.y;
        gi20 += w * x2.x; gi21 += w * x2.y;
    }

#pragma unroll
    for (int step = 0; step < 3; step++) {
        float g0 = bhj, g1 = bhj;
        if (step > 0) {
#pragma unroll 4
            for (int k = 0; k < 128; k++) {
                float w = Wh[(size_t)k * 384];
                float2 hv = *(const float2*)&hsh[k][0];
                g0 += w * hv.x; g1 += w * hv.y;
            }
        }
        float gs0, gs1;
        if (dir) { gs0 = (step == 0 ? gi20 : (step == 1 ? gi10 : gi00));
                   gs1 = (step == 0 ? gi21 : (step == 1 ? gi11 : gi01)); }
        else     { gs0 = (step == 0 ? gi00 : (step == 1 ? gi10 : gi20));
                   gs1 = (step == 0 ? gi01 : (step == 1 ? gi11 : gi21)); }
        gis[j][0] = gs0; gis[j][1] = gs1;
        ghs[j][0] = g0;  ghs[j][1] = g1;
        __syncthreads();
        if (j < 128) {
#pragma unroll
            for (int nb = 0; nb < 2; nb++) {
                float r  = sigmoidf(gis[j][nb] + ghs[j][nb]);
                float z  = sigmoidf(gis[j + 128][nb] + ghs[j + 128][nb]);
                float nn = tanhf(gis[j + 256][nb] + r * ghs[j + 256][nb]);
                float hnew = (1.f - z) * nn + z * hsh[j][nb];
                hsh[j][nb] = hnew;
                if (step == 2)
                    atomicAdd(&out[(size_t)(b0 + nb) * Hh + j], 0.25f * hnew);
            }
        }
        __syncthreads();
    }
}

// ---------------------------------------------------------------------------
extern "C" void kernel_launch(void* const* d_in, const int* in_sizes, int n_in,
                              void* d_out, int out_size, void* d_ws, size_t ws_size,
                              hipStream_t stream) {
    const float* h      = (const float*)d_in[0];
    const int*   wid    = (const int*)d_in[1];
    const int*   src    = (const int*)d_in[2];
    const int*   dst    = (const int*)d_in[3];
    const int*   gid    = (const int*)d_in[4];
    const float* projW  = (const float*)d_in[5];
    const float* projB  = (const float*)d_in[6];
    const float* convWn = (const float*)d_in[7];
    const float* convBn = (const float*)d_in[8];
    const float* convAtt= (const float*)d_in[9];
    const float* convWs = (const float*)d_in[10];
    const float* convB  = (const float*)d_in[11];
    const float* convG  = (const float*)d_in[12];
    const float* convBe = (const float*)d_in[13];
    const float* Wih0   = (const float*)d_in[14];
    const float* Whh0   = (const float*)d_in[15];
    const float* bih0   = (const float*)d_in[16];
    const float* bhh0   = (const float*)d_in[17];
    const float* Wih1   = (const float*)d_in[18];
    const float* Whh1   = (const float*)d_in[19];
    const float* bih1   = (const float*)d_in[20];
    const float* bhh1   = (const float*)d_in[21];
    float* out = (float*)d_out;

    char* p = (char*)d_ws;
    auto align16 = [&]() { p = (char*)(((uintptr_t)p + 15) & ~(uintptr_t)15); };
    auto alloc_f = [&](size_t n) { align16(); float* r = (float*)p; p += n * sizeof(float); return r; };
    auto alloc_i = [&](size_t n) { align16(); int* r = (int*)p; p += n * sizeof(int); return r; };
    auto alloc_s = [&](size_t n) { align16(); unsigned short* r = (unsigned short*)p; p += n * sizeof(unsigned short); return r; };
    float* hcur  = alloc_f((size_t)Nn * 128);
    float* T     = alloc_f((size_t)Nn * 384);
    float* adbuf = alloc_f((size_t)Nn * 4);
    float* addbuf= alloc_f((size_t)Nn * 4);
    // contiguous zero region: reado | deg
    float* reado = alloc_f((size_t)3 * Bb * Hh);
    int* deg  = alloc_i(Nn);
    const size_t zero_bytes = (size_t)3 * Bb * Hh * sizeof(float) + Nn * sizeof(int);
    float* WihT0 = alloc_f((size_t)2 * 128 * 384);
    float* WhhT0 = alloc_f((size_t)2 * 128 * 384);
    float* WihT1 = alloc_f((size_t)2 * 256 * 384);
    float* WhhT1 = alloc_f((size_t)2 * 128 * 384);
    float* vavd  = alloc_f(1536);
    float* vc    = alloc_f(12);
    float* biasF = alloc_f(256);
    float* y0g   = alloc_f((size_t)3 * Bb * 256);   // layer-0 outputs [t][b][dir*128+j]
    int* offs = alloc_i(Nn + 1);
    int* cur  = alloc_i(Nn);
    int* csrc = alloc_i(Ee);
    int* goffs = alloc_i(Bb + 1);
    unsigned short* hb = alloc_s((size_t)Nn * 128);   // bf16 hcur plane
    unsigned short* pBth = alloc_s(128 * 128);
    unsigned short* pBtl = alloc_s(128 * 128);
    unsigned short* WfTh[2] = { alloc_s(128 * 384), alloc_s(128 * 384) };
    unsigned short* WfTl[2] = { alloc_s(128 * 384), alloc_s(128 * 384) };

    hipMemsetAsync(reado, 0, zero_bytes, stream);

    PrepArgs pa;
    pa.projW = projW + (size_t)Vv * Hh;
    pa.convWn = convWn; pa.convWs = convWs; pa.convAtt = convAtt;
    pa.convBn = convBn; pa.convB = convB;
    pa.Wih0 = Wih0; pa.Whh0 = Whh0; pa.Wih1 = Wih1; pa.Whh1 = Whh1;
    pa.gid = gid; pa.dst = dst;
    pa.pBth = pBth; pa.pBtl = pBtl;
    pa.WfTh0 = WfTh[0]; pa.WfTl0 = WfTl[0]; pa.WfTh1 = WfTh[1]; pa.WfTl1 = WfTl[1];
    pa.vavd = vavd; pa.vc = vc; pa.biasF = biasF;
    pa.WihT0 = WihT0; pa.WhhT0 = WhhT0; pa.WihT1 = WihT1; pa.WhhT1 = WhhT1;
    pa.goffs = goffs; pa.deg = deg;
    const int prep_total = 16384 + 2 * 49152 + 1536 + 12 + 256 + 98304 + 98304 + 196608 + 98304 + Nn + Ee;
    prep_all<<<(prep_total + 255) / 256, 256, 0, stream>>>(pa);

    scan_offsets<<<1, 1024, 0, stream>>>(deg, offs, cur, out);
    fill_csr<<<1250, 256, 0, stream>>>(dst, src, cur, csrc);

    // projection + dots L0 + hb + readout0
    {
        GArgs g = {};
        g.A = h; g.Bth = pBth; g.Btl = pBtl; g.bias = projB;
        g.M = Nn; g.K = 128;
        g.wid = wid; g.projW = projW; g.hcur = hcur;
        g.gid = gid; g.reado = reado;
        g.vavd = vavd; g.vc = vc; g.adf = adbuf; g.addf = addbuf; g.hb = hb;
        gemm_fused<0><<<dim3(1, Nn / 32), 256, 0, stream>>>(g);
    }

    const int nwaveblocks = (Nn * 64 + 255) / 256;   // 5000
    for (int l = 0; l < 2; l++) {
        gat_gather<<<nwaveblocks, 256, 0, stream>>>(hb, (const float4*)adbuf, (const float4*)addbuf,
                                                    offs, csrc, T);
        {
            GArgs g = {};
            g.A = T; g.Bth = WfTh[l]; g.Btl = WfTl[l]; g.bias = biasF + l * 128;
            g.M = Nn; g.K = 384;
            g.deg = deg; g.gamma = convG + l * Hh; g.beta = convBe + l * Hh;
            g.hcur = hcur;
            g.gid = gid; g.reado = reado + (size_t)(l + 1) * Bb * Hh;
            if (l == 0) { g.vavd = vavd + 768; g.vc = vc + 6; g.adf = adbuf; g.addf = addbuf; g.hb = hb; }
            gemm_fused<2><<<dim3(1, Nn / 32), 256, 0, stream>>>(g);
        }
    }

    gru_l0<<<dim3(Bb / 2, 2), 384, 0, stream>>>(reado, goffs, WihT0, WhhT0, bih0, bhh0,
                                                y0g, out);
    gru_l1<<<dim3(Bb / 2, 2), 384, 0, stream>>>(y0g, WihT1, WhhT1, bih1, bhh1, out);
}

// Round 6
// 360.386 us; speedup vs baseline: 1.6279x; 1.0662x over previous
//
#include <hip/hip_runtime.h>
#include <cstddef>
#include <cstdint>

// Problem constants (from reference)
static constexpr int Nn    = 20000;
static constexpr int Ee    = 320000;
static constexpr int Vv    = 100;
static constexpr int Hh    = 128;
static constexpr int HEADS = 3;
static constexpr int Bb    = 200;
static constexpr float NEG = 0.2f;
static constexpr float EPS = 1e-5f;

typedef short bf16x8 __attribute__((ext_vector_type(8)));
typedef float f32x4  __attribute__((ext_vector_type(4)));

__device__ inline unsigned short bf16_rne(float x) {
    unsigned u = __builtin_bit_cast(unsigned, x);
    u += 0x7FFFu + ((u >> 16) & 1u);
    return (unsigned short)(u >> 16);
}
__device__ inline float bf16_f(unsigned short h) {
    unsigned u = ((unsigned)h) << 16;
    return __builtin_bit_cast(float, u);
}
__device__ inline float bf_lo(unsigned u) { return __builtin_bit_cast(float, u << 16); }
__device__ inline float bf_hi(unsigned u) { return __builtin_bit_cast(float, u & 0xFFFF0000u); }
__device__ inline float lrelu(float a) { return a >= 0.f ? a : NEG * a; }
__device__ inline float sigmoidf(float x) { return 1.f / (1.f + __expf(-x)); }

// ---------------------------------------------------------------------------
// CSR scan + fill (hist lives in prep_all)
// ---------------------------------------------------------------------------
__global__ __launch_bounds__(1024) void scan_offsets(const int* __restrict__ deg,
                                                     int* __restrict__ offs,
                                                     int* __restrict__ cur) {
    __shared__ int sums[1024];
    const int tid = threadIdx.x;
    const int per = (Nn + 1023) >> 10;
    int begin = tid * per;
    int end = begin + per; if (end > Nn) end = Nn;
    if (begin > Nn) begin = Nn;
    int s = 0;
    for (int i = begin; i < end; i++) s += deg[i];
    sums[tid] = s;
    __syncthreads();
    for (int off = 1; off < 1024; off <<= 1) {
        int v = (tid >= off) ? sums[tid - off] : 0;
        __syncthreads();
        sums[tid] += v;
        __syncthreads();
    }
    int run = sums[tid] - s;
    for (int i = begin; i < end; i++) {
        offs[i] = run; cur[i] = run;
        run += deg[i];
    }
    if (end == Nn) offs[Nn] = run;
}

__global__ void fill_csr(const int* __restrict__ dst, const int* __restrict__ src,
                         int* __restrict__ cur, int* __restrict__ csrc) {
    for (int i = blockIdx.x * blockDim.x + threadIdx.x; i < Ee; i += gridDim.x * blockDim.x) {
        int p = atomicAdd(&cur[dst[i]], 1);
        csrc[p] = src[i];
    }
}

// ---------------------------------------------------------------------------
// Fused prep: projW split; Wfused = blockdiag(Wn)@Ws split-transposed;
// va/vd = Wn_h @ att halves; vc = bn_h . att halves; biasF = convB + bn@Ws;
// GRU weight transposes (coalesced [k][j] layout); graph offsets; dst hist.
// ---------------------------------------------------------------------------
struct PrepArgs {
    const float *projW, *convWn, *convWs, *convAtt, *convBn, *convB;
    const float *Wih0, *Whh0, *Wih1, *Whh1;
    const int *gid, *dst;
    unsigned short *pBth, *pBtl;
    unsigned short *WfTh0, *WfTl0, *WfTh1, *WfTl1;
    float *vavd, *vc, *biasF;
    float *WihT0, *WhhT0, *WihT1, *WhhT1;
    int *goffs, *deg;
};

__device__ inline void wsplit(const float* B, int K, int N, int idx,
                              unsigned short* Bth, unsigned short* Btl) {
    int k = idx / N, n = idx - k * N;
    float v = B[idx];
    unsigned short h = bf16_rne(v);
    unsigned short l = bf16_rne(v - bf16_f(h));
    Bth[(size_t)n * K + k] = h;
    Btl[(size_t)n * K + k] = l;
}
__device__ inline void gruT(const float* W, int K, int idx, float* WT) {
    int d = idx / (384 * K);
    int r = idx - d * 384 * K;
    int j = r / K, k = r - j * K;
    WT[(size_t)d * K * 384 + (size_t)k * 384 + j] = W[idx];
}

__global__ void prep_all(PrepArgs a) {
    int i = blockIdx.x * blockDim.x + threadIdx.x;
    if (i < 16384) { wsplit(a.projW, 128, 128, i, a.pBth, a.pBtl); return; } i -= 16384;
#pragma unroll
    for (int l = 0; l < 2; l++) {
        if (i < 49152) {
            int k = i >> 7, c = i & 127;
            int h = k >> 7, i_ = k & 127;
            const float* wn = a.convWn + (size_t)l * 49152 + (size_t)i_ * 384 + h * 128;
            const float* ws = a.convWs + (size_t)l * 49152 + (size_t)(h * 128) * 128 + c;
            float v = 0.f;
            for (int j = 0; j < 128; j++) v += wn[j] * ws[(size_t)j * 128];
            unsigned short hi = bf16_rne(v);
            unsigned short lo = bf16_rne(v - bf16_f(hi));
            unsigned short* th = l ? a.WfTh1 : a.WfTh0;
            unsigned short* tl = l ? a.WfTl1 : a.WfTl0;
            th[(size_t)c * 384 + k] = hi;
            tl[(size_t)c * 384 + k] = lo;
            return;
        }
        i -= 49152;
    }
    if (i < 1536) {
        int l = i / 768, r = i % 768;
        int sd = r / 384, rr = r % 384, h = rr >> 7, i_ = rr & 127;
        const float* wn = a.convWn + (size_t)l * 49152 + (size_t)i_ * 384 + h * 128;
        const float* at = a.convAtt + l * 768 + h * 256 + sd * 128;
        float v = 0.f;
        for (int j = 0; j < 128; j++) v += wn[j] * at[j];
        a.vavd[i] = v;
        return;
    } i -= 1536;
    if (i < 12) {
        int l = i / 6, r = i % 6, sd = r / 3, h = r % 3;
        const float* bn = a.convBn + l * 384 + h * 128;
        const float* at = a.convAtt + l * 768 + h * 256 + sd * 128;
        float v = 0.f;
        for (int j = 0; j < 128; j++) v += bn[j] * at[j];
        a.vc[i] = v;
        return;
    } i -= 12;
    if (i < 256) {
        int l = i >> 7, c = i & 127;
        const float* bn = a.convBn + l * 384;
        const float* ws = a.convWs + (size_t)l * 49152 + c;
        float v = a.convB[l * 128 + c];
        for (int k = 0; k < 384; k++) v += bn[k] * ws[(size_t)k * 128];
        a.biasF[i] = v;
        return;
    } i -= 256;
    if (i < 98304)  { gruT(a.Wih0, 128, i, a.WihT0); return; }  i -= 98304;
    if (i < 98304)  { gruT(a.Whh0, 128, i, a.WhhT0); return; }  i -= 98304;
    if (i < 196608) { gruT(a.Wih1, 256, i, a.WihT1); return; }  i -= 196608;
    if (i < 98304)  { gruT(a.Whh1, 128, i, a.WhhT1); return; }  i -= 98304;
    if (i < Nn) {
        int g = a.gid[i];
        if (i == 0) { for (int b = 0; b <= g; b++) a.goffs[b] = 0; }
        else { int pg = a.gid[i - 1]; for (int b = pg + 1; b <= g; b++) a.goffs[b] = i; }
        if (i == Nn - 1) { for (int b = g + 1; b <= Bb; b++) a.goffs[b] = Nn; }
        return;
    } i -= Nn;
    if (i < Ee) atomicAdd(&a.deg[a.dst[i]], 1);
}

// ---------------------------------------------------------------------------
// Split-bf16 MFMA GEMM, BM=32, BN=128, BK=32; 256 threads = 4 waves (1x4),
// wave tile 32x32 (2x2 MFMA 16x16x32). K-loop register-prefetch pipelined
// (next iteration's global loads issued under the MFMA phase). Fused
// epilogues: MODE 0 proj; MODE 2 residual+LN+ReLU. Both: per-graph readout;
// optional next-layer att dots + bf16 hcur plane.
// ---------------------------------------------------------------------------
struct GArgs {
    const float* A; const unsigned short* Bth; const unsigned short* Btl;
    const float* bias; int M, K;
    const int* wid; const float* projW;                 // MODE 0
    const int* deg; const float* gamma; const float* beta;  // MODE 2
    float* hcur;
    const int* gid; float* reado;
    const float* vavd; const float* vc;                 // null -> skip dots/hb
    float* adf; float* addf;
    unsigned short* hb;
};

template <int MODE>
__global__ __launch_bounds__(256) void gemm_fused(GArgs a) {
    __shared__ unsigned short As_hi[32][40];
    __shared__ unsigned short As_lo[32][40];
    __shared__ unsigned short Bs_hi[128][40];
    __shared__ unsigned short Bs_lo[128][40];
    __shared__ float ytile[32][132];
    __shared__ float sred[6][32][4];
    __shared__ int sgid[32];
    const int tid  = threadIdx.x;
    const int row0 = blockIdx.y * 32;
    const int wn   = tid >> 6;          // wave 0..3 along N
    const int L    = tid & 63;
    const int lrow = L & 15;
    const int lq   = L >> 4;
    const int K = a.K;

    // staging geometry (fixed per thread)
    const int mA  = tid >> 3;           // A row 0..31
    const int kqA = (tid & 7) * 4;      // A col (floats)
    const int nB  = tid >> 1;           // B row 0..127
    const int khB = (tid & 1) * 16;     // B col base (shorts)
    const float* Arow = a.A + (size_t)(row0 + mA) * K + kqA;
    const unsigned short* Bhrow = a.Bth + (size_t)nB * K + khB;
    const unsigned short* Blrow = a.Btl + (size_t)nB * K + khB;

    f32x4 acc[2][2];
#pragma unroll
    for (int i = 0; i < 2; i++)
#pragma unroll
        for (int j = 0; j < 2; j++) acc[i][j] = (f32x4){0.f, 0.f, 0.f, 0.f};

    // prefetch iteration 0
    float4 av  = *(const float4*)(Arow);
    float4 vbh0 = *(const float4*)(Bhrow);
    float4 vbh1 = *(const float4*)(Bhrow + 8);
    float4 vbl0 = *(const float4*)(Blrow);
    float4 vbl1 = *(const float4*)(Blrow + 8);

    for (int kb = 0; kb < K; kb += 32) {
        {   // write staged registers to LDS (A converted to split-bf16)
            unsigned short h0 = bf16_rne(av.x), h1 = bf16_rne(av.y),
                           h2 = bf16_rne(av.z), h3 = bf16_rne(av.w);
            *(short4*)&As_hi[mA][kqA] = make_short4((short)h0, (short)h1, (short)h2, (short)h3);
            *(short4*)&As_lo[mA][kqA] = make_short4((short)bf16_rne(av.x - bf16_f(h0)),
                                                    (short)bf16_rne(av.y - bf16_f(h1)),
                                                    (short)bf16_rne(av.z - bf16_f(h2)),
                                                    (short)bf16_rne(av.w - bf16_f(h3)));
            *(float4*)&Bs_hi[nB][khB]     = vbh0;
            *(float4*)&Bs_hi[nB][khB + 8] = vbh1;
            *(float4*)&Bs_lo[nB][khB]     = vbl0;
            *(float4*)&Bs_lo[nB][khB + 8] = vbl1;
        }
        __syncthreads();
        if (kb + 32 < K) {   // issue next iteration's loads (hidden under MFMA)
            av   = *(const float4*)(Arow + kb + 32);
            vbh0 = *(const float4*)(Bhrow + kb + 32);
            vbh1 = *(const float4*)(Bhrow + kb + 40);
            vbl0 = *(const float4*)(Blrow + kb + 32);
            vbl1 = *(const float4*)(Blrow + kb + 40);
        }
        bf16x8 ah[2], al[2], bh[2], bl[2];
#pragma unroll
        for (int mi = 0; mi < 2; mi++) {
            int r = mi * 16 + lrow;
            ah[mi] = *(const bf16x8*)&As_hi[r][lq * 8];
            al[mi] = *(const bf16x8*)&As_lo[r][lq * 8];
        }
#pragma unroll
        for (int ni = 0; ni < 2; ni++) {
            int r = wn * 32 + ni * 16 + lrow;
            bh[ni] = *(const bf16x8*)&Bs_hi[r][lq * 8];
            bl[ni] = *(const bf16x8*)&Bs_lo[r][lq * 8];
        }
#pragma unroll
        for (int mi = 0; mi < 2; mi++)
#pragma unroll
            for (int ni = 0; ni < 2; ni++) {
                acc[mi][ni] = __builtin_amdgcn_mfma_f32_16x16x32_bf16(ah[mi], bh[ni], acc[mi][ni], 0, 0, 0);
                acc[mi][ni] = __builtin_amdgcn_mfma_f32_16x16x32_bf16(ah[mi], bl[ni], acc[mi][ni], 0, 0, 0);
                acc[mi][ni] = __builtin_amdgcn_mfma_f32_16x16x32_bf16(al[mi], bh[ni], acc[mi][ni], 0, 0, 0);
            }
        __syncthreads();
    }

    // bias
#pragma unroll
    for (int ni = 0; ni < 2; ni++) {
        float bb = a.bias[wn * 32 + ni * 16 + lrow];
#pragma unroll
        for (int mi = 0; mi < 2; mi++)
#pragma unroll
            for (int r = 0; r < 4; r++) acc[mi][ni][r] += bb;
    }

    if constexpr (MODE == 0) {
        // acc := y = acc + projW[wid[row]]  (bias already in)
#pragma unroll
        for (int mi = 0; mi < 2; mi++)
#pragma unroll
            for (int r = 0; r < 4; r++) {
                int lr = mi * 16 + lq * 4 + r;
                int row = row0 + lr;
                int wi = a.wid[row];
#pragma unroll
                for (int ni = 0; ni < 2; ni++) {
                    int c = wn * 32 + ni * 16 + lrow;
                    float y = acc[mi][ni][r] + a.projW[(size_t)wi * 128 + c];
                    acc[mi][ni][r] = y;
                    a.hcur[(size_t)row * 128 + c] = y;
                    ytile[lr][c] = y;
                }
            }
    }

    if constexpr (MODE == 2) {
        __shared__ float red1[32][4], red2[32][4];
        float g4[2], be4[2];
#pragma unroll
        for (int ni = 0; ni < 2; ni++) {
            int c = wn * 32 + ni * 16 + lrow;
            g4[ni] = a.gamma[c]; be4[ni] = a.beta[c];
        }
#pragma unroll
        for (int mi = 0; mi < 2; mi++)
#pragma unroll
            for (int r = 0; r < 4; r++) {
                int lr = mi * 16 + lq * 4 + r;
                int row = row0 + lr;
                int dg = a.deg[row];
#pragma unroll
                for (int ni = 0; ni < 2; ni++) {
                    int c = wn * 32 + ni * 16 + lrow;
                    float hold = a.hcur[(size_t)row * 128 + c];
                    acc[mi][ni][r] = hold + (dg > 0 ? acc[mi][ni][r] : 0.f);
                }
            }
#pragma unroll
        for (int mi = 0; mi < 2; mi++)
#pragma unroll
            for (int r = 0; r < 4; r++) {
                float ps = acc[mi][0][r] + acc[mi][1][r];
#pragma unroll
                for (int o = 1; o < 16; o <<= 1) ps += __shfl_xor(ps, o, 64);
                if (lrow == 0) red1[mi * 16 + lq * 4 + r][wn] = ps;
            }
        __syncthreads();
#pragma unroll
        for (int mi = 0; mi < 2; mi++)
#pragma unroll
            for (int r = 0; r < 4; r++) {
                int lr = mi * 16 + lq * 4 + r;
                float mu = (red1[lr][0] + red1[lr][1] + red1[lr][2] + red1[lr][3]) * (1.f / 128.f);
                float qs = 0.f;
#pragma unroll
                for (int ni = 0; ni < 2; ni++) {
                    float dx = acc[mi][ni][r] - mu;
                    qs += dx * dx;
                }
#pragma unroll
                for (int o = 1; o < 16; o <<= 1) qs += __shfl_xor(qs, o, 64);
                if (lrow == 0) red2[lr][wn] = qs;
            }
        __syncthreads();
#pragma unroll
        for (int mi = 0; mi < 2; mi++)
#pragma unroll
            for (int r = 0; r < 4; r++) {
                int lr = mi * 16 + lq * 4 + r;
                int row = row0 + lr;
                float mu = (red1[lr][0] + red1[lr][1] + red1[lr][2] + red1[lr][3]) * (1.f / 128.f);
                float var = (red2[lr][0] + red2[lr][1] + red2[lr][2] + red2[lr][3]) * (1.f / 128.f);
                float rs = rsqrtf(var + EPS);
#pragma unroll
                for (int ni = 0; ni < 2; ni++) {
                    int c = wn * 32 + ni * 16 + lrow;
                    float y = fmaxf((acc[mi][ni][r] - mu) * rs * g4[ni] + be4[ni], 0.f);
                    acc[mi][ni][r] = y;
                    a.hcur[(size_t)row * 128 + c] = y;
                    ytile[lr][c] = y;
                }
            }
    }

    if (tid < 32) sgid[tid] = a.gid[row0 + tid];

    // ---- register-space attention dots (no ytile loop, no global v loop) ----
    const bool dots = (a.vavd != nullptr);
    if (dots) {
        float vv0[6], vv1[6];
#pragma unroll
        for (int d = 0; d < 6; d++) {
            vv0[d] = a.vavd[d * 128 + wn * 32 + lrow];
            vv1[d] = a.vavd[d * 128 + wn * 32 + 16 + lrow];
        }
#pragma unroll
        for (int d = 0; d < 6; d++) {
#pragma unroll
            for (int mi = 0; mi < 2; mi++)
#pragma unroll
                for (int r = 0; r < 4; r++) {
                    float ps = acc[mi][0][r] * vv0[d] + acc[mi][1][r] * vv1[d];
#pragma unroll
                    for (int o = 1; o < 16; o <<= 1) ps += __shfl_xor(ps, o, 64);
                    if (lrow == 0) sred[d][mi * 16 + lq * 4 + r][wn] = ps;
                }
        }
    }
    __syncthreads();

    // fused per-graph readout (gid sorted -> runs, atomic per run)
    {
        int j = tid & 127, hh = tid >> 7;
        float sum = 0.f; int curg = -1;
        for (int r = hh * 16; r < hh * 16 + 16; r++) {
            int g = sgid[r];
            if (g != curg) {
                if (curg >= 0) atomicAdd(&a.reado[(size_t)curg * 128 + j], sum);
                sum = 0.f; curg = g;
            }
            sum += ytile[r][j];
        }
        if (curg >= 0) atomicAdd(&a.reado[(size_t)curg * 128 + j], sum);
    }

    if (dots) {
        if (tid < 192) {
            int row = tid & 31, d = tid >> 5;     // d in [0,6)
            float s = sred[d][row][0] + sred[d][row][1] + sred[d][row][2] + sred[d][row][3]
                    + a.vc[d];
            int node = row0 + row;
            int sd = d / 3, h = d - sd * 3;
            float* dstp = sd ? a.addf : a.adf;
            dstp[(size_t)node * 4 + h] = s;
        }
        {   // bf16 hcur plane from ytile (<=2-way bank aliasing, free)
            int row = tid >> 3, c0 = (tid & 7) * 16;
            unsigned* dst = (unsigned*)(a.hb + (size_t)(row0 + row) * 128 + c0);
#pragma unroll
            for (int q = 0; q < 8; q++) {
                unsigned lo = bf16_rne(ytile[row][c0 + 2 * q]);
                unsigned hi = bf16_rne(ytile[row][c0 + 2 * q + 1]);
                dst[q] = lo | (hi << 16);
            }
        }
    }
}

// ---------------------------------------------------------------------------
// GAT gather: one wave per dst node, bf16 hcur rows (256B), scores from dots.
// ---------------------------------------------------------------------------
__global__ __launch_bounds__(256) void gat_gather(const unsigned short* __restrict__ hb,
                                                  const float4* __restrict__ ad,
                                                  const float4* __restrict__ add,
                                                  const int* __restrict__ offs,
                                                  const int* __restrict__ csrc,
                                                  float* __restrict__ T) {
    __shared__ float4 slot[4][64];
    const int n = (blockIdx.x * 256 + threadIdx.x) >> 6;
    const int wv_ = threadIdx.x >> 6;
    const int L = threadIdx.x & 63;
    if (n >= Nn) return;
    const int start = offs[n];
    const int deg = offs[n + 1] - start;
    float2* o2 = (float2*)(T + (size_t)n * 384);
    if (deg == 0) {
        float2 z = make_float2(0.f, 0.f);
        o2[L] = z; o2[64 + L] = z; o2[128 + L] = z;
        return;
    }
    const float4 adn = add[n];
    float2 t0 = make_float2(0.f, 0.f), t1 = t0, t2 = t0;

    if (deg <= 64) {
        int sn = 0; float e0 = 0.f, e1 = 0.f, e2 = 0.f;
        if (L < deg) {
            sn = csrc[start + L];
            float4 a4 = ad[sn];
            e0 = __expf(lrelu(a4.x + adn.x));
            e1 = __expf(lrelu(a4.y + adn.y));
            e2 = __expf(lrelu(a4.z + adn.z));
        }
        float s0 = e0, s1 = e1, s2 = e2;
#pragma unroll
        for (int o = 32; o > 0; o >>= 1) {
            s0 += __shfl_xor(s0, o, 64);
            s1 += __shfl_xor(s1, o, 64);
            s2 += __shfl_xor(s2, o, 64);
        }
        slot[wv_][L] = make_float4(__builtin_bit_cast(float, sn),
                                   e0 / s0, e1 / s1, e2 / s2);
        __builtin_amdgcn_wave_barrier();
#pragma unroll 2
        for (int j = 0; j < deg; j++) {
            float4 sc = slot[wv_][j];
            int s_n = __builtin_bit_cast(int, sc.x);
            unsigned u = ((const unsigned*)(hb + (size_t)s_n * 128))[L];
            float x0 = bf_lo(u), x1 = bf_hi(u);
            t0.x += sc.y * x0; t0.y += sc.y * x1;
            t1.x += sc.z * x0; t1.y += sc.z * x1;
            t2.x += sc.w * x0; t2.y += sc.w * x1;
        }
    } else {
        float s0 = 0.f, s1 = 0.f, s2 = 0.f;
        for (int i = L; i < deg; i += 64) {
            int sn = csrc[start + i];
            float4 a4 = ad[sn];
            s0 += __expf(lrelu(a4.x + adn.x));
            s1 += __expf(lrelu(a4.y + adn.y));
            s2 += __expf(lrelu(a4.z + adn.z));
        }
#pragma unroll
        for (int o = 32; o > 0; o >>= 1) {
            s0 += __shfl_xor(s0, o, 64);
            s1 += __shfl_xor(s1, o, 64);
            s2 += __shfl_xor(s2, o, 64);
        }
        float i0 = 1.f / s0, i1 = 1.f / s1, i2 = 1.f / s2;
        for (int base = 0; base < deg; base += 64) {
            int cnt = deg - base; if (cnt > 64) cnt = 64;
            if (L < cnt) {
                int sn = csrc[start + base + L];
                float4 a4 = ad[sn];
                slot[wv_][L] = make_float4(__builtin_bit_cast(float, sn),
                                           __expf(lrelu(a4.x + adn.x)) * i0,
                                           __expf(lrelu(a4.y + adn.y)) * i1,
                                           __expf(lrelu(a4.z + adn.z)) * i2);
            }
            __builtin_amdgcn_wave_barrier();
            for (int j = 0; j < cnt; j++) {
                float4 sc = slot[wv_][j];
                int s_n = __builtin_bit_cast(int, sc.x);
                unsigned u = ((const unsigned*)(hb + (size_t)s_n * 128))[L];
                float x0 = bf_lo(u), x1 = bf_hi(u);
                t0.x += sc.y * x0; t0.y += sc.y * x1;
                t1.x += sc.z * x0; t1.y += sc.z * x1;
                t2.x += sc.w * x0; t2.y += sc.w * x1;
            }
            __builtin_amdgcn_wave_barrier();
        }
    }
    o2[L] = t0; o2[64 + L] = t1; o2[128 + L] = t2;
}

// ---------------------------------------------------------------------------
// GRU: byte-exact round-0 gru_all (known-good 45.5 us, BW-bound streaming
// ~710 MB of weights) with ONE exact change: skip the Whh.h dot at step 0
// where h == 0 (g = bhh exactly). Cuts Whh re-stream from 3x to 2x per
// layer: ~710 -> ~550 MB. One block per batch element, 768 thr (2dir x 384).
// ---------------------------------------------------------------------------
__global__ __launch_bounds__(768) void gru_all(const float* __restrict__ reado,
                                               const int* __restrict__ goffs,
                                               const float* __restrict__ WihT0,
                                               const float* __restrict__ WhhT0,
                                               const float* __restrict__ bih0,
                                               const float* __restrict__ bhh0,
                                               const float* __restrict__ WihT1,
                                               const float* __restrict__ WhhT1,
                                               const float* __restrict__ bih1,
                                               const float* __restrict__ bhh1,
                                               float* __restrict__ out) {
    const int b = blockIdx.x;
    const int tid = threadIdx.x;
    const int dir = tid / 384;
    const int j = tid - dir * 384;
    __shared__ float xs[3][128];
    __shared__ float y0s[3][256];
    __shared__ float hs[2][128];
    __shared__ float gil[2][384], ghl[2][384];
    __shared__ float fin01[2][128];
    if (tid < 128) {
        int cnt = goffs[b + 1] - goffs[b];
        float invc = 1.f / fmaxf((float)cnt, 1.f);
#pragma unroll
        for (int t = 0; t < 3; t++)
            xs[t][tid] = reado[(size_t)t * Bb * Hh + (size_t)b * Hh + tid] * invc;
    }
    if (j < 128) hs[dir][j] = 0.f;
    __syncthreads();
    {
        const float* Wi = WihT0 + (size_t)dir * 128 * 384;
        const float* Wh = WhhT0 + (size_t)dir * 128 * 384;
        float gi[3];
        gi[0] = gi[1] = gi[2] = bih0[dir * 384 + j];
        for (int k = 0; k < 128; k++) {
            float w = Wi[(size_t)k * 384 + j];
            gi[0] += w * xs[0][k]; gi[1] += w * xs[1][k]; gi[2] += w * xs[2][k];
        }
        const float bhj = bhh0[dir * 384 + j];
        for (int step = 0; step < 3; step++) {
            int t = dir ? 2 - step : step;
            float g = bhj;
            if (step > 0) {
                for (int k = 0; k < 128; k++) g += Wh[(size_t)k * 384 + j] * hs[dir][k];
            }
            ghl[dir][j] = g;
            gil[dir][j] = gi[t];
            __syncthreads();
            if (j < 128) {
                float r = sigmoidf(gil[dir][j] + ghl[dir][j]);
                float z = sigmoidf(gil[dir][j + 128] + ghl[dir][j + 128]);
                float nn2 = tanhf(gil[dir][j + 256] + r * ghl[dir][j + 256]);
                float hnew = (1.f - z) * nn2 + z * hs[dir][j];
                hs[dir][j] = hnew;
                y0s[t][dir * 128 + j] = hnew;
                if (step == 2) fin01[dir][j] = hnew;
            }
            __syncthreads();
        }
    }
    if (j < 128) hs[dir][j] = 0.f;
    {
        const float* Wi = WihT1 + (size_t)dir * 256 * 384;
        const float* Wh = WhhT1 + (size_t)dir * 128 * 384;
        float gi[3];
        gi[0] = gi[1] = gi[2] = bih1[dir * 384 + j];
        for (int k = 0; k < 256; k++) {
            float w = Wi[(size_t)k * 384 + j];
            gi[0] += w * y0s[0][k]; gi[1] += w * y0s[1][k]; gi[2] += w * y0s[2][k];
        }
        const float bhj = bhh1[dir * 384 + j];
        __syncthreads();
        for (int step = 0; step < 3; step++) {
            int t = dir ? 2 - step : step;
            float g = bhj;
            if (step > 0) {
                for (int k = 0; k < 128; k++) g += Wh[(size_t)k * 384 + j] * hs[dir][k];
            }
            ghl[dir][j] = g;
            gil[dir][j] = gi[t];
            __syncthreads();
            if (j < 128) {
                float r = sigmoidf(gil[dir][j] + ghl[dir][j]);
                float z = sigmoidf(gil[dir][j + 128] + ghl[dir][j + 128]);
                float nn2 = tanhf(gil[dir][j + 256] + r * ghl[dir][j + 256]);
                float hnew = (1.f - z) * nn2 + z * hs[dir][j];
                hs[dir][j] = hnew;
                if (step == 2) xs[dir][j] = hnew;
            }
            __syncthreads();
        }
    }
    if (tid < 128)
        out[(size_t)b * Hh + tid] = 0.25f * (fin01[0][tid] + fin01[1][tid] +
                                             xs[0][tid] + xs[1][tid]);
}

// ---------------------------------------------------------------------------
extern "C" void kernel_launch(void* const* d_in, const int* in_sizes, int n_in,
                              void* d_out, int out_size, void* d_ws, size_t ws_size,
                              hipStream_t stream) {
    const float* h      = (const float*)d_in[0];
    const int*   wid    = (const int*)d_in[1];
    const int*   src    = (const int*)d_in[2];
    const int*   dst    = (const int*)d_in[3];
    const int*   gid    = (const int*)d_in[4];
    const float* projW  = (const float*)d_in[5];
    const float* projB  = (const float*)d_in[6];
    const float* convWn = (const float*)d_in[7];
    const float* convBn = (const float*)d_in[8];
    const float* convAtt= (const float*)d_in[9];
    const float* convWs = (const float*)d_in[10];
    const float* convB  = (const float*)d_in[11];
    const float* convG  = (const float*)d_in[12];
    const float* convBe = (const float*)d_in[13];
    const float* Wih0   = (const float*)d_in[14];
    const float* Whh0   = (const float*)d_in[15];
    const float* bih0   = (const float*)d_in[16];
    const float* bhh0   = (const float*)d_in[17];
    const float* Wih1   = (const float*)d_in[18];
    const float* Whh1   = (const float*)d_in[19];
    const float* bih1   = (const float*)d_in[20];
    const float* bhh1   = (const float*)d_in[21];
    float* out = (float*)d_out;

    char* p = (char*)d_ws;
    auto align16 = [&]() { p = (char*)(((uintptr_t)p + 15) & ~(uintptr_t)15); };
    auto alloc_f = [&](size_t n) { align16(); float* r = (float*)p; p += n * sizeof(float); return r; };
    auto alloc_i = [&](size_t n) { align16(); int* r = (int*)p; p += n * sizeof(int); return r; };
    auto alloc_s = [&](size_t n) { align16(); unsigned short* r = (unsigned short*)p; p += n * sizeof(unsigned short); return r; };
    float* hcur  = alloc_f((size_t)Nn * 128);
    float* T     = alloc_f((size_t)Nn * 384);
    float* adbuf = alloc_f((size_t)Nn * 4);
    float* addbuf= alloc_f((size_t)Nn * 4);
    // contiguous zero region: reado | deg
    float* reado = alloc_f((size_t)3 * Bb * Hh);
    int* deg  = alloc_i(Nn);
    const size_t zero_bytes = (size_t)3 * Bb * Hh * sizeof(float) + Nn * sizeof(int);
    float* WihT0 = alloc_f((size_t)2 * 128 * 384);
    float* WhhT0 = alloc_f((size_t)2 * 128 * 384);
    float* WihT1 = alloc_f((size_t)2 * 256 * 384);
    float* WhhT1 = alloc_f((size_t)2 * 128 * 384);
    float* vavd  = alloc_f(1536);
    float* vc    = alloc_f(12);
    float* biasF = alloc_f(256);
    int* offs = alloc_i(Nn + 1);
    int* cur  = alloc_i(Nn);
    int* csrc = alloc_i(Ee);
    int* goffs = alloc_i(Bb + 1);
    unsigned short* hb = alloc_s((size_t)Nn * 128);   // bf16 hcur plane
    unsigned short* pBth = alloc_s(128 * 128);
    unsigned short* pBtl = alloc_s(128 * 128);
    unsigned short* WfTh[2] = { alloc_s(128 * 384), alloc_s(128 * 384) };
    unsigned short* WfTl[2] = { alloc_s(128 * 384), alloc_s(128 * 384) };

    hipMemsetAsync(reado, 0, zero_bytes, stream);

    PrepArgs pa;
    pa.projW = projW + (size_t)Vv * Hh;
    pa.convWn = convWn; pa.convWs = convWs; pa.convAtt = convAtt;
    pa.convBn = convBn; pa.convB = convB;
    pa.Wih0 = Wih0; pa.Whh0 = Whh0; pa.Wih1 = Wih1; pa.Whh1 = Whh1;
    pa.gid = gid; pa.dst = dst;
    pa.pBth = pBth; pa.pBtl = pBtl;
    pa.WfTh0 = WfTh[0]; pa.WfTl0 = WfTl[0]; pa.WfTh1 = WfTh[1]; pa.WfTl1 = WfTl[1];
    pa.vavd = vavd; pa.vc = vc; pa.biasF = biasF;
    pa.WihT0 = WihT0; pa.WhhT0 = WhhT0; pa.WihT1 = WihT1; pa.WhhT1 = WhhT1;
    pa.goffs = goffs; pa.deg = deg;
    const int prep_total = 16384 + 2 * 49152 + 1536 + 12 + 256 + 98304 + 98304 + 196608 + 98304 + Nn + Ee;
    prep_all<<<(prep_total + 255) / 256, 256, 0, stream>>>(pa);

    scan_offsets<<<1, 1024, 0, stream>>>(deg, offs, cur);
    fill_csr<<<1250, 256, 0, stream>>>(dst, src, cur, csrc);

    // projection + dots L0 + hb + readout0
    {
        GArgs g = {};
        g.A = h; g.Bth = pBth; g.Btl = pBtl; g.bias = projB;
        g.M = Nn; g.K = 128;
        g.wid = wid; g.projW = projW; g.hcur = hcur;
        g.gid = gid; g.reado = reado;
        g.vavd = vavd; g.vc = vc; g.adf = adbuf; g.addf = addbuf; g.hb = hb;
        gemm_fused<0><<<dim3(1, Nn / 32), 256, 0, stream>>>(g);
    }

    const int nwaveblocks = (Nn * 64 + 255) / 256;   // 5000
    for (int l = 0; l < 2; l++) {
        gat_gather<<<nwaveblocks, 256, 0, stream>>>(hb, (const float4*)adbuf, (const float4*)addbuf,
                                                    offs, csrc, T);
        {
            GArgs g = {};
            g.A = T; g.Bth = WfTh[l]; g.Btl = WfTl[l]; g.bias = biasF + l * 128;
            g.M = Nn; g.K = 384;
            g.deg = deg; g.gamma = convG + l * Hh; g.beta = convBe + l * Hh;
            g.hcur = hcur;
            g.gid = gid; g.reado = reado + (size_t)(l + 1) * Bb * Hh;
            if (l == 0) { g.vavd = vavd + 768; g.vc = vc + 6; g.adf = adbuf; g.addf = addbuf; g.hb = hb; }
            gemm_fused<2><<<dim3(1, Nn / 32), 256, 0, stream>>>(g);
        }
    }

    gru_all<<<Bb, 768, 0, stream>>>(reado, goffs, WihT0, WhhT0, bih0, bhh0,
                                    WihT1, WhhT1, bih1, bhh1, out);
}

// Round 7
// 349.825 us; speedup vs baseline: 1.6771x; 1.0302x over previous
//
#include <hip/hip_runtime.h>
#include <cstddef>
#include <cstdint>

// Problem constants (from reference)
static constexpr int Nn    = 20000;
static constexpr int Ee    = 320000;
static constexpr int Vv    = 100;
static constexpr int Hh    = 128;
static constexpr int HEADS = 3;
static constexpr int Bb    = 200;
static constexpr float NEG = 0.2f;
static constexpr float EPS = 1e-5f;

typedef short bf16x8 __attribute__((ext_vector_type(8)));
typedef float f32x4  __attribute__((ext_vector_type(4)));

__device__ inline unsigned short bf16_rne(float x) {
    unsigned u = __builtin_bit_cast(unsigned, x);
    u += 0x7FFFu + ((u >> 16) & 1u);
    return (unsigned short)(u >> 16);
}
__device__ inline float bf16_f(unsigned short h) {
    unsigned u = ((unsigned)h) << 16;
    return __builtin_bit_cast(float, u);
}
__device__ inline float bf_lo(unsigned u) { return __builtin_bit_cast(float, u << 16); }
__device__ inline float bf_hi(unsigned u) { return __builtin_bit_cast(float, u & 0xFFFF0000u); }
__device__ inline float lrelu(float a) { return a >= 0.f ? a : NEG * a; }
__device__ inline float sigmoidf(float x) { return 1.f / (1.f + __expf(-x)); }

// ---------------------------------------------------------------------------
// CSR scan + fill (hist lives in prep_all)
// ---------------------------------------------------------------------------
__global__ __launch_bounds__(1024) void scan_offsets(const int* __restrict__ deg,
                                                     int* __restrict__ offs,
                                                     int* __restrict__ cur) {
    __shared__ int sums[1024];
    const int tid = threadIdx.x;
    const int per = (Nn + 1023) >> 10;
    int begin = tid * per;
    int end = begin + per; if (end > Nn) end = Nn;
    if (begin > Nn) begin = Nn;
    int s = 0;
    for (int i = begin; i < end; i++) s += deg[i];
    sums[tid] = s;
    __syncthreads();
    for (int off = 1; off < 1024; off <<= 1) {
        int v = (tid >= off) ? sums[tid - off] : 0;
        __syncthreads();
        sums[tid] += v;
        __syncthreads();
    }
    int run = sums[tid] - s;
    for (int i = begin; i < end; i++) {
        offs[i] = run; cur[i] = run;
        run += deg[i];
    }
    if (end == Nn) offs[Nn] = run;
}

__global__ void fill_csr(const int* __restrict__ dst, const int* __restrict__ src,
                         int* __restrict__ cur, int* __restrict__ csrc) {
    for (int i = blockIdx.x * blockDim.x + threadIdx.x; i < Ee; i += gridDim.x * blockDim.x) {
        int p = atomicAdd(&cur[dst[i]], 1);
        csrc[p] = src[i];
    }
}

// ---------------------------------------------------------------------------
// Fused prep: projW split; Wfused = blockdiag(Wn)@Ws split-transposed;
// va/vd = Wn_h @ att halves; vc = bn_h . att halves; biasF = convB + bn@Ws;
// GRU weight repack to [dir][k/4][j][4] (coalesced float4-per-thread);
// graph offsets; dst hist.
// ---------------------------------------------------------------------------
struct PrepArgs {
    const float *projW, *convWn, *convWs, *convAtt, *convBn, *convB;
    const float *Wih0, *Whh0, *Wih1, *Whh1;
    const int *gid, *dst;
    unsigned short *pBth, *pBtl;
    unsigned short *WfTh0, *WfTl0, *WfTh1, *WfTl1;
    float *vavd, *vc, *biasF;
    float *WihT0, *WhhT0, *WihT1, *WhhT1;
    int *goffs, *deg;
};

__device__ inline void wsplit(const float* B, int K, int N, int idx,
                              unsigned short* Bth, unsigned short* Btl) {
    int k = idx / N, n = idx - k * N;
    float v = B[idx];
    unsigned short h = bf16_rne(v);
    unsigned short l = bf16_rne(v - bf16_f(h));
    Bth[(size_t)n * K + k] = h;
    Btl[(size_t)n * K + k] = l;
}
// repack W[d][j][k] (row-major) -> W4[d][k>>2][j][k&3]
__device__ inline void gruT(const float* W, int K, int idx, float* WT) {
    int d = idx / (384 * K);
    int r = idx - d * 384 * K;
    int j = r / K, k = r - j * K;
    WT[(size_t)d * K * 384 + (size_t)(k >> 2) * 1536 + j * 4 + (k & 3)] = W[idx];
}

__global__ void prep_all(PrepArgs a) {
    int i = blockIdx.x * blockDim.x + threadIdx.x;
    if (i < 16384) { wsplit(a.projW, 128, 128, i, a.pBth, a.pBtl); return; } i -= 16384;
#pragma unroll
    for (int l = 0; l < 2; l++) {
        if (i < 49152) {
            int k = i >> 7, c = i & 127;
            int h = k >> 7, i_ = k & 127;
            const float* wn = a.convWn + (size_t)l * 49152 + (size_t)i_ * 384 + h * 128;
            const float* ws = a.convWs + (size_t)l * 49152 + (size_t)(h * 128) * 128 + c;
            float v = 0.f;
            for (int j = 0; j < 128; j++) v += wn[j] * ws[(size_t)j * 128];
            unsigned short hi = bf16_rne(v);
            unsigned short lo = bf16_rne(v - bf16_f(hi));
            unsigned short* th = l ? a.WfTh1 : a.WfTh0;
            unsigned short* tl = l ? a.WfTl1 : a.WfTl0;
            th[(size_t)c * 384 + k] = hi;
            tl[(size_t)c * 384 + k] = lo;
            return;
        }
        i -= 49152;
    }
    if (i < 1536) {
        int l = i / 768, r = i % 768;
        int sd = r / 384, rr = r % 384, h = rr >> 7, i_ = rr & 127;
        const float* wn = a.convWn + (size_t)l * 49152 + (size_t)i_ * 384 + h * 128;
        const float* at = a.convAtt + l * 768 + h * 256 + sd * 128;
        float v = 0.f;
        for (int j = 0; j < 128; j++) v += wn[j] * at[j];
        a.vavd[i] = v;
        return;
    } i -= 1536;
    if (i < 12) {
        int l = i / 6, r = i % 6, sd = r / 3, h = r % 3;
        const float* bn = a.convBn + l * 384 + h * 128;
        const float* at = a.convAtt + l * 768 + h * 256 + sd * 128;
        float v = 0.f;
        for (int j = 0; j < 128; j++) v += bn[j] * at[j];
        a.vc[i] = v;
        return;
    } i -= 12;
    if (i < 256) {
        int l = i >> 7, c = i & 127;
        const float* bn = a.convBn + l * 384;
        const float* ws = a.convWs + (size_t)l * 49152 + c;
        float v = a.convB[l * 128 + c];
        for (int k = 0; k < 384; k++) v += bn[k] * ws[(size_t)k * 128];
        a.biasF[i] = v;
        return;
    } i -= 256;
    if (i < 98304)  { gruT(a.Wih0, 128, i, a.WihT0); return; }  i -= 98304;
    if (i < 98304)  { gruT(a.Whh0, 128, i, a.WhhT0); return; }  i -= 98304;
    if (i < 196608) { gruT(a.Wih1, 256, i, a.WihT1); return; }  i -= 196608;
    if (i < 98304)  { gruT(a.Whh1, 128, i, a.WhhT1); return; }  i -= 98304;
    if (i < Nn) {
        int g = a.gid[i];
        if (i == 0) { for (int b = 0; b <= g; b++) a.goffs[b] = 0; }
        else { int pg = a.gid[i - 1]; for (int b = pg + 1; b <= g; b++) a.goffs[b] = i; }
        if (i == Nn - 1) { for (int b = g + 1; b <= Bb; b++) a.goffs[b] = Nn; }
        return;
    } i -= Nn;
    if (i < Ee) atomicAdd(&a.deg[a.dst[i]], 1);
}

// ---------------------------------------------------------------------------
// Split-bf16 MFMA GEMM, BM=32, BN=128, BK=32; 256 threads = 4 waves (1x4),
// wave tile 32x32 (2x2 MFMA 16x16x32). K-loop register-prefetch pipelined
// (next iteration's global loads issued under the MFMA phase). Fused
// epilogues: MODE 0 proj; MODE 2 residual+LN+ReLU. Both: per-graph readout;
// optional next-layer att dots + bf16 hcur plane.
// ---------------------------------------------------------------------------
struct GArgs {
    const float* A; const unsigned short* Bth; const unsigned short* Btl;
    const float* bias; int M, K;
    const int* wid; const float* projW;                 // MODE 0
    const int* deg; const float* gamma; const float* beta;  // MODE 2
    float* hcur;
    const int* gid; float* reado;
    const float* vavd; const float* vc;                 // null -> skip dots/hb
    float* adf; float* addf;
    unsigned short* hb;
};

template <int MODE>
__global__ __launch_bounds__(256) void gemm_fused(GArgs a) {
    __shared__ unsigned short As_hi[32][40];
    __shared__ unsigned short As_lo[32][40];
    __shared__ unsigned short Bs_hi[128][40];
    __shared__ unsigned short Bs_lo[128][40];
    __shared__ float ytile[32][132];
    __shared__ float sred[6][32][4];
    __shared__ int sgid[32];
    const int tid  = threadIdx.x;
    const int row0 = blockIdx.y * 32;
    const int wn   = tid >> 6;          // wave 0..3 along N
    const int L    = tid & 63;
    const int lrow = L & 15;
    const int lq   = L >> 4;
    const int K = a.K;

    // staging geometry (fixed per thread)
    const int mA  = tid >> 3;           // A row 0..31
    const int kqA = (tid & 7) * 4;      // A col (floats)
    const int nB  = tid >> 1;           // B row 0..127
    const int khB = (tid & 1) * 16;     // B col base (shorts)
    const float* Arow = a.A + (size_t)(row0 + mA) * K + kqA;
    const unsigned short* Bhrow = a.Bth + (size_t)nB * K + khB;
    const unsigned short* Blrow = a.Btl + (size_t)nB * K + khB;

    f32x4 acc[2][2];
#pragma unroll
    for (int i = 0; i < 2; i++)
#pragma unroll
        for (int j = 0; j < 2; j++) acc[i][j] = (f32x4){0.f, 0.f, 0.f, 0.f};

    // prefetch iteration 0
    float4 av  = *(const float4*)(Arow);
    float4 vbh0 = *(const float4*)(Bhrow);
    float4 vbh1 = *(const float4*)(Bhrow + 8);
    float4 vbl0 = *(const float4*)(Blrow);
    float4 vbl1 = *(const float4*)(Blrow + 8);

    for (int kb = 0; kb < K; kb += 32) {
        {   // write staged registers to LDS (A converted to split-bf16)
            unsigned short h0 = bf16_rne(av.x), h1 = bf16_rne(av.y),
                           h2 = bf16_rne(av.z), h3 = bf16_rne(av.w);
            *(short4*)&As_hi[mA][kqA] = make_short4((short)h0, (short)h1, (short)h2, (short)h3);
            *(short4*)&As_lo[mA][kqA] = make_short4((short)bf16_rne(av.x - bf16_f(h0)),
                                                    (short)bf16_rne(av.y - bf16_f(h1)),
                                                    (short)bf16_rne(av.z - bf16_f(h2)),
                                                    (short)bf16_rne(av.w - bf16_f(h3)));
            *(float4*)&Bs_hi[nB][khB]     = vbh0;
            *(float4*)&Bs_hi[nB][khB + 8] = vbh1;
            *(float4*)&Bs_lo[nB][khB]     = vbl0;
            *(float4*)&Bs_lo[nB][khB + 8] = vbl1;
        }
        __syncthreads();
        if (kb + 32 < K) {   // issue next iteration's loads (hidden under MFMA)
            av   = *(const float4*)(Arow + kb + 32);
            vbh0 = *(const float4*)(Bhrow + kb + 32);
            vbh1 = *(const float4*)(Bhrow + kb + 40);
            vbl0 = *(const float4*)(Blrow + kb + 32);
            vbl1 = *(const float4*)(Blrow + kb + 40);
        }
        bf16x8 ah[2], al[2], bh[2], bl[2];
#pragma unroll
        for (int mi = 0; mi < 2; mi++) {
            int r = mi * 16 + lrow;
            ah[mi] = *(const bf16x8*)&As_hi[r][lq * 8];
            al[mi] = *(const bf16x8*)&As_lo[r][lq * 8];
        }
#pragma unroll
        for (int ni = 0; ni < 2; ni++) {
            int r = wn * 32 + ni * 16 + lrow;
            bh[ni] = *(const bf16x8*)&Bs_hi[r][lq * 8];
            bl[ni] = *(const bf16x8*)&Bs_lo[r][lq * 8];
        }
#pragma unroll
        for (int mi = 0; mi < 2; mi++)
#pragma unroll
            for (int ni = 0; ni < 2; ni++) {
                acc[mi][ni] = __builtin_amdgcn_mfma_f32_16x16x32_bf16(ah[mi], bh[ni], acc[mi][ni], 0, 0, 0);
                acc[mi][ni] = __builtin_amdgcn_mfma_f32_16x16x32_bf16(ah[mi], bl[ni], acc[mi][ni], 0, 0, 0);
                acc[mi][ni] = __builtin_amdgcn_mfma_f32_16x16x32_bf16(al[mi], bh[ni], acc[mi][ni], 0, 0, 0);
            }
        __syncthreads();
    }

    // bias
#pragma unroll
    for (int ni = 0; ni < 2; ni++) {
        float bb = a.bias[wn * 32 + ni * 16 + lrow];
#pragma unroll
        for (int mi = 0; mi < 2; mi++)
#pragma unroll
            for (int r = 0; r < 4; r++) acc[mi][ni][r] += bb;
    }

    if constexpr (MODE == 0) {
        // acc := y = acc + projW[wid[row]]  (bias already in)
#pragma unroll
        for (int mi = 0; mi < 2; mi++)
#pragma unroll
            for (int r = 0; r < 4; r++) {
                int lr = mi * 16 + lq * 4 + r;
                int row = row0 + lr;
                int wi = a.wid[row];
#pragma unroll
                for (int ni = 0; ni < 2; ni++) {
                    int c = wn * 32 + ni * 16 + lrow;
                    float y = acc[mi][ni][r] + a.projW[(size_t)wi * 128 + c];
                    acc[mi][ni][r] = y;
                    a.hcur[(size_t)row * 128 + c] = y;
                    ytile[lr][c] = y;
                }
            }
    }

    if constexpr (MODE == 2) {
        __shared__ float red1[32][4], red2[32][4];
        float g4[2], be4[2];
#pragma unroll
        for (int ni = 0; ni < 2; ni++) {
            int c = wn * 32 + ni * 16 + lrow;
            g4[ni] = a.gamma[c]; be4[ni] = a.beta[c];
        }
#pragma unroll
        for (int mi = 0; mi < 2; mi++)
#pragma unroll
            for (int r = 0; r < 4; r++) {
                int lr = mi * 16 + lq * 4 + r;
                int row = row0 + lr;
                int dg = a.deg[row];
#pragma unroll
                for (int ni = 0; ni < 2; ni++) {
                    int c = wn * 32 + ni * 16 + lrow;
                    float hold = a.hcur[(size_t)row * 128 + c];
                    acc[mi][ni][r] = hold + (dg > 0 ? acc[mi][ni][r] : 0.f);
                }
            }
#pragma unroll
        for (int mi = 0; mi < 2; mi++)
#pragma unroll
            for (int r = 0; r < 4; r++) {
                float ps = acc[mi][0][r] + acc[mi][1][r];
#pragma unroll
                for (int o = 1; o < 16; o <<= 1) ps += __shfl_xor(ps, o, 64);
                if (lrow == 0) red1[mi * 16 + lq * 4 + r][wn] = ps;
            }
        __syncthreads();
#pragma unroll
        for (int mi = 0; mi < 2; mi++)
#pragma unroll
            for (int r = 0; r < 4; r++) {
                int lr = mi * 16 + lq * 4 + r;
                float mu = (red1[lr][0] + red1[lr][1] + red1[lr][2] + red1[lr][3]) * (1.f / 128.f);
                float qs = 0.f;
#pragma unroll
                for (int ni = 0; ni < 2; ni++) {
                    float dx = acc[mi][ni][r] - mu;
                    qs += dx * dx;
                }
#pragma unroll
                for (int o = 1; o < 16; o <<= 1) qs += __shfl_xor(qs, o, 64);
                if (lrow == 0) red2[lr][wn] = qs;
            }
        __syncthreads();
#pragma unroll
        for (int mi = 0; mi < 2; mi++)
#pragma unroll
            for (int r = 0; r < 4; r++) {
                int lr = mi * 16 + lq * 4 + r;
                int row = row0 + lr;
                float mu = (red1[lr][0] + red1[lr][1] + red1[lr][2] + red1[lr][3]) * (1.f / 128.f);
                float var = (red2[lr][0] + red2[lr][1] + red2[lr][2] + red2[lr][3]) * (1.f / 128.f);
                float rs = rsqrtf(var + EPS);
#pragma unroll
                for (int ni = 0; ni < 2; ni++) {
                    int c = wn * 32 + ni * 16 + lrow;
                    float y = fmaxf((acc[mi][ni][r] - mu) * rs * g4[ni] + be4[ni], 0.f);
                    acc[mi][ni][r] = y;
                    a.hcur[(size_t)row * 128 + c] = y;
                    ytile[lr][c] = y;
                }
            }
    }

    if (tid < 32) sgid[tid] = a.gid[row0 + tid];

    // ---- register-space attention dots (no ytile loop, no global v loop) ----
    const bool dots = (a.vavd != nullptr);
    if (dots) {
        float vv0[6], vv1[6];
#pragma unroll
        for (int d = 0; d < 6; d++) {
            vv0[d] = a.vavd[d * 128 + wn * 32 + lrow];
            vv1[d] = a.vavd[d * 128 + wn * 32 + 16 + lrow];
        }
#pragma unroll
        for (int d = 0; d < 6; d++) {
#pragma unroll
            for (int mi = 0; mi < 2; mi++)
#pragma unroll
                for (int r = 0; r < 4; r++) {
                    float ps = acc[mi][0][r] * vv0[d] + acc[mi][1][r] * vv1[d];
#pragma unroll
                    for (int o = 1; o < 16; o <<= 1) ps += __shfl_xor(ps, o, 64);
                    if (lrow == 0) sred[d][mi * 16 + lq * 4 + r][wn] = ps;
                }
        }
    }
    __syncthreads();

    // fused per-graph readout (gid sorted -> runs, atomic per run)
    {
        int j = tid & 127, hh = tid >> 7;
        float sum = 0.f; int curg = -1;
        for (int r = hh * 16; r < hh * 16 + 16; r++) {
            int g = sgid[r];
            if (g != curg) {
                if (curg >= 0) atomicAdd(&a.reado[(size_t)curg * 128 + j], sum);
                sum = 0.f; curg = g;
            }
            sum += ytile[r][j];
        }
        if (curg >= 0) atomicAdd(&a.reado[(size_t)curg * 128 + j], sum);
    }

    if (dots) {
        if (tid < 192) {
            int row = tid & 31, d = tid >> 5;     // d in [0,6)
            float s = sred[d][row][0] + sred[d][row][1] + sred[d][row][2] + sred[d][row][3]
                    + a.vc[d];
            int node = row0 + row;
            int sd = d / 3, h = d - sd * 3;
            float* dstp = sd ? a.addf : a.adf;
            dstp[(size_t)node * 4 + h] = s;
        }
        {   // bf16 hcur plane from ytile (<=2-way bank aliasing, free)
            int row = tid >> 3, c0 = (tid & 7) * 16;
            unsigned* dst = (unsigned*)(a.hb + (size_t)(row0 + row) * 128 + c0);
#pragma unroll
            for (int q = 0; q < 8; q++) {
                unsigned lo = bf16_rne(ytile[row][c0 + 2 * q]);
                unsigned hi = bf16_rne(ytile[row][c0 + 2 * q + 1]);
                dst[q] = lo | (hi << 16);
            }
        }
    }
}

// ---------------------------------------------------------------------------
// GAT gather: one wave per dst node, bf16 hcur rows (256B), scores from dots.
// ---------------------------------------------------------------------------
__global__ __launch_bounds__(256) void gat_gather(const unsigned short* __restrict__ hb,
                                                  const float4* __restrict__ ad,
                                                  const float4* __restrict__ add,
                                                  const int* __restrict__ offs,
                                                  const int* __restrict__ csrc,
                                                  float* __restrict__ T) {
    __shared__ float4 slot[4][64];
    const int n = (blockIdx.x * 256 + threadIdx.x) >> 6;
    const int wv_ = threadIdx.x >> 6;
    const int L = threadIdx.x & 63;
    if (n >= Nn) return;
    const int start = offs[n];
    const int deg = offs[n + 1] - start;
    float2* o2 = (float2*)(T + (size_t)n * 384);
    if (deg == 0) {
        float2 z = make_float2(0.f, 0.f);
        o2[L] = z; o2[64 + L] = z; o2[128 + L] = z;
        return;
    }
    const float4 adn = add[n];
    float2 t0 = make_float2(0.f, 0.f), t1 = t0, t2 = t0;

    if (deg <= 64) {
        int sn = 0; float e0 = 0.f, e1 = 0.f, e2 = 0.f;
        if (L < deg) {
            sn = csrc[start + L];
            float4 a4 = ad[sn];
            e0 = __expf(lrelu(a4.x + adn.x));
            e1 = __expf(lrelu(a4.y + adn.y));
            e2 = __expf(lrelu(a4.z + adn.z));
        }
        float s0 = e0, s1 = e1, s2 = e2;
#pragma unroll
        for (int o = 32; o > 0; o >>= 1) {
            s0 += __shfl_xor(s0, o, 64);
            s1 += __shfl_xor(s1, o, 64);
            s2 += __shfl_xor(s2, o, 64);
        }
        slot[wv_][L] = make_float4(__builtin_bit_cast(float, sn),
                                   e0 / s0, e1 / s1, e2 / s2);
        __builtin_amdgcn_wave_barrier();
#pragma unroll 2
        for (int j = 0; j < deg; j++) {
            float4 sc = slot[wv_][j];
            int s_n = __builtin_bit_cast(int, sc.x);
            unsigned u = ((const unsigned*)(hb + (size_t)s_n * 128))[L];
            float x0 = bf_lo(u), x1 = bf_hi(u);
            t0.x += sc.y * x0; t0.y += sc.y * x1;
            t1.x += sc.z * x0; t1.y += sc.z * x1;
            t2.x += sc.w * x0; t2.y += sc.w * x1;
        }
    } else {
        float s0 = 0.f, s1 = 0.f, s2 = 0.f;
        for (int i = L; i < deg; i += 64) {
            int sn = csrc[start + i];
            float4 a4 = ad[sn];
            s0 += __expf(lrelu(a4.x + adn.x));
            s1 += __expf(lrelu(a4.y + adn.y));
            s2 += __expf(lrelu(a4.z + adn.z));
        }
#pragma unroll
        for (int o = 32; o > 0; o >>= 1) {
            s0 += __shfl_xor(s0, o, 64);
            s1 += __shfl_xor(s1, o, 64);
            s2 += __shfl_xor(s2, o, 64);
        }
        float i0 = 1.f / s0, i1 = 1.f / s1, i2 = 1.f / s2;
        for (int base = 0; base < deg; base += 64) {
            int cnt = deg - base; if (cnt > 64) cnt = 64;
            if (L < cnt) {
                int sn = csrc[start + base + L];
                float4 a4 = ad[sn];
                slot[wv_][L] = make_float4(__builtin_bit_cast(float, sn),
                                           __expf(lrelu(a4.x + adn.x)) * i0,
                                           __expf(lrelu(a4.y + adn.y)) * i1,
                                           __expf(lrelu(a4.z + adn.z)) * i2);
            }
            __builtin_amdgcn_wave_barrier();
            for (int j = 0; j < cnt; j++) {
                float4 sc = slot[wv_][j];
                int s_n = __builtin_bit_cast(int, sc.x);
                unsigned u = ((const unsigned*)(hb + (size_t)s_n * 128))[L];
                float x0 = bf_lo(u), x1 = bf_hi(u);
                t0.x += sc.y * x0; t0.y += sc.y * x1;
                t1.x += sc.z * x0; t1.y += sc.z * x1;
                t2.x += sc.w * x0; t2.y += sc.w * x1;
            }
            __builtin_amdgcn_wave_barrier();
        }
    }
    o2[L] = t0; o2[64 + L] = t1; o2[128 + L] = t2;
}

// ---------------------------------------------------------------------------
// GRU: round-6 structure (one block per batch elem, 768 thr, step-0 h-dot
// skipped) with weights repacked to [dir][k/4][j][4] so each thread loads
// float4 (16B) instead of scalar (4B): 4x fewer load instructions, 4x the
// in-flight bytes per outstanding load -> pushes the L2 weight stream toward
// BW ceiling (measured 15 TB/s effective of 34.5 ceiling at scalar loads).
// LDS operands read as float4 broadcasts (align 16).
// ---------------------------------------------------------------------------
__global__ __launch_bounds__(768) void gru_all(const float* __restrict__ reado,
                                               const int* __restrict__ goffs,
                                               const float* __restrict__ WihT0,
                                               const float* __restrict__ WhhT0,
                                               const float* __restrict__ bih0,
                                               const float* __restrict__ bhh0,
                                               const float* __restrict__ WihT1,
                                               const float* __restrict__ WhhT1,
                                               const float* __restrict__ bih1,
                                               const float* __restrict__ bhh1,
                                               float* __restrict__ out) {
    const int b = blockIdx.x;
    const int tid = threadIdx.x;
    const int dir = tid / 384;
    const int j = tid - dir * 384;
    __shared__ __align__(16) float xs[3][128];
    __shared__ __align__(16) float y0s[3][256];
    __shared__ __align__(16) float hs[2][128];
    __shared__ float gil[2][384], ghl[2][384];
    __shared__ float fin01[2][128];
    if (tid < 128) {
        int cnt = goffs[b + 1] - goffs[b];
        float invc = 1.f / fmaxf((float)cnt, 1.f);
#pragma unroll
        for (int t = 0; t < 3; t++)
            xs[t][tid] = reado[(size_t)t * Bb * Hh + (size_t)b * Hh + tid] * invc;
    }
    if (j < 128) hs[dir][j] = 0.f;
    __syncthreads();
    {
        const float* Wi = WihT0 + (size_t)dir * 128 * 384;
        const float* Wh = WhhT0 + (size_t)dir * 128 * 384;
        float gi0, gi1, gi2;
        gi0 = gi1 = gi2 = bih0[dir * 384 + j];
#pragma unroll 4
        for (int k4 = 0; k4 < 32; k4++) {
            float4 w  = *(const float4*)(Wi + k4 * 1536 + j * 4);
            float4 x0 = *(const float4*)&xs[0][k4 * 4];
            float4 x1 = *(const float4*)&xs[1][k4 * 4];
            float4 x2 = *(const float4*)&xs[2][k4 * 4];
            gi0 += w.x * x0.x + w.y * x0.y + w.z * x0.z + w.w * x0.w;
            gi1 += w.x * x1.x + w.y * x1.y + w.z * x1.z + w.w * x1.w;
            gi2 += w.x * x2.x + w.y * x2.y + w.z * x2.z + w.w * x2.w;
        }
        const float bhj = bhh0[dir * 384 + j];
        for (int step = 0; step < 3; step++) {
            int t = dir ? 2 - step : step;
            float g = bhj;
            if (step > 0) {
#pragma unroll 4
                for (int k4 = 0; k4 < 32; k4++) {
                    float4 w  = *(const float4*)(Wh + k4 * 1536 + j * 4);
                    float4 hv = *(const float4*)&hs[dir][k4 * 4];
                    g += w.x * hv.x + w.y * hv.y + w.z * hv.z + w.w * hv.w;
                }
            }
            ghl[dir][j] = g;
            gil[dir][j] = dir ? (step == 0 ? gi2 : (step == 1 ? gi1 : gi0))
                              : (step == 0 ? gi0 : (step == 1 ? gi1 : gi2));
            __syncthreads();
            if (j < 128) {
                float r = sigmoidf(gil[dir][j] + ghl[dir][j]);
                float z = sigmoidf(gil[dir][j + 128] + ghl[dir][j + 128]);
                float nn2 = tanhf(gil[dir][j + 256] + r * ghl[dir][j + 256]);
                float hnew = (1.f - z) * nn2 + z * hs[dir][j];
                hs[dir][j] = hnew;
                y0s[t][dir * 128 + j] = hnew;
                if (step == 2) fin01[dir][j] = hnew;
            }
            __syncthreads();
        }
    }
    if (j < 128) hs[dir][j] = 0.f;
    {
        const float* Wi = WihT1 + (size_t)dir * 256 * 384;
        const float* Wh = WhhT1 + (size_t)dir * 128 * 384;
        float gi0, gi1, gi2;
        gi0 = gi1 = gi2 = bih1[dir * 384 + j];
        __syncthreads();
#pragma unroll 4
        for (int k4 = 0; k4 < 64; k4++) {
            float4 w  = *(const float4*)(Wi + k4 * 1536 + j * 4);
            float4 x0 = *(const float4*)&y0s[0][k4 * 4];
            float4 x1 = *(const float4*)&y0s[1][k4 * 4];
            float4 x2 = *(const float4*)&y0s[2][k4 * 4];
            gi0 += w.x * x0.x + w.y * x0.y + w.z * x0.z + w.w * x0.w;
            gi1 += w.x * x1.x + w.y * x1.y + w.z * x1.z + w.w * x1.w;
            gi2 += w.x * x2.x + w.y * x2.y + w.z * x2.z + w.w * x2.w;
        }
        const float bhj = bhh1[dir * 384 + j];
        for (int step = 0; step < 3; step++) {
            float g = bhj;
            if (step > 0) {
#pragma unroll 4
                for (int k4 = 0; k4 < 32; k4++) {
                    float4 w  = *(const float4*)(Wh + k4 * 1536 + j * 4);
                    float4 hv = *(const float4*)&hs[dir][k4 * 4];
                    g += w.x * hv.x + w.y * hv.y + w.z * hv.z + w.w * hv.w;
                }
            }
            ghl[dir][j] = g;
            gil[dir][j] = dir ? (step == 0 ? gi2 : (step == 1 ? gi1 : gi0))
                              : (step == 0 ? gi0 : (step == 1 ? gi1 : gi2));
            __syncthreads();
            if (j < 128) {
                float r = sigmoidf(gil[dir][j] + ghl[dir][j]);
                float z = sigmoidf(gil[dir][j + 128] + ghl[dir][j + 128]);
                float nn2 = tanhf(gil[dir][j + 256] + r * ghl[dir][j + 256]);
                float hnew = (1.f - z) * nn2 + z * hs[dir][j];
                hs[dir][j] = hnew;
                if (step == 2) fin01[dir][j] = 0.25f * (fin01[dir][j] + hnew);
            }
            __syncthreads();
        }
    }
    if (tid < 128)
        out[(size_t)b * Hh + tid] = fin01[0][tid] + fin01[1][tid];
}

// ---------------------------------------------------------------------------
extern "C" void kernel_launch(void* const* d_in, const int* in_sizes, int n_in,
                              void* d_out, int out_size, void* d_ws, size_t ws_size,
                              hipStream_t stream) {
    const float* h      = (const float*)d_in[0];
    const int*   wid    = (const int*)d_in[1];
    const int*   src    = (const int*)d_in[2];
    const int*   dst    = (const int*)d_in[3];
    const int*   gid    = (const int*)d_in[4];
    const float* projW  = (const float*)d_in[5];
    const float* projB  = (const float*)d_in[6];
    const float* convWn = (const float*)d_in[7];
    const float* convBn = (const float*)d_in[8];
    const float* convAtt= (const float*)d_in[9];
    const float* convWs = (const float*)d_in[10];
    const float* convB  = (const float*)d_in[11];
    const float* convG  = (const float*)d_in[12];
    const float* convBe = (const float*)d_in[13];
    const float* Wih0   = (const float*)d_in[14];
    const float* Whh0   = (const float*)d_in[15];
    const float* bih0   = (const float*)d_in[16];
    const float* bhh0   = (const float*)d_in[17];
    const float* Wih1   = (const float*)d_in[18];
    const float* Whh1   = (const float*)d_in[19];
    const float* bih1   = (const float*)d_in[20];
    const float* bhh1   = (const float*)d_in[21];
    float* out = (float*)d_out;

    char* p = (char*)d_ws;
    auto align16 = [&]() { p = (char*)(((uintptr_t)p + 15) & ~(uintptr_t)15); };
    auto alloc_f = [&](size_t n) { align16(); float* r = (float*)p; p += n * sizeof(float); return r; };
    auto alloc_i = [&](size_t n) { align16(); int* r = (int*)p; p += n * sizeof(int); return r; };
    auto alloc_s = [&](size_t n) { align16(); unsigned short* r = (unsigned short*)p; p += n * sizeof(unsigned short); return r; };
    float* hcur  = alloc_f((size_t)Nn * 128);
    float* T     = alloc_f((size_t)Nn * 384);
    float* adbuf = alloc_f((size_t)Nn * 4);
    float* addbuf= alloc_f((size_t)Nn * 4);
    // contiguous zero region: reado | deg
    float* reado = alloc_f((size_t)3 * Bb * Hh);
    int* deg  = alloc_i(Nn);
    const size_t zero_bytes = (size_t)3 * Bb * Hh * sizeof(float) + Nn * sizeof(int);
    float* WihT0 = alloc_f((size_t)2 * 128 * 384);
    float* WhhT0 = alloc_f((size_t)2 * 128 * 384);
    float* WihT1 = alloc_f((size_t)2 * 256 * 384);
    float* WhhT1 = alloc_f((size_t)2 * 128 * 384);
    float* vavd  = alloc_f(1536);
    float* vc    = alloc_f(12);
    float* biasF = alloc_f(256);
    int* offs = alloc_i(Nn + 1);
    int* cur  = alloc_i(Nn);
    int* csrc = alloc_i(Ee);
    int* goffs = alloc_i(Bb + 1);
    unsigned short* hb = alloc_s((size_t)Nn * 128);   // bf16 hcur plane
    unsigned short* pBth = alloc_s(128 * 128);
    unsigned short* pBtl = alloc_s(128 * 128);
    unsigned short* WfTh[2] = { alloc_s(128 * 384), alloc_s(128 * 384) };
    unsigned short* WfTl[2] = { alloc_s(128 * 384), alloc_s(128 * 384) };

    hipMemsetAsync(reado, 0, zero_bytes, stream);

    PrepArgs pa;
    pa.projW = projW + (size_t)Vv * Hh;
    pa.convWn = convWn; pa.convWs = convWs; pa.convAtt = convAtt;
    pa.convBn = convBn; pa.convB = convB;
    pa.Wih0 = Wih0; pa.Whh0 = Whh0; pa.Wih1 = Wih1; pa.Whh1 = Whh1;
    pa.gid = gid; pa.dst = dst;
    pa.pBth = pBth; pa.pBtl = pBtl;
    pa.WfTh0 = WfTh[0]; pa.WfTl0 = WfTl[0]; pa.WfTh1 = WfTh[1]; pa.WfTl1 = WfTl[1];
    pa.vavd = vavd; pa.vc = vc; pa.biasF = biasF;
    pa.WihT0 = WihT0; pa.WhhT0 = WhhT0; pa.WihT1 = WihT1; pa.WhhT1 = WhhT1;
    pa.goffs = goffs; pa.deg = deg;
    const int prep_total = 16384 + 2 * 49152 + 1536 + 12 + 256 + 98304 + 98304 + 196608 + 98304 + Nn + Ee;
    prep_all<<<(prep_total + 255) / 256, 256, 0, stream>>>(pa);

    scan_offsets<<<1, 1024, 0, stream>>>(deg, offs, cur);
    fill_csr<<<1250, 256, 0, stream>>>(dst, src, cur, csrc);

    // projection + dots L0 + hb + readout0
    {
        GArgs g = {};
        g.A = h; g.Bth = pBth; g.Btl = pBtl; g.bias = projB;
        g.M = Nn; g.K = 128;
        g.wid = wid; g.projW = projW; g.hcur = hcur;
        g.gid = gid; g.reado = reado;
        g.vavd = vavd; g.vc = vc; g.adf = adbuf; g.addf = addbuf; g.hb = hb;
        gemm_fused<0><<<dim3(1, Nn / 32), 256, 0, stream>>>(g);
    }

    const int nwaveblocks = (Nn * 64 + 255) / 256;   // 5000
    for (int l = 0; l < 2; l++) {
        gat_gather<<<nwaveblocks, 256, 0, stream>>>(hb, (const float4*)adbuf, (const float4*)addbuf,
                                                    offs, csrc, T);
        {
            GArgs g = {};
            g.A = T; g.Bth = WfTh[l]; g.Btl = WfTl[l]; g.bias = biasF + l * 128;
            g.M = Nn; g.K = 384;
            g.deg = deg; g.gamma = convG + l * Hh; g.beta = convBe + l * Hh;
            g.hcur = hcur;
            g.gid = gid; g.reado = reado + (size_t)(l + 1) * Bb * Hh;
            if (l == 0) { g.vavd = vavd + 768; g.vc = vc + 6; g.adf = adbuf; g.addf = addbuf; g.hb = hb; }
            gemm_fused<2><<<dim3(1, Nn / 32), 256, 0, stream>>>(g);
        }
    }

    gru_all<<<Bb, 768, 0, stream>>>(reado, goffs, WihT0, WhhT0, bih0, bhh0,
                                    WihT1, WhhT1, bih1, bhh1, out);
}